// Round 2
// baseline (4062.740 us; speedup 1.0000x reference)
//
#include <hip/hip_runtime.h>
#include <hip/hip_bf16.h>
#include <math.h>

typedef __hip_bfloat16 bf16;

// Problem constants (B,S,D,H,R,DFF fixed by the reference)
#define NB 4
#define NS 1024
#define ND 1024
#define NH 16
#define NDH 64
#define NR 64
#define NDFF 4096
#define NM (NB*NS)     // 4096 rows
#define NTOPK 204      // int(1024*0.2)

static __device__ __forceinline__ float b2f(bf16 x) { return __bfloat162float(x); }
static __device__ __forceinline__ bf16  f2b(float x) { return __float2bfloat16(x); }

// 8 consecutive bf16 -> fp32 (one 16B load)
static __device__ __forceinline__ void ld8(const bf16* p, float* d) {
  const uint4 u = *(const uint4*)p;
  d[0] = __uint_as_float((u.x & 0xffffu) << 16);
  d[1] = __uint_as_float(u.x & 0xffff0000u);
  d[2] = __uint_as_float((u.y & 0xffffu) << 16);
  d[3] = __uint_as_float(u.y & 0xffff0000u);
  d[4] = __uint_as_float((u.z & 0xffffu) << 16);
  d[5] = __uint_as_float(u.z & 0xffff0000u);
  d[6] = __uint_as_float((u.w & 0xffffu) << 16);
  d[7] = __uint_as_float(u.w & 0xffff0000u);
}
// 8 consecutive fp32 (two 16B loads)
static __device__ __forceinline__ void ldf8(const float* p, float* d) {
  const float4 u0 = ((const float4*)p)[0];
  const float4 u1 = ((const float4*)p)[1];
  d[0]=u0.x; d[1]=u0.y; d[2]=u0.z; d[3]=u0.w;
  d[4]=u1.x; d[5]=u1.y; d[6]=u1.z; d[7]=u1.w;
}
// 4 consecutive bf16 -> fp32 (one 8B load)
static __device__ __forceinline__ void ld4(const bf16* p, float* d) {
  const uint2 u = *(const uint2*)p;
  d[0] = __uint_as_float((u.x & 0xffffu) << 16);
  d[1] = __uint_as_float(u.x & 0xffff0000u);
  d[2] = __uint_as_float((u.y & 0xffffu) << 16);
  d[3] = __uint_as_float(u.y & 0xffff0000u);
}

static __device__ __forceinline__ float block_sum_256(float v, float* rbuf, int tid) {
  rbuf[tid] = v;
  __syncthreads();
  #pragma unroll
  for (int st = 128; st > 0; st >>= 1) {
    if (tid < st) rbuf[tid] += rbuf[tid + st];
    __syncthreads();
  }
  const float r = rbuf[0];
  __syncthreads();
  return r;
}

// ---------------------------------------------------------------------------
// Tiled GEMM: C[M,N] = A[M,K] @ W[N,K]^T + bias[N]   (fp32 accum)
// A is fp32 (AF32=1) or bf16 (AF32=0); W/bias always fp32 (they are inputs).
// 64x64 tile, BK=32, 256 threads, 4x4 outputs/thread (strided-16 mapping so
// LDS float4 reads are <=2-way bank-conflicted).
// ---------------------------------------------------------------------------
template<int AF32, int RELU, int OUTF32>
__global__ __launch_bounds__(256) void gemm_kernel(
    const void* __restrict__ Ap, const float* __restrict__ W,
    const float* __restrict__ bias, void* __restrict__ Cout,
    int M, int N, int K)
{
  __shared__ float As[64][36];
  __shared__ float Ws[64][36];
  const int tid = threadIdx.x;
  const int m0 = blockIdx.y << 6;
  const int n0 = blockIdx.x << 6;
  const int lr = tid >> 2;           // staging row 0..63
  const int lc = (tid & 3) << 3;     // staging col {0,8,16,24}
  const int ty = tid >> 4;           // 0..15 -> rows ty+16*i
  const int tx = tid & 15;           // 0..15 -> cols tx+16*j

  float acc[4][4];
  #pragma unroll
  for (int i = 0; i < 4; ++i)
    #pragma unroll
    for (int j = 0; j < 4; ++j) acc[i][j] = 0.f;

  for (int k0 = 0; k0 < K; k0 += 32) {
    float av[8], wv[8];
    if (AF32) ldf8((const float*)Ap + (size_t)(m0 + lr) * K + (k0 + lc), av);
    else      ld8((const bf16*)Ap + (size_t)(m0 + lr) * K + (k0 + lc), av);
    ldf8(W + (size_t)(n0 + lr) * K + (k0 + lc), wv);
    __syncthreads();   // protect previous iteration's LDS reads
    #pragma unroll
    for (int t = 0; t < 8; ++t) { As[lr][lc + t] = av[t]; Ws[lr][lc + t] = wv[t]; }
    __syncthreads();
    #pragma unroll
    for (int kk = 0; kk < 32; kk += 4) {
      float4 a[4], w[4];
      #pragma unroll
      for (int i = 0; i < 4; ++i) a[i] = *(const float4*)&As[ty + 16*i][kk];
      #pragma unroll
      for (int j = 0; j < 4; ++j) w[j] = *(const float4*)&Ws[tx + 16*j][kk];
      #pragma unroll
      for (int i = 0; i < 4; ++i)
        #pragma unroll
        for (int j = 0; j < 4; ++j)
          acc[i][j] += a[i].x*w[j].x + a[i].y*w[j].y + a[i].z*w[j].z + a[i].w*w[j].w;
    }
  }

  float bj[4];
  #pragma unroll
  for (int j = 0; j < 4; ++j) bj[j] = bias[n0 + tx + 16*j];
  #pragma unroll
  for (int i = 0; i < 4; ++i) {
    const size_t rowoff = (size_t)(m0 + ty + 16*i) * N;
    #pragma unroll
    for (int j = 0; j < 4; ++j) {
      float v = acc[i][j] + bj[j];
      if (RELU) v = fmaxf(v, 0.f);
      const int col = n0 + tx + 16*j;
      if (OUTF32) ((float*)Cout)[rowoff + col] = v;
      else        ((bf16*)Cout)[rowoff + col] = f2b(v);
    }
  }
}

// ---------------------------------------------------------------------------
// Dense MHA: block = (b, h, 16 q-rows). qkv workspace is bf16.
// Scores for 16x1024 kept bf16 in LDS (two-pass softmax).
// ---------------------------------------------------------------------------
__global__ __launch_bounds__(256) void attn_dense_kernel(
    const bf16* __restrict__ qkv, bf16* __restrict__ ctx)
{
  __shared__ float Qt[16][64];
  __shared__ float KVt[64][68];
  __shared__ bf16  Sc[16][1024];
  __shared__ float red[16][16];
  __shared__ float rowmax[16], rowsum[16];
  const int tid = threadIdx.x;
  const int b = blockIdx.z, h = blockIdx.y;
  const int q0 = blockIdx.x << 4;
  const size_t ld = 3 * ND;

  { // load Q tile (16x64) -> fp32 LDS
    const int r = tid >> 4, c = (tid & 15) << 2;
    ld4(qkv + ((size_t)(b*NS + q0 + r))*ld + h*NDH + c, &Qt[r][c]);
  }

  const int sr  = tid >> 2;            // staging row 0..63
  const int scc = (tid & 3) << 4;      // staging col {0,16,32,48}
  const int q   = tid >> 4;            // 0..15
  const int kb  = tid & 15;

  // pass 1: scores
  for (int kt = 0; kt < NS; kt += 64) {
    float t0[8], t1[8];
    const bf16* kp = qkv + ((size_t)(b*NS + kt + sr))*ld + ND + h*NDH + scc;
    ld8(kp, t0); ld8(kp + 8, t1);
    __syncthreads();
    #pragma unroll
    for (int t = 0; t < 8; ++t) { KVt[sr][scc + t] = t0[t]; KVt[sr][scc + 8 + t] = t1[t]; }
    __syncthreads();
    #pragma unroll
    for (int jj = 0; jj < 4; ++jj) {
      const int k = kb + (jj << 4);
      float s = 0.f;
      #pragma unroll
      for (int c = 0; c < 64; c += 4) {
        const float4 qa = *(const float4*)&Qt[q][c];
        const float4 ka = *(const float4*)&KVt[k][c];
        s += qa.x*ka.x + qa.y*ka.y + qa.z*ka.z + qa.w*ka.w;
      }
      Sc[q][kt + k] = f2b(s * 0.125f);   // 1/sqrt(64)
    }
  }
  __syncthreads();

  // softmax over each of the 16 rows (16 threads per row)
  {
    const int r = tid >> 4, l = tid & 15;
    float pm = -3.0e38f;
    for (int j2 = 0; j2 < 64; ++j2) pm = fmaxf(pm, b2f(Sc[r][l + (j2 << 4)]));
    red[r][l] = pm;
    __syncthreads();
    if (tid < 16) {
      float m = red[tid][0];
      #pragma unroll
      for (int t = 1; t < 16; ++t) m = fmaxf(m, red[tid][t]);
      rowmax[tid] = m;
    }
    __syncthreads();
    const float m = rowmax[r];
    float ps = 0.f;
    for (int j2 = 0; j2 < 64; ++j2) {
      const int idx = l + (j2 << 4);
      const float e = __expf(b2f(Sc[r][idx]) - m);
      const bf16 eb = f2b(e);
      Sc[r][idx] = eb;
      ps += b2f(eb);                 // sum the rounded weights for consistency
    }
    red[r][l] = ps;
    __syncthreads();
    if (tid < 16) {
      float s = 0.f;
      #pragma unroll
      for (int t = 0; t < 16; ++t) s += red[tid][t];
      rowsum[tid] = s;
    }
    // pass-2 barriers make rowsum visible before use
  }

  // pass 2: ctx = P @ V
  float a0 = 0.f, a1 = 0.f, a2 = 0.f, a3 = 0.f;
  const int d4 = (tid & 15) << 2;
  for (int kt = 0; kt < NS; kt += 64) {
    float t0[8], t1[8];
    const bf16* vp = qkv + ((size_t)(b*NS + kt + sr))*ld + 2*ND + h*NDH + scc;
    ld8(vp, t0); ld8(vp + 8, t1);
    __syncthreads();
    #pragma unroll
    for (int t = 0; t < 8; ++t) { KVt[sr][scc + t] = t0[t]; KVt[sr][scc + 8 + t] = t1[t]; }
    __syncthreads();
    for (int k = 0; k < 64; ++k) {
      const float p = b2f(Sc[q][kt + k]);
      const float4 v = *(const float4*)&KVt[k][d4];
      a0 += p*v.x; a1 += p*v.y; a2 += p*v.z; a3 += p*v.w;
    }
  }
  const float inv = 1.f / rowsum[q];
  bf16* op = ctx + ((size_t)(b*NS + q0 + q))*ND + h*NDH + d4;
  op[0] = f2b(a0*inv); op[1] = f2b(a1*inv); op[2] = f2b(a2*inv); op[3] = f2b(a3*inv);
}

// ---------------------------------------------------------------------------
// Low-rank top-k sparse attention. Block = one (b,q) row.
// softmax->topk->renorm == restricted softmax over the 204 largest scores.
// ---------------------------------------------------------------------------
__global__ __launch_bounds__(256) void sparse_attn_kernel(
    const float* __restrict__ Qs, const float* __restrict__ Ks,
    const bf16* __restrict__ Vs, float* __restrict__ outp)
{
  __shared__ float qrow[64];
  __shared__ float sorig[1024];
  __shared__ float ssort[1024];
  __shared__ float wts[1024];
  __shared__ float rbuf[256];
  const int tid = threadIdx.x;
  const int b = blockIdx.y, qi = blockIdx.x;

  if (tid < 64) qrow[tid] = Qs[((size_t)(b*NS + qi))*NR + tid];
  __syncthreads();

  // scores: each thread 4 rows of K (contiguous float4 reads, K resident in L2)
  #pragma unroll
  for (int j = 0; j < 4; ++j) {
    const int k = tid + (j << 8);
    const float4* kp = (const float4*)(Ks + ((size_t)(b*NS + k))*NR);
    float s = 0.f;
    #pragma unroll
    for (int c = 0; c < 16; ++c) {
      const float4 qa = *(const float4*)&qrow[c << 2];
      const float4 ka = kp[c];
      s += qa.x*ka.x + qa.y*ka.y + qa.z*ka.z + qa.w*ka.w;
    }
    s *= 0.125f;                     // 1/sqrt(64)
    sorig[k] = s; ssort[k] = s;
  }

  // bitonic sort descending (1024 elems, 256 threads)
  for (int size = 2; size <= 1024; size <<= 1) {
    for (int stride = size >> 1; stride > 0; stride >>= 1) {
      __syncthreads();
      #pragma unroll
      for (int t = 0; t < 4; ++t) {
        const int i = tid + (t << 8);
        const int j2 = i ^ stride;
        if (j2 > i) {
          const float x = ssort[i], y = ssort[j2];
          const bool desc = ((i & size) == 0);
          if (desc ? (x < y) : (x > y)) { ssort[i] = y; ssort[j2] = x; }
        }
      }
    }
  }
  __syncthreads();
  const float thr = ssort[NTOPK - 1];
  const float mx  = ssort[0];

  float psTop = 0.f, psAll = 0.f;
  #pragma unroll
  for (int j = 0; j < 4; ++j) {
    const int k = tid + (j << 8);
    const float s = sorig[k];
    const float e = __expf(s - mx);
    psAll += e;
    const float w = (s >= thr) ? e : 0.f;
    psTop += w;
    wts[k] = w;
  }
  const float sumTop = block_sum_256(psTop, rbuf, tid);
  const float sumAll = block_sum_256(psAll, rbuf, tid);
  // denominator: sum(topv) + 1e-9, expressed in exp units (Z cancels)
  const float inv = 1.f / (sumTop + 1e-9f * sumAll);

  float a0 = 0.f, a1 = 0.f, a2 = 0.f, a3 = 0.f;
  const bf16* vb = Vs + (size_t)b*NS*ND + tid;
  for (int k = 0; k < 1024; ++k) {
    const float w = wts[k];          // uniform across block -> uniform branch
    if (w > 0.f) {
      const bf16* vp = vb + (size_t)k*ND;
      a0 += w * b2f(vp[0]);
      a1 += w * b2f(vp[256]);
      a2 += w * b2f(vp[512]);
      a3 += w * b2f(vp[768]);
    }
  }
  float* op = outp + ((size_t)(b*NS + qi))*ND + tid;
  op[0] = a0*inv; op[256] = a1*inv; op[512] = a2*inv; op[768] = a3*inv;
}

// ---------------------------------------------------------------------------
// fused = sig*dense + (1-sig)*sparse ; x1 = LN1(src + fused)  (bf16 out)
// ---------------------------------------------------------------------------
__global__ __launch_bounds__(256) void fuse_ln1_kernel(
    const float* __restrict__ src, const float* __restrict__ dense,
    const float* __restrict__ sparse, const float* __restrict__ lam,
    const float* __restrict__ g, const float* __restrict__ beta,
    bf16* __restrict__ x1)
{
  __shared__ float y[ND];
  __shared__ float rbuf[256];
  const int tid = threadIdx.x;
  const size_t base = (size_t)blockIdx.x * ND;
  const float sig = 1.f / (1.f + __expf(-lam[0]));
  const float c1 = 1.f - sig;
  float s1 = 0.f, s2 = 0.f;
  #pragma unroll
  for (int j = 0; j < 4; ++j) {
    const int i = tid + (j << 8);
    const float v = src[base + i] + sig * dense[base + i] + c1 * sparse[base + i];
    y[i] = v; s1 += v; s2 += v * v;
  }
  const float sum1 = block_sum_256(s1, rbuf, tid);
  const float sum2 = block_sum_256(s2, rbuf, tid);
  const float mean = sum1 * (1.f / ND);
  const float var  = sum2 * (1.f / ND) - mean * mean;
  const float rstd = rsqrtf(var + 1e-5f);
  #pragma unroll
  for (int j = 0; j < 4; ++j) {
    const int i = tid + (j << 8);
    x1[base + i] = f2b((y[i] - mean) * rstd * g[i] + beta[i]);
  }
}

// out = LN2(x1 + ff)  (fp32 out)
__global__ __launch_bounds__(256) void ln2_kernel(
    const bf16* __restrict__ x1, const float* __restrict__ ff,
    const float* __restrict__ g, const float* __restrict__ beta,
    float* __restrict__ outp)
{
  __shared__ float y[ND];
  __shared__ float rbuf[256];
  const int tid = threadIdx.x;
  const size_t base = (size_t)blockIdx.x * ND;
  float s1 = 0.f, s2 = 0.f;
  #pragma unroll
  for (int j = 0; j < 4; ++j) {
    const int i = tid + (j << 8);
    const float v = b2f(x1[base + i]) + ff[base + i];
    y[i] = v; s1 += v; s2 += v * v;
  }
  const float sum1 = block_sum_256(s1, rbuf, tid);
  const float sum2 = block_sum_256(s2, rbuf, tid);
  const float mean = sum1 * (1.f / ND);
  const float var  = sum2 * (1.f / ND) - mean * mean;
  const float rstd = rsqrtf(var + 1e-5f);
  #pragma unroll
  for (int j = 0; j < 4; ++j) {
    const int i = tid + (j << 8);
    outp[base + i] = (y[i] - mean) * rstd * g[i] + beta[i];
  }
}

// ---------------------------------------------------------------------------
extern "C" void kernel_launch(void* const* d_in, const int* in_sizes, int n_in,
                              void* d_out, int out_size, void* d_ws, size_t ws_size,
                              hipStream_t stream)
{
  const float* src        = (const float*)d_in[0];
  const float* in_proj_w  = (const float*)d_in[1];
  const float* in_proj_b  = (const float*)d_in[2];
  const float* out_proj_w = (const float*)d_in[3];
  const float* out_proj_b = (const float*)d_in[4];
  const float* Qp_w = (const float*)d_in[5];
  const float* Qp_b = (const float*)d_in[6];
  const float* Kp_w = (const float*)d_in[7];
  const float* Kp_b = (const float*)d_in[8];
  const float* Vp_w = (const float*)d_in[9];
  const float* Vp_b = (const float*)d_in[10];
  const float* lam  = (const float*)d_in[11];
  const float* ff1_w = (const float*)d_in[12];
  const float* ff1_b = (const float*)d_in[13];
  const float* ff2_w = (const float*)d_in[14];
  const float* ff2_b = (const float*)d_in[15];
  const float* ln1_g = (const float*)d_in[16];
  const float* ln1_b = (const float*)d_in[17];
  const float* ln2_g = (const float*)d_in[18];
  const float* ln2_b = (const float*)d_in[19];
  (void)in_sizes; (void)n_in; (void)out_size; (void)ws_size;

  char* ws = (char*)d_ws;
  size_t off = 0;
  auto take = [&](size_t bytes) -> void* {
    void* p = ws + off; off += (bytes + 255) & ~(size_t)255; return p;
  };
  bf16*  qkv    = (bf16*) take((size_t)NM * 3 * ND * 2);  // 25.2 MB
  bf16*  ctx    = (bf16*) take((size_t)NM * ND * 2);      //  8.4 MB
  float* dense  = (float*)take((size_t)NM * ND * 4);      // 16.8 MB
  float* Qsp    = (float*)take((size_t)NM * NR * 4);      //  1.0 MB
  float* Ksp    = (float*)take((size_t)NM * NR * 4);      //  1.0 MB
  bf16*  Vsp    = (bf16*) take((size_t)NM * ND * 2);      //  8.4 MB
  float* sparse = (float*)take((size_t)NM * ND * 4);      // 16.8 MB
  bf16*  x1     = (bf16*) take((size_t)NM * ND * 2);      //  8.4 MB
  bf16*  h1     = (bf16*) take((size_t)NM * NDFF * 2);    // 33.6 MB
  float* ffout  = (float*)take((size_t)NM * ND * 4);      // 16.8 MB  (total ~136 MB)

  const dim3 blk(256);
  // 1. qkv = src @ in_proj_w^T + b          [4096,3072] (bf16 out)
  gemm_kernel<1,0,0><<<dim3(3*ND/64, NM/64), blk, 0, stream>>>(src, in_proj_w, in_proj_b, (void*)qkv, NM, 3*ND, ND);
  // 2. dense multi-head attention -> ctx (bf16)
  attn_dense_kernel<<<dim3(NS/16, NH, NB), blk, 0, stream>>>(qkv, ctx);
  // 3. dense_output = ctx @ out_proj^T + b  (fp32)
  gemm_kernel<0,0,1><<<dim3(ND/64, NM/64), blk, 0, stream>>>(ctx, out_proj_w, out_proj_b, (void*)dense, NM, ND, ND);
  // 4/5. low-rank projections Q,K (fp32)
  gemm_kernel<1,0,1><<<dim3(NR/64, NM/64), blk, 0, stream>>>(src, Qp_w, Qp_b, (void*)Qsp, NM, NR, ND);
  gemm_kernel<1,0,1><<<dim3(NR/64, NM/64), blk, 0, stream>>>(src, Kp_w, Kp_b, (void*)Ksp, NM, NR, ND);
  // 6. V projection (bf16)
  gemm_kernel<1,0,0><<<dim3(ND/64, NM/64), blk, 0, stream>>>(src, Vp_w, Vp_b, (void*)Vsp, NM, ND, ND);
  // 7. top-k sparse attention (fp32 out)
  sparse_attn_kernel<<<dim3(NS, NB), blk, 0, stream>>>(Qsp, Ksp, Vsp, sparse);
  // 8. fuse + residual + LN1 -> x1 (bf16)
  fuse_ln1_kernel<<<dim3(NM), blk, 0, stream>>>(src, dense, sparse, lam, ln1_g, ln1_b, x1);
  // 9. h1 = relu(x1 @ ff1^T + b)  (bf16)
  gemm_kernel<0,1,0><<<dim3(NDFF/64, NM/64), blk, 0, stream>>>(x1, ff1_w, ff1_b, (void*)h1, NM, NDFF, ND);
  // 10. ff = h1 @ ff2^T + b  (fp32)
  gemm_kernel<0,0,1><<<dim3(ND/64, NM/64), blk, 0, stream>>>(h1, ff2_w, ff2_b, (void*)ffout, NM, ND, NDFF);
  // 11. out = LN2(x1 + ff)  (fp32)
  ln2_kernel<<<dim3(NM), blk, 0, stream>>>(x1, ffout, ln2_g, ln2_b, (float*)d_out);
}

// Round 4
// 1760.237 us; speedup vs baseline: 2.3081x; 2.3081x over previous
//
#include <hip/hip_runtime.h>
#include <hip/hip_bf16.h>
#include <math.h>

typedef __hip_bfloat16 bf16;
typedef __attribute__((ext_vector_type(8))) short short8;
typedef __attribute__((ext_vector_type(4))) float f32x4;

// Problem constants
#define NB 4
#define NS 1024
#define ND 1024
#define NH 16
#define NDH 64
#define NR 64
#define NDFF 4096
#define NM (NB*NS)     // 4096 rows
#define NTOPK 204      // int(1024*0.2)

static __device__ __forceinline__ float b2f(bf16 x) { return __bfloat162float(x); }
static __device__ __forceinline__ bf16  f2b(float x) { return __float2bfloat16(x); }
static __device__ __forceinline__ unsigned short bfbits(float x) {
  bf16 h = __float2bfloat16(x);
  return *reinterpret_cast<unsigned short*>(&h);
}

// 8 consecutive bf16 -> fp32 (one 16B load)
static __device__ __forceinline__ void ld8(const bf16* p, float* d) {
  const uint4 u = *(const uint4*)p;
  d[0] = __uint_as_float((u.x & 0xffffu) << 16);
  d[1] = __uint_as_float(u.x & 0xffff0000u);
  d[2] = __uint_as_float((u.y & 0xffffu) << 16);
  d[3] = __uint_as_float(u.y & 0xffff0000u);
  d[4] = __uint_as_float((u.z & 0xffffu) << 16);
  d[5] = __uint_as_float(u.z & 0xffff0000u);
  d[6] = __uint_as_float((u.w & 0xffffu) << 16);
  d[7] = __uint_as_float(u.w & 0xffff0000u);
}

static __device__ __forceinline__ float block_sum_256(float v, float* rbuf, int tid) {
  rbuf[tid] = v;
  __syncthreads();
  #pragma unroll
  for (int st = 128; st > 0; st >>= 1) {
    if (tid < st) rbuf[tid] += rbuf[tid + st];
    __syncthreads();
  }
  const float r = rbuf[0];
  __syncthreads();
  return r;
}

// ---------------------------------------------------------------------------
// fp32 -> bf16 cast (n multiple of 4)
// ---------------------------------------------------------------------------
__global__ __launch_bounds__(256) void cast_kernel(const float* __restrict__ in,
                                                   bf16* __restrict__ out, int n) {
  const int i = (blockIdx.x * 256 + threadIdx.x) * 4;
  if (i < n) {
    const float4 v = *(const float4*)(in + i);
    uint2 o;
    o.x = (unsigned)bfbits(v.x) | ((unsigned)bfbits(v.y) << 16);
    o.y = (unsigned)bfbits(v.z) | ((unsigned)bfbits(v.w) << 16);
    *(uint2*)(out + i) = o;
  }
}

// Concat Qp_w/Kp_w -> bf16 [128][1024], Qp_b/Kp_b -> fp32 [128]
__global__ __launch_bounds__(256) void pack_qk_kernel(
    const float* __restrict__ Qw, const float* __restrict__ Kw,
    const float* __restrict__ Qb, const float* __restrict__ Kb,
    bf16* __restrict__ w, float* __restrict__ bias) {
  const int r = blockIdx.x;  // 0..127
  const float* srcw = (r < 64) ? (Qw + (size_t)r * ND) : (Kw + (size_t)(r - 64) * ND);
  for (int i = threadIdx.x; i < ND; i += 256) w[(size_t)r * ND + i] = f2b(srcw[i]);
  if (r == 0)
    for (int i = threadIdx.x; i < 128; i += 256)
      bias[i] = (i < 64) ? Qb[i] : Kb[i - 64];
}

// ---------------------------------------------------------------------------
// Generic batched MFMA GEMM: C[m][n] = scale * sum_k A[m][k]*W[n][k] (+bias[n])
// A, W bf16 row-major, strides lda/ldb; batch z: off = (z>>4)*Hi + (z&15)*Lo.
// 256 threads = 4 waves; BMxBN tile with BM*BN == 4*64*64; wave = 64x64 via
// 4x4 grid of 16x16x32 MFMAs; BK=32. LDS rows padded to 40 bf16 (80 B) ->
// ds_read_b128 is 2-way bank-aliased only (free on CDNA4).
// ---------------------------------------------------------------------------
template<int BM, int BN, int BIAS, int RELU, int OUTF32>
__global__ __launch_bounds__(256) void mfma_gemm(
    const bf16* __restrict__ A, const bf16* __restrict__ W,
    const float* __restrict__ bias, void* __restrict__ C,
    int K, int lda, int ldb, int ldc,
    long long aHi, long long aLo, long long bHi, long long bLo,
    long long cHi, long long cLo, float scale)
{
  constexpr int LDT = 40;
  __shared__ short As[BM * LDT];
  __shared__ short Bs[BN * LDT];
  const int tid  = threadIdx.x;
  const int lane = tid & 63;
  const int w    = tid >> 6;
  const int z    = blockIdx.z;
  const long long aOff = (long long)(z >> 4) * aHi + (long long)(z & 15) * aLo;
  const long long bOff = (long long)(z >> 4) * bHi + (long long)(z & 15) * bLo;
  const long long cOff = (long long)(z >> 4) * cHi + (long long)(z & 15) * cLo;
  const int m0 = blockIdx.y * BM;
  const int n0 = blockIdx.x * BN;
  constexpr int WN = BN / 64;
  const int wr = w / WN, wc = w % WN;
  const int lm = lane & 15, quad = lane >> 4;

  f32x4 acc[4][4];
  #pragma unroll
  for (int i = 0; i < 4; ++i)
    #pragma unroll
    for (int j = 0; j < 4; ++j) acc[i][j] = (f32x4){0.f, 0.f, 0.f, 0.f};

  const int sr = tid >> 2;        // 0..63
  const int sc = (tid & 3) << 3;  // 0,8,16,24
  const bf16* Ab = A + aOff;
  const bf16* Bb = W + bOff;

  for (int k0 = 0; k0 < K; k0 += 32) {
    uint4 ar[BM / 64], br[BN / 64];
    #pragma unroll
    for (int it = 0; it < BM / 64; ++it)
      ar[it] = *(const uint4*)(Ab + (long long)(m0 + it * 64 + sr) * lda + k0 + sc);
    #pragma unroll
    for (int it = 0; it < BN / 64; ++it)
      br[it] = *(const uint4*)(Bb + (long long)(n0 + it * 64 + sr) * ldb + k0 + sc);
    __syncthreads();   // previous iter's LDS reads complete
    #pragma unroll
    for (int it = 0; it < BM / 64; ++it)
      *(uint4*)&As[(it * 64 + sr) * LDT + sc] = ar[it];
    #pragma unroll
    for (int it = 0; it < BN / 64; ++it)
      *(uint4*)&Bs[(it * 64 + sr) * LDT + sc] = br[it];
    __syncthreads();
    short8 af[4], bfr[4];
    #pragma unroll
    for (int i = 0; i < 4; ++i)
      af[i] = *(const short8*)&As[(wr * 64 + i * 16 + lm) * LDT + quad * 8];
    #pragma unroll
    for (int j = 0; j < 4; ++j)
      bfr[j] = *(const short8*)&Bs[(wc * 64 + j * 16 + lm) * LDT + quad * 8];
    #pragma unroll
    for (int i = 0; i < 4; ++i)
      #pragma unroll
      for (int j = 0; j < 4; ++j)
        acc[i][j] = __builtin_amdgcn_mfma_f32_16x16x32_bf16(af[i], bfr[j], acc[i][j], 0, 0, 0);
  }

  #pragma unroll
  for (int i = 0; i < 4; ++i) {
    #pragma unroll
    for (int j = 0; j < 4; ++j) {
      const int n = n0 + wc * 64 + j * 16 + lm;
      const float bj = BIAS ? bias[n] : 0.f;
      #pragma unroll
      for (int rr = 0; rr < 4; ++rr) {
        const int m = m0 + wr * 64 + i * 16 + quad * 4 + rr;
        float v = acc[i][j][rr] * scale + bj;
        if (RELU) v = fmaxf(v, 0.f);
        const long long co = cOff + (long long)m * ldc + n;
        if (OUTF32) ((float*)C)[co] = v;
        else        ((bf16*)C)[co] = f2b(v);
      }
    }
  }
}

// ---------------------------------------------------------------------------
// Row softmax in place over bf16 [rows][1024]; one wave per row.
// ---------------------------------------------------------------------------
__global__ __launch_bounds__(256) void softmax_kernel(bf16* __restrict__ P) {
  const int tid = threadIdx.x;
  const int lane = tid & 63;
  const int w = tid >> 6;
  const long long row = (long long)blockIdx.x * 4 + w;
  bf16* p = P + row * 1024 + lane * 16;
  float v[16];
  ld8(p, v); ld8(p + 8, v + 8);
  float m = v[0];
  #pragma unroll
  for (int t = 1; t < 16; ++t) m = fmaxf(m, v[t]);
  #pragma unroll
  for (int s = 1; s < 64; s <<= 1) m = fmaxf(m, __shfl_xor(m, s, 64));
  float sum = 0.f;
  #pragma unroll
  for (int t = 0; t < 16; ++t) { v[t] = __expf(v[t] - m); sum += v[t]; }
  #pragma unroll
  for (int s = 1; s < 64; s <<= 1) sum += __shfl_xor(sum, s, 64);
  const float inv = 1.f / sum;
  uint4 o0, o1;
  o0.x = (unsigned)bfbits(v[0]*inv)  | ((unsigned)bfbits(v[1]*inv)  << 16);
  o0.y = (unsigned)bfbits(v[2]*inv)  | ((unsigned)bfbits(v[3]*inv)  << 16);
  o0.z = (unsigned)bfbits(v[4]*inv)  | ((unsigned)bfbits(v[5]*inv)  << 16);
  o0.w = (unsigned)bfbits(v[6]*inv)  | ((unsigned)bfbits(v[7]*inv)  << 16);
  o1.x = (unsigned)bfbits(v[8]*inv)  | ((unsigned)bfbits(v[9]*inv)  << 16);
  o1.y = (unsigned)bfbits(v[10]*inv) | ((unsigned)bfbits(v[11]*inv) << 16);
  o1.z = (unsigned)bfbits(v[12]*inv) | ((unsigned)bfbits(v[13]*inv) << 16);
  o1.w = (unsigned)bfbits(v[14]*inv) | ((unsigned)bfbits(v[15]*inv) << 16);
  ((uint4*)p)[0] = o0; ((uint4*)p)[1] = o1;
}

// ---------------------------------------------------------------------------
// Per-batch: Vt_b[h][d][s] = qkv_b[s, 2048 + h*64 + d]  (64x64 LDS transpose)
// ---------------------------------------------------------------------------
__global__ __launch_bounds__(256) void transpose_v_kernel(
    const bf16* __restrict__ qkv_b, bf16* __restrict__ Vt_b) {
  __shared__ short T[64][72];
  const int tid = threadIdx.x;
  const int h = blockIdx.y;
  const int s0 = blockIdx.x * 64;
  const bf16* src = qkv_b + (long long)s0 * 3072 + 2 * ND + h * 64;
  {
    const int s = tid >> 2, c = (tid & 3) * 16;
    const uint4 a0 = *(const uint4*)(src + (long long)s * 3072 + c);
    const uint4 a1 = *(const uint4*)(src + (long long)s * 3072 + c + 8);
    *(uint4*)&T[s][c] = a0; *(uint4*)&T[s][c + 8] = a1;
  }
  __syncthreads();
  {
    const int d = tid >> 2, c = (tid & 3) * 16;
    unsigned wds[8];
    #pragma unroll
    for (int u = 0; u < 8; ++u) {
      const unsigned lo = (unsigned short)T[c + 2 * u][d];
      const unsigned hi = (unsigned short)T[c + 2 * u + 1][d];
      wds[u] = lo | (hi << 16);
    }
    bf16* dst = Vt_b + (long long)h * (NDH * NS) + (long long)d * NS + s0 + c;
    uint4 o0, o1;
    o0.x = wds[0]; o0.y = wds[1]; o0.z = wds[2]; o0.w = wds[3];
    o1.x = wds[4]; o1.y = wds[5]; o1.z = wds[6]; o1.w = wds[7];
    ((uint4*)dst)[0] = o0; ((uint4*)dst)[1] = o1;
  }
}

// ---------------------------------------------------------------------------
// Low-rank top-k sparse attention (QKs fp32 [4096][128]: Q cols 0..63, K 64..127)
// bf16 output.
// ---------------------------------------------------------------------------
__global__ __launch_bounds__(256) void sparse_attn_kernel(
    const float* __restrict__ QKs, const bf16* __restrict__ Vs,
    bf16* __restrict__ outp)
{
  __shared__ float qrow[64];
  __shared__ float sorig[1024];
  __shared__ float ssort[1024];
  __shared__ float wts[1024];
  __shared__ float rbuf[256];
  const int tid = threadIdx.x;
  const int b = blockIdx.y, qi = blockIdx.x;

  if (tid < 64) qrow[tid] = QKs[((size_t)(b * NS + qi)) * 128 + tid];
  __syncthreads();

  #pragma unroll
  for (int j = 0; j < 4; ++j) {
    const int k = tid + (j << 8);
    const float4* kp = (const float4*)(QKs + ((size_t)(b * NS + k)) * 128 + 64);
    float s = 0.f;
    #pragma unroll
    for (int c = 0; c < 16; ++c) {
      const float4 qa = *(const float4*)&qrow[c << 2];
      const float4 ka = kp[c];
      s += qa.x * ka.x + qa.y * ka.y + qa.z * ka.z + qa.w * ka.w;
    }
    s *= 0.125f;
    sorig[k] = s; ssort[k] = s;
  }

  for (int size = 2; size <= 1024; size <<= 1) {
    for (int stride = size >> 1; stride > 0; stride >>= 1) {
      __syncthreads();
      #pragma unroll
      for (int t = 0; t < 4; ++t) {
        const int i = tid + (t << 8);
        const int j2 = i ^ stride;
        if (j2 > i) {
          const float x = ssort[i], y = ssort[j2];
          const bool desc = ((i & size) == 0);
          if (desc ? (x < y) : (x > y)) { ssort[i] = y; ssort[j2] = x; }
        }
      }
    }
  }
  __syncthreads();
  const float thr = ssort[NTOPK - 1];
  const float mx  = ssort[0];

  float psTop = 0.f, psAll = 0.f;
  #pragma unroll
  for (int j = 0; j < 4; ++j) {
    const int k = tid + (j << 8);
    const float s = sorig[k];
    const float e = __expf(s - mx);
    psAll += e;
    const float w = (s >= thr) ? e : 0.f;
    psTop += w;
    wts[k] = w;
  }
  const float sumTop = block_sum_256(psTop, rbuf, tid);
  const float sumAll = block_sum_256(psAll, rbuf, tid);
  const float inv = 1.f / (sumTop + 1e-9f * sumAll);

  float a0 = 0.f, a1 = 0.f, a2 = 0.f, a3 = 0.f;
  const bf16* vb = Vs + (size_t)b * NS * ND + tid;
  for (int k = 0; k < 1024; ++k) {
    const float w = wts[k];
    if (w > 0.f) {
      const bf16* vp = vb + (size_t)k * ND;
      a0 += w * b2f(vp[0]);
      a1 += w * b2f(vp[256]);
      a2 += w * b2f(vp[512]);
      a3 += w * b2f(vp[768]);
    }
  }
  bf16* op = outp + ((size_t)(b * NS + qi)) * ND + tid;
  op[0] = f2b(a0 * inv); op[256] = f2b(a1 * inv);
  op[512] = f2b(a2 * inv); op[768] = f2b(a3 * inv);
}

// ---------------------------------------------------------------------------
// fused = sig*dense + (1-sig)*sparse ; x1 = LN1(src + fused)  (bf16 out)
// ---------------------------------------------------------------------------
__global__ __launch_bounds__(256) void fuse_ln1_kernel(
    const float* __restrict__ src, const bf16* __restrict__ dense,
    const bf16* __restrict__ sparse, const float* __restrict__ lam,
    const float* __restrict__ g, const float* __restrict__ beta,
    bf16* __restrict__ x1)
{
  __shared__ float y[ND];
  __shared__ float rbuf[256];
  const int tid = threadIdx.x;
  const size_t base = (size_t)blockIdx.x * ND;
  const float sig = 1.f / (1.f + __expf(-lam[0]));
  const float c1 = 1.f - sig;
  float s1 = 0.f, s2 = 0.f;
  #pragma unroll
  for (int j = 0; j < 4; ++j) {
    const int i = tid + (j << 8);
    const float v = src[base + i] + sig * b2f(dense[base + i]) + c1 * b2f(sparse[base + i]);
    y[i] = v; s1 += v; s2 += v * v;
  }
  const float sum1 = block_sum_256(s1, rbuf, tid);
  const float sum2 = block_sum_256(s2, rbuf, tid);
  const float mean = sum1 * (1.f / ND);
  const float var  = sum2 * (1.f / ND) - mean * mean;
  const float rstd = rsqrtf(var + 1e-5f);
  #pragma unroll
  for (int j = 0; j < 4; ++j) {
    const int i = tid + (j << 8);
    x1[base + i] = f2b((y[i] - mean) * rstd * g[i] + beta[i]);
  }
}

// out = LN2(x1 + ff)  (fp32 out; ff is bf16)
__global__ __launch_bounds__(256) void ln2_kernel(
    const bf16* __restrict__ x1, const bf16* __restrict__ ff,
    const float* __restrict__ g, const float* __restrict__ beta,
    float* __restrict__ outp)
{
  __shared__ float y[ND];
  __shared__ float rbuf[256];
  const int tid = threadIdx.x;
  const size_t base = (size_t)blockIdx.x * ND;
  float s1 = 0.f, s2 = 0.f;
  #pragma unroll
  for (int j = 0; j < 4; ++j) {
    const int i = tid + (j << 8);
    const float v = b2f(x1[base + i]) + b2f(ff[base + i]);
    y[i] = v; s1 += v; s2 += v * v;
  }
  const float sum1 = block_sum_256(s1, rbuf, tid);
  const float sum2 = block_sum_256(s2, rbuf, tid);
  const float mean = sum1 * (1.f / ND);
  const float var  = sum2 * (1.f / ND) - mean * mean;
  const float rstd = rsqrtf(var + 1e-5f);
  #pragma unroll
  for (int j = 0; j < 4; ++j) {
    const int i = tid + (j << 8);
    outp[base + i] = (y[i] - mean) * rstd * g[i] + beta[i];
  }
}

// ---------------------------------------------------------------------------
extern "C" void kernel_launch(void* const* d_in, const int* in_sizes, int n_in,
                              void* d_out, int out_size, void* d_ws, size_t ws_size,
                              hipStream_t stream)
{
  const float* src        = (const float*)d_in[0];
  const float* in_proj_w  = (const float*)d_in[1];
  const float* in_proj_b  = (const float*)d_in[2];
  const float* out_proj_w = (const float*)d_in[3];
  const float* out_proj_b = (const float*)d_in[4];
  const float* Qp_w  = (const float*)d_in[5];
  const float* Qp_b  = (const float*)d_in[6];
  const float* Kp_w  = (const float*)d_in[7];
  const float* Kp_b  = (const float*)d_in[8];
  const float* Vp_w  = (const float*)d_in[9];
  const float* Vp_b  = (const float*)d_in[10];
  const float* lam   = (const float*)d_in[11];
  const float* ff1_w = (const float*)d_in[12];
  const float* ff1_b = (const float*)d_in[13];
  const float* ff2_w = (const float*)d_in[14];
  const float* ff2_b = (const float*)d_in[15];
  const float* ln1_g = (const float*)d_in[16];
  const float* ln1_b = (const float*)d_in[17];
  const float* ln2_g = (const float*)d_in[18];
  const float* ln2_b = (const float*)d_in[19];
  (void)in_sizes; (void)n_in; (void)out_size; (void)ws_size;

  // --------- workspace layout (total ~132.5 MB; round-2's 136.3 MB is proven safe)
  char* ws = (char*)d_ws;
  size_t off = 0;
  auto take = [&](size_t bytes) -> void* {
    void* p = ws + off; off += (bytes + 255) & ~(size_t)255; return p;
  };
  bf16*  src_bf  = (bf16*) take((size_t)NM * ND * 2);          //  8.4 MB
  bf16*  w_qkv   = (bf16*) take((size_t)3 * ND * ND * 2);      //  6.3 MB
  bf16*  w_out   = (bf16*) take((size_t)ND * ND * 2);          //  2.1 MB
  bf16*  w_vp    = (bf16*) take((size_t)ND * ND * 2);          //  2.1 MB
  bf16*  w_ff1   = (bf16*) take((size_t)NDFF * ND * 2);        //  8.4 MB
  bf16*  w_ff2   = (bf16*) take((size_t)ND * NDFF * 2);        //  8.4 MB
  bf16*  w_qk    = (bf16*) take((size_t)128 * ND * 2);         //  0.26 MB
  float* bias_qk = (float*)take(128 * 4);
  const size_t mark = off;                                     // reuse point
  bf16*  qkv     = (bf16*) take((size_t)NM * 3 * ND * 2);      // 25.2 MB [dead after attn]
  bf16*  S_b     = (bf16*) take((size_t)NH * NS * NS * 2);     // 33.5 MB [dead after attn]
  bf16*  Vt_b    = (bf16*) take((size_t)NH * NDH * NS * 2);    //  2.1 MB [dead after attn]
  bf16*  ctx     = (bf16*) take((size_t)NM * ND * 2);          //  8.4 MB
  bf16*  dense   = (bf16*) take((size_t)NM * ND * 2);          //  8.4 MB
  float* QKs     = (float*)take((size_t)NM * 128 * 4);         //  2.1 MB
  bf16*  Vsp     = (bf16*) take((size_t)NM * ND * 2);          //  8.4 MB
  bf16*  sparse  = (bf16*) take((size_t)NM * ND * 2);          //  8.4 MB
  // aliased into qkv+S_b region (both dead by the time these are written):
  bf16*  x1      = (bf16*)(ws + mark);                                   //  8.4 MB
  bf16*  h1      = (bf16*)(ws + mark + (size_t)NM * ND * 2);             // 33.6 MB
  bf16*  ffout   = (bf16*)(ws + mark + (size_t)NM * ND * 2 + (size_t)NM * NDFF * 2); // 8.4 MB
  // x1+h1+ffout = 50.4 MB  <  qkv+S_b = 58.7 MB  ✓

  const dim3 blk(256);
  auto cast = [&](const float* in, bf16* out, int n) {
    cast_kernel<<<dim3((n + 1023) / 1024), blk, 0, stream>>>(in, out, n);
  };
  // 0. fp32 -> bf16 conversions
  cast(src,        src_bf, NM * ND);
  cast(in_proj_w,  w_qkv,  3 * ND * ND);
  cast(out_proj_w, w_out,  ND * ND);
  cast(Vp_w,       w_vp,   ND * ND);
  cast(ff1_w,      w_ff1,  NDFF * ND);
  cast(ff2_w,      w_ff2,  ND * NDFF);
  pack_qk_kernel<<<dim3(128), blk, 0, stream>>>(Qp_w, Kp_w, Qp_b, Kp_b, w_qk, bias_qk);

  // 1. qkv = src @ in_proj^T + b   [4096,3072] bf16
  mfma_gemm<128,128,1,0,0><<<dim3(3*ND/128, NM/128, 1), blk, 0, stream>>>(
      src_bf, w_qkv, in_proj_b, qkv, ND, ND, ND, 3*ND, 0,0, 0,0, 0,0, 1.f);

  // 2. dense MHA, per batch (S_b / Vt_b reused across b)
  for (int b = 0; b < NB; ++b) {
    const bf16* qkv_b = qkv + (size_t)b * NS * 3 * ND;
    // 2a. S_b[h] = (Q K^T)/8, batched over 16 heads
    mfma_gemm<128,128,0,0,0><<<dim3(NS/128, NS/128, NH), blk, 0, stream>>>(
        qkv_b, qkv_b + ND, nullptr, S_b, NDH, 3*ND, 3*ND, NS,
        0, NDH, 0, NDH, 0, (long long)NS*NS, 0.125f);
    // 2b. softmax rows in place
    softmax_kernel<<<dim3(NH*NS/4), blk, 0, stream>>>(S_b);
    // 2c. Vt_b[h][d][s]
    transpose_v_kernel<<<dim3(NS/64, NH), blk, 0, stream>>>(qkv_b, Vt_b);
    // 2d. ctx_b = P @ V (256x64 tiles; BM*BN must equal 4 waves * 64*64)
    mfma_gemm<256,64,0,0,0><<<dim3(1, NS/256, NH), blk, 0, stream>>>(
        S_b, Vt_b, nullptr, ctx + (size_t)b * NS * ND, NS, NS, NS, ND,
        0, (long long)NS*NS, 0, (long long)NDH*NS, 0, NDH, 1.f);
  }

  // 3. dense_output = ctx @ out_proj^T + b  (bf16)
  mfma_gemm<128,128,1,0,0><<<dim3(ND/128, NM/128, 1), blk, 0, stream>>>(
      ctx, w_out, out_proj_b, dense, ND, ND, ND, ND, 0,0, 0,0, 0,0, 1.f);
  // 4. QKs = src @ [Qp;Kp]^T + b  (fp32 [4096][128])
  mfma_gemm<128,128,1,0,1><<<dim3(1, NM/128, 1), blk, 0, stream>>>(
      src_bf, w_qk, bias_qk, QKs, ND, ND, ND, 128, 0,0, 0,0, 0,0, 1.f);
  // 5. Vsp = src @ Vp^T + b  (bf16)
  mfma_gemm<128,128,1,0,0><<<dim3(ND/128, NM/128, 1), blk, 0, stream>>>(
      src_bf, w_vp, Vp_b, Vsp, ND, ND, ND, ND, 0,0, 0,0, 0,0, 1.f);
  // 6. top-k sparse attention (bf16 out)
  sparse_attn_kernel<<<dim3(NS, NB), blk, 0, stream>>>(QKs, Vsp, sparse);
  // 7. fuse + residual + LN1 -> x1 (bf16)  [qkv/S_b dead; x1 aliases them]
  fuse_ln1_kernel<<<dim3(NM), blk, 0, stream>>>(src, dense, sparse, lam, ln1_g, ln1_b, x1);
  // 8. h1 = relu(x1 @ ff1^T + b)  (bf16)
  mfma_gemm<128,128,1,1,0><<<dim3(NDFF/128, NM/128, 1), blk, 0, stream>>>(
      x1, w_ff1, ff1_b, h1, ND, ND, ND, NDFF, 0,0, 0,0, 0,0, 1.f);
  // 9. ff = h1 @ ff2^T + b  (bf16)
  mfma_gemm<128,128,1,0,0><<<dim3(ND/128, NM/128, 1), blk, 0, stream>>>(
      h1, w_ff2, ff2_b, ffout, NDFF, NDFF, NDFF, ND, 0,0, 0,0, 0,0, 1.f);
  // 10. out = LN2(x1 + ff)  (fp32)
  ln2_kernel<<<dim3(NM), blk, 0, stream>>>(x1, ffout, ln2_g, ln2_b, (float*)d_out);
}

// Round 5
// 1461.153 us; speedup vs baseline: 2.7805x; 1.2047x over previous
//
#include <hip/hip_runtime.h>
#include <hip/hip_bf16.h>
#include <math.h>

typedef __hip_bfloat16 bf16;
typedef __attribute__((ext_vector_type(8))) short short8;
typedef __attribute__((ext_vector_type(4))) float f32x4;

// Problem constants
#define NB 4
#define NS 1024
#define ND 1024
#define NH 16
#define NDH 64
#define NR 64
#define NDFF 4096
#define NM (NB*NS)     // 4096 rows
#define NTOPK 204      // int(1024*0.2)

static __device__ __forceinline__ float b2f(bf16 x) { return __bfloat162float(x); }
static __device__ __forceinline__ bf16  f2b(float x) { return __float2bfloat16(x); }
static __device__ __forceinline__ unsigned short bfbits(float x) {
  bf16 h = __float2bfloat16(x);
  return *reinterpret_cast<unsigned short*>(&h);
}

// 8 consecutive bf16 -> fp32 (one 16B load)
static __device__ __forceinline__ void ld8(const bf16* p, float* d) {
  const uint4 u = *(const uint4*)p;
  d[0] = __uint_as_float((u.x & 0xffffu) << 16);
  d[1] = __uint_as_float(u.x & 0xffff0000u);
  d[2] = __uint_as_float((u.y & 0xffffu) << 16);
  d[3] = __uint_as_float(u.y & 0xffff0000u);
  d[4] = __uint_as_float((u.z & 0xffffu) << 16);
  d[5] = __uint_as_float(u.z & 0xffff0000u);
  d[6] = __uint_as_float((u.w & 0xffffu) << 16);
  d[7] = __uint_as_float(u.w & 0xffff0000u);
}

static __device__ __forceinline__ float block_sum_256(float v, float* rbuf, int tid) {
  rbuf[tid] = v;
  __syncthreads();
  #pragma unroll
  for (int st = 128; st > 0; st >>= 1) {
    if (tid < st) rbuf[tid] += rbuf[tid + st];
    __syncthreads();
  }
  const float r = rbuf[0];
  __syncthreads();
  return r;
}

// ---------------------------------------------------------------------------
// fp32 -> bf16 cast (n multiple of 4)
// ---------------------------------------------------------------------------
__global__ __launch_bounds__(256) void cast_kernel(const float* __restrict__ in,
                                                   bf16* __restrict__ out, int n) {
  const int i = (blockIdx.x * 256 + threadIdx.x) * 4;
  if (i < n) {
    const float4 v = *(const float4*)(in + i);
    uint2 o;
    o.x = (unsigned)bfbits(v.x) | ((unsigned)bfbits(v.y) << 16);
    o.y = (unsigned)bfbits(v.z) | ((unsigned)bfbits(v.w) << 16);
    *(uint2*)(out + i) = o;
  }
}

// Concat Qp_w/Kp_w -> bf16 [128][1024], Qp_b/Kp_b -> fp32 [128]
__global__ __launch_bounds__(256) void pack_qk_kernel(
    const float* __restrict__ Qw, const float* __restrict__ Kw,
    const float* __restrict__ Qb, const float* __restrict__ Kb,
    bf16* __restrict__ w, float* __restrict__ bias) {
  const int r = blockIdx.x;  // 0..127
  const float* srcw = (r < 64) ? (Qw + (size_t)r * ND) : (Kw + (size_t)(r - 64) * ND);
  for (int i = threadIdx.x; i < ND; i += 256) w[(size_t)r * ND + i] = f2b(srcw[i]);
  if (r == 0)
    for (int i = threadIdx.x; i < 128; i += 256)
      bias[i] = (i < 64) ? Qb[i] : Kb[i - 64];
}

// ---------------------------------------------------------------------------
// Generic batched MFMA GEMM: C[m][n] = scale * sum_k A[m][k]*W[n][k] (+bias[n])
// A, W bf16 row-major, strides lda/ldb; batch z: off = (z>>4)*Hi + (z&15)*Lo.
// 256 threads = 4 waves; BMxBN tile with BM*BN == 4*64*64; wave = 64x64 via
// 4x4 grid of 16x16x32 MFMAs; BK=32. LDS rows padded to 40 bf16 (80 B) ->
// ds_read_b128 is 2-way bank-aliased only (free on CDNA4).
// ---------------------------------------------------------------------------
template<int BM, int BN, int BIAS, int RELU, int OUTF32>
__global__ __launch_bounds__(256) void mfma_gemm(
    const bf16* __restrict__ A, const bf16* __restrict__ W,
    const float* __restrict__ bias, void* __restrict__ C,
    int K, int lda, int ldb, int ldc,
    long long aHi, long long aLo, long long bHi, long long bLo,
    long long cHi, long long cLo, float scale)
{
  constexpr int LDT = 40;
  __shared__ short As[BM * LDT];
  __shared__ short Bs[BN * LDT];
  const int tid  = threadIdx.x;
  const int lane = tid & 63;
  const int w    = tid >> 6;
  const int z    = blockIdx.z;
  const long long aOff = (long long)(z >> 4) * aHi + (long long)(z & 15) * aLo;
  const long long bOff = (long long)(z >> 4) * bHi + (long long)(z & 15) * bLo;
  const long long cOff = (long long)(z >> 4) * cHi + (long long)(z & 15) * cLo;
  const int m0 = blockIdx.y * BM;
  const int n0 = blockIdx.x * BN;
  constexpr int WN = BN / 64;
  const int wr = w / WN, wc = w % WN;
  const int lm = lane & 15, quad = lane >> 4;

  f32x4 acc[4][4];
  #pragma unroll
  for (int i = 0; i < 4; ++i)
    #pragma unroll
    for (int j = 0; j < 4; ++j) acc[i][j] = (f32x4){0.f, 0.f, 0.f, 0.f};

  const int sr = tid >> 2;        // 0..63
  const int sc = (tid & 3) << 3;  // 0,8,16,24
  const bf16* Ab = A + aOff;
  const bf16* Bb = W + bOff;

  for (int k0 = 0; k0 < K; k0 += 32) {
    uint4 ar[BM / 64], br[BN / 64];
    #pragma unroll
    for (int it = 0; it < BM / 64; ++it)
      ar[it] = *(const uint4*)(Ab + (long long)(m0 + it * 64 + sr) * lda + k0 + sc);
    #pragma unroll
    for (int it = 0; it < BN / 64; ++it)
      br[it] = *(const uint4*)(Bb + (long long)(n0 + it * 64 + sr) * ldb + k0 + sc);
    __syncthreads();   // previous iter's LDS reads complete
    #pragma unroll
    for (int it = 0; it < BM / 64; ++it)
      *(uint4*)&As[(it * 64 + sr) * LDT + sc] = ar[it];
    #pragma unroll
    for (int it = 0; it < BN / 64; ++it)
      *(uint4*)&Bs[(it * 64 + sr) * LDT + sc] = br[it];
    __syncthreads();
    short8 af[4], bfr[4];
    #pragma unroll
    for (int i = 0; i < 4; ++i)
      af[i] = *(const short8*)&As[(wr * 64 + i * 16 + lm) * LDT + quad * 8];
    #pragma unroll
    for (int j = 0; j < 4; ++j)
      bfr[j] = *(const short8*)&Bs[(wc * 64 + j * 16 + lm) * LDT + quad * 8];
    #pragma unroll
    for (int i = 0; i < 4; ++i)
      #pragma unroll
      for (int j = 0; j < 4; ++j)
        acc[i][j] = __builtin_amdgcn_mfma_f32_16x16x32_bf16(af[i], bfr[j], acc[i][j], 0, 0, 0);
  }

  #pragma unroll
  for (int i = 0; i < 4; ++i) {
    #pragma unroll
    for (int j = 0; j < 4; ++j) {
      const int n = n0 + wc * 64 + j * 16 + lm;
      const float bj = BIAS ? bias[n] : 0.f;
      #pragma unroll
      for (int rr = 0; rr < 4; ++rr) {
        const int m = m0 + wr * 64 + i * 16 + quad * 4 + rr;
        float v = acc[i][j][rr] * scale + bj;
        if (RELU) v = fmaxf(v, 0.f);
        const long long co = cOff + (long long)m * ldc + n;
        if (OUTF32) ((float*)C)[co] = v;
        else        ((bf16*)C)[co] = f2b(v);
      }
    }
  }
}

// ---------------------------------------------------------------------------
// Row softmax in place over bf16 [rows][1024]; one wave per row.
// ---------------------------------------------------------------------------
__global__ __launch_bounds__(256) void softmax_kernel(bf16* __restrict__ P) {
  const int tid = threadIdx.x;
  const int lane = tid & 63;
  const int w = tid >> 6;
  const long long row = (long long)blockIdx.x * 4 + w;
  bf16* p = P + row * 1024 + lane * 16;
  float v[16];
  ld8(p, v); ld8(p + 8, v + 8);
  float m = v[0];
  #pragma unroll
  for (int t = 1; t < 16; ++t) m = fmaxf(m, v[t]);
  #pragma unroll
  for (int s = 1; s < 64; s <<= 1) m = fmaxf(m, __shfl_xor(m, s, 64));
  float sum = 0.f;
  #pragma unroll
  for (int t = 0; t < 16; ++t) { v[t] = __expf(v[t] - m); sum += v[t]; }
  #pragma unroll
  for (int s = 1; s < 64; s <<= 1) sum += __shfl_xor(sum, s, 64);
  const float inv = 1.f / sum;
  uint4 o0, o1;
  o0.x = (unsigned)bfbits(v[0]*inv)  | ((unsigned)bfbits(v[1]*inv)  << 16);
  o0.y = (unsigned)bfbits(v[2]*inv)  | ((unsigned)bfbits(v[3]*inv)  << 16);
  o0.z = (unsigned)bfbits(v[4]*inv)  | ((unsigned)bfbits(v[5]*inv)  << 16);
  o0.w = (unsigned)bfbits(v[6]*inv)  | ((unsigned)bfbits(v[7]*inv)  << 16);
  o1.x = (unsigned)bfbits(v[8]*inv)  | ((unsigned)bfbits(v[9]*inv)  << 16);
  o1.y = (unsigned)bfbits(v[10]*inv) | ((unsigned)bfbits(v[11]*inv) << 16);
  o1.z = (unsigned)bfbits(v[12]*inv) | ((unsigned)bfbits(v[13]*inv) << 16);
  o1.w = (unsigned)bfbits(v[14]*inv) | ((unsigned)bfbits(v[15]*inv) << 16);
  ((uint4*)p)[0] = o0; ((uint4*)p)[1] = o1;
}

// ---------------------------------------------------------------------------
// Per-batch: Vt_b[h][d][s] = qkv_b[s, 2048 + h*64 + d]  (64x64 LDS transpose)
// ---------------------------------------------------------------------------
__global__ __launch_bounds__(256) void transpose_v_kernel(
    const bf16* __restrict__ qkv_b, bf16* __restrict__ Vt_b) {
  __shared__ short T[64][72];
  const int tid = threadIdx.x;
  const int h = blockIdx.y;
  const int s0 = blockIdx.x * 64;
  const bf16* src = qkv_b + (long long)s0 * 3072 + 2 * ND + h * 64;
  {
    const int s = tid >> 2, c = (tid & 3) * 16;
    const uint4 a0 = *(const uint4*)(src + (long long)s * 3072 + c);
    const uint4 a1 = *(const uint4*)(src + (long long)s * 3072 + c + 8);
    *(uint4*)&T[s][c] = a0; *(uint4*)&T[s][c + 8] = a1;
  }
  __syncthreads();
  {
    const int d = tid >> 2, c = (tid & 3) * 16;
    unsigned wds[8];
    #pragma unroll
    for (int u = 0; u < 8; ++u) {
      const unsigned lo = (unsigned short)T[c + 2 * u][d];
      const unsigned hi = (unsigned short)T[c + 2 * u + 1][d];
      wds[u] = lo | (hi << 16);
    }
    bf16* dst = Vt_b + (long long)h * (NDH * NS) + (long long)d * NS + s0 + c;
    uint4 o0, o1;
    o0.x = wds[0]; o0.y = wds[1]; o0.z = wds[2]; o0.w = wds[3];
    o1.x = wds[4]; o1.y = wds[5]; o1.z = wds[6]; o1.w = wds[7];
    ((uint4*)dst)[0] = o0; ((uint4*)dst)[1] = o1;
  }
}

// ---------------------------------------------------------------------------
// Batched 1024x1024 bf16 transpose: dst[b][d][s] = src[b][s][d]
// ---------------------------------------------------------------------------
__global__ __launch_bounds__(256) void transpose_sq_kernel(
    const bf16* __restrict__ src, bf16* __restrict__ dst) {
  __shared__ short T[64][72];
  const int tid = threadIdx.x;
  const int b = blockIdx.z;
  const int s0 = blockIdx.x * 64, d0 = blockIdx.y * 64;
  const bf16* sp = src + ((long long)b * NS + s0) * ND + d0;
  {
    const int s = tid >> 2, c = (tid & 3) * 16;
    const uint4 a0 = *(const uint4*)(sp + (long long)s * ND + c);
    const uint4 a1 = *(const uint4*)(sp + (long long)s * ND + c + 8);
    *(uint4*)&T[s][c] = a0; *(uint4*)&T[s][c + 8] = a1;
  }
  __syncthreads();
  {
    const int d = tid >> 2, c = (tid & 3) * 16;
    unsigned wds[8];
    #pragma unroll
    for (int u = 0; u < 8; ++u) {
      const unsigned lo = (unsigned short)T[c + 2 * u][d];
      const unsigned hi = (unsigned short)T[c + 2 * u + 1][d];
      wds[u] = lo | (hi << 16);
    }
    bf16* dp = dst + ((long long)b * ND + d0 + d) * NS + s0 + c;
    uint4 o0, o1;
    o0.x = wds[0]; o0.y = wds[1]; o0.z = wds[2]; o0.w = wds[3];
    o1.x = wds[4]; o1.y = wds[5]; o1.z = wds[6]; o1.w = wds[7];
    ((uint4*)dp)[0] = o0; ((uint4*)dp)[1] = o1;
  }
}

// ---------------------------------------------------------------------------
// Sparse attention weights: per (b,q) row, compute low-rank scores, find the
// 204th-largest via 4-pass radix-select on sortable-uint keys, and write the
// dense normalized weight row aw[q][1024] (bf16, zeros for non-top-k).
// Restricted softmax == softmax->topk->renorm (softmax is monotone); the
// reference's 1e-9 denominator term is preserved exactly via sumAll
// (exp reference point cancels in the ratio).
// ---------------------------------------------------------------------------
__global__ __launch_bounds__(256) void sparse_weights_kernel(
    const float* __restrict__ QKs, bf16* __restrict__ aw)
{
  __shared__ float qrow[64];
  __shared__ unsigned hist[256];
  __shared__ float rbuf[256];
  __shared__ unsigned shPref;
  __shared__ int shNeed;
  const int tid = threadIdx.x;
  const int lane = tid & 63;
  const int b = blockIdx.y, qi = blockIdx.x;

  if (tid < 64) qrow[tid] = QKs[((size_t)(b * NS + qi)) * 128 + tid];
  if (tid == 0) { shPref = 0u; shNeed = NTOPK; }
  __syncthreads();

  // scores: each thread 4 rows of K (K part = QKs cols 64..127)
  float sv[4];
  unsigned key[4];
  #pragma unroll
  for (int j = 0; j < 4; ++j) {
    const int k = tid + (j << 8);
    const float4* kp = (const float4*)(QKs + ((size_t)(b * NS + k)) * 128 + 64);
    float s = 0.f;
    #pragma unroll
    for (int c = 0; c < 16; ++c) {
      const float4 qa = *(const float4*)&qrow[c << 2];
      const float4 ka = kp[c];
      s += qa.x * ka.x + qa.y * ka.y + qa.z * ka.z + qa.w * ka.w;
    }
    s *= 0.125f;                       // 1/sqrt(64)
    sv[j] = s;
    unsigned u = __float_as_uint(s);
    key[j] = (u & 0x80000000u) ? ~u : (u | 0x80000000u);  // descending-sortable
  }

  // 4-pass radix select (MSB -> LSB) for the NTOPK-th largest key
  for (int p = 3; p >= 0; --p) {
    __syncthreads();                   // prev scan done before zeroing
    hist[tid] = 0u;
    __syncthreads();
    const unsigned pref = shPref;
    const int need = shNeed;
    const int sh = (p + 1) * 8;
    #pragma unroll
    for (int j = 0; j < 4; ++j) {
      const bool part = (p == 3) || ((key[j] >> sh) == pref);
      if (part) atomicAdd(&hist[(key[j] >> (p * 8)) & 255u], 1u);
    }
    __syncthreads();
    if (tid < 64) {                    // wave 0: suffix scan + crossing
      unsigned h0 = hist[4 * lane], h1 = hist[4 * lane + 1];
      unsigned h2 = hist[4 * lane + 2], h3 = hist[4 * lane + 3];
      unsigned s3 = h3, s2 = h2 + s3, s1 = h1 + s2, s0 = h0 + s1;
      unsigned sum = s0;
      #pragma unroll
      for (int d2 = 1; d2 < 64; d2 <<= 1) {
        const unsigned t = __shfl_down(sum, d2, 64);
        if (lane < 64 - d2) sum += t;
      }
      const unsigned above = sum - s0;
      unsigned cum[4]  = {above + s0, above + s1, above + s2, above + s3};
      unsigned next[4] = {above + s1, above + s2, above + s3, above};
      #pragma unroll
      for (int i = 0; i < 4; ++i) {
        if ((int)cum[i] >= need && (int)next[i] < need) {
          shPref = (pref << 8) | (unsigned)(4 * lane + i);
          shNeed = need - (int)next[i];
        }
      }
    }
  }
  __syncthreads();
  const unsigned T = shPref;
  const unsigned tb = (T & 0x80000000u) ? (T ^ 0x80000000u) : ~T;
  const float thr = __uint_as_float(tb);

  // weights referenced to thr (reference cancels in normalization)
  float wv[4];
  float psTop = 0.f, psAll = 0.f;
  #pragma unroll
  for (int j = 0; j < 4; ++j) {
    const float e = __expf(sv[j] - thr);
    psAll += e;
    const float w = (key[j] >= T) ? e : 0.f;
    psTop += w;
    wv[j] = w;
  }
  const float sumTop = block_sum_256(psTop, rbuf, tid);
  const float sumAll = block_sum_256(psAll, rbuf, tid);
  const float inv = 1.f / (sumTop + 1e-9f * sumAll);

  bf16* op = aw + ((size_t)(b * NS + qi)) * 1024 + tid;
  #pragma unroll
  for (int j = 0; j < 4; ++j) op[j << 8] = f2b(wv[j] * inv);
}

// ---------------------------------------------------------------------------
// fused = sig*dense + (1-sig)*sparse ; x1 = LN1(src + fused)  (bf16 out)
// ---------------------------------------------------------------------------
__global__ __launch_bounds__(256) void fuse_ln1_kernel(
    const float* __restrict__ src, const bf16* __restrict__ dense,
    const bf16* __restrict__ sparse, const float* __restrict__ lam,
    const float* __restrict__ g, const float* __restrict__ beta,
    bf16* __restrict__ x1)
{
  __shared__ float y[ND];
  __shared__ float rbuf[256];
  const int tid = threadIdx.x;
  const size_t base = (size_t)blockIdx.x * ND;
  const float sig = 1.f / (1.f + __expf(-lam[0]));
  const float c1 = 1.f - sig;
  float s1 = 0.f, s2 = 0.f;
  #pragma unroll
  for (int j = 0; j < 4; ++j) {
    const int i = tid + (j << 8);
    const float v = src[base + i] + sig * b2f(dense[base + i]) + c1 * b2f(sparse[base + i]);
    y[i] = v; s1 += v; s2 += v * v;
  }
  const float sum1 = block_sum_256(s1, rbuf, tid);
  const float sum2 = block_sum_256(s2, rbuf, tid);
  const float mean = sum1 * (1.f / ND);
  const float var  = sum2 * (1.f / ND) - mean * mean;
  const float rstd = rsqrtf(var + 1e-5f);
  #pragma unroll
  for (int j = 0; j < 4; ++j) {
    const int i = tid + (j << 8);
    x1[base + i] = f2b((y[i] - mean) * rstd * g[i] + beta[i]);
  }
}

// out = LN2(x1 + ff)  (fp32 out; ff is bf16)
__global__ __launch_bounds__(256) void ln2_kernel(
    const bf16* __restrict__ x1, const bf16* __restrict__ ff,
    const float* __restrict__ g, const float* __restrict__ beta,
    float* __restrict__ outp)
{
  __shared__ float y[ND];
  __shared__ float rbuf[256];
  const int tid = threadIdx.x;
  const size_t base = (size_t)blockIdx.x * ND;
  float s1 = 0.f, s2 = 0.f;
  #pragma unroll
  for (int j = 0; j < 4; ++j) {
    const int i = tid + (j << 8);
    const float v = b2f(x1[base + i]) + b2f(ff[base + i]);
    y[i] = v; s1 += v; s2 += v * v;
  }
  const float sum1 = block_sum_256(s1, rbuf, tid);
  const float sum2 = block_sum_256(s2, rbuf, tid);
  const float mean = sum1 * (1.f / ND);
  const float var  = sum2 * (1.f / ND) - mean * mean;
  const float rstd = rsqrtf(var + 1e-5f);
  #pragma unroll
  for (int j = 0; j < 4; ++j) {
    const int i = tid + (j << 8);
    outp[base + i] = (y[i] - mean) * rstd * g[i] + beta[i];
  }
}

// ---------------------------------------------------------------------------
extern "C" void kernel_launch(void* const* d_in, const int* in_sizes, int n_in,
                              void* d_out, int out_size, void* d_ws, size_t ws_size,
                              hipStream_t stream)
{
  const float* src        = (const float*)d_in[0];
  const float* in_proj_w  = (const float*)d_in[1];
  const float* in_proj_b  = (const float*)d_in[2];
  const float* out_proj_w = (const float*)d_in[3];
  const float* out_proj_b = (const float*)d_in[4];
  const float* Qp_w  = (const float*)d_in[5];
  const float* Qp_b  = (const float*)d_in[6];
  const float* Kp_w  = (const float*)d_in[7];
  const float* Kp_b  = (const float*)d_in[8];
  const float* Vp_w  = (const float*)d_in[9];
  const float* Vp_b  = (const float*)d_in[10];
  const float* lam   = (const float*)d_in[11];
  const float* ff1_w = (const float*)d_in[12];
  const float* ff1_b = (const float*)d_in[13];
  const float* ff2_w = (const float*)d_in[14];
  const float* ff2_b = (const float*)d_in[15];
  const float* ln1_g = (const float*)d_in[16];
  const float* ln1_b = (const float*)d_in[17];
  const float* ln2_g = (const float*)d_in[18];
  const float* ln2_b = (const float*)d_in[19];
  (void)in_sizes; (void)n_in; (void)out_size; (void)ws_size;

  // --------- workspace layout (total ~132.5 MB; 136.3 MB proven safe in R2)
  char* ws = (char*)d_ws;
  size_t off = 0;
  auto take = [&](size_t bytes) -> void* {
    void* p = ws + off; off += (bytes + 255) & ~(size_t)255; return p;
  };
  bf16*  src_bf  = (bf16*) take((size_t)NM * ND * 2);          //  8.4 MB
  bf16*  w_qkv   = (bf16*) take((size_t)3 * ND * ND * 2);      //  6.3 MB
  bf16*  w_out   = (bf16*) take((size_t)ND * ND * 2);          //  2.1 MB
  bf16*  w_vp    = (bf16*) take((size_t)ND * ND * 2);          //  2.1 MB
  bf16*  w_ff1   = (bf16*) take((size_t)NDFF * ND * 2);        //  8.4 MB
  bf16*  w_ff2   = (bf16*) take((size_t)ND * NDFF * 2);        //  8.4 MB
  bf16*  w_qk    = (bf16*) take((size_t)128 * ND * 2);         //  0.26 MB
  float* bias_qk = (float*)take(128 * 4);
  const size_t mark = off;                                     // reuse point
  bf16*  qkv     = (bf16*) take((size_t)NM * 3 * ND * 2);      // 25.2 MB [dead after attn]
  bf16*  S_b     = (bf16*) take((size_t)NH * NS * NS * 2);     // 33.5 MB [dead after attn]
  bf16*  Vt_b    = (bf16*) take((size_t)NH * NDH * NS * 2);    //  2.1 MB [dead after attn]
  bf16*  ctx     = (bf16*) take((size_t)NM * ND * 2);          //  8.4 MB [dead after step 3]
  bf16*  dense   = (bf16*) take((size_t)NM * ND * 2);          //  8.4 MB
  float* QKs     = (float*)take((size_t)NM * 128 * 4);         //  2.1 MB
  bf16*  Vsp     = (bf16*) take((size_t)NM * ND * 2);          //  8.4 MB
  bf16*  sparse  = (bf16*) take((size_t)NM * ND * 2);          //  8.4 MB
  // aliases into dead regions:
  bf16*  x1    = (bf16*)(ws + mark);                                       // [0, 8.4M)
  bf16*  h1    = (bf16*)(ws + mark + (size_t)NM * ND * 2);                 // [8.4, 42.0M)
  bf16*  ffout = (bf16*)(ws + mark + (size_t)NM * ND * 2 + (size_t)NM * NDFF * 2); // [42.0, 50.4M)
  bf16*  aw    = (bf16*)(ws + mark + 2 * (size_t)NM * ND * 2 + (size_t)NM * NDFF * 2); // [50.4, 58.8M) in qkv+S_b (60.8M)
  bf16*  Vsp_t = (bf16*)ctx;  // ctx dead after step 3; Vsp_t written step 5b, read 6b

  const dim3 blk(256);
  auto cast = [&](const float* in, bf16* out, int n) {
    cast_kernel<<<dim3((n + 1023) / 1024), blk, 0, stream>>>(in, out, n);
  };
  // 0. fp32 -> bf16 conversions
  cast(src,        src_bf, NM * ND);
  cast(in_proj_w,  w_qkv,  3 * ND * ND);
  cast(out_proj_w, w_out,  ND * ND);
  cast(Vp_w,       w_vp,   ND * ND);
  cast(ff1_w,      w_ff1,  NDFF * ND);
  cast(ff2_w,      w_ff2,  ND * NDFF);
  pack_qk_kernel<<<dim3(128), blk, 0, stream>>>(Qp_w, Kp_w, Qp_b, Kp_b, w_qk, bias_qk);

  // 1. qkv = src @ in_proj^T + b   [4096,3072] bf16
  mfma_gemm<128,128,1,0,0><<<dim3(3*ND/128, NM/128, 1), blk, 0, stream>>>(
      src_bf, w_qkv, in_proj_b, qkv, ND, ND, ND, 3*ND, 0,0, 0,0, 0,0, 1.f);

  // 2. dense MHA, per batch (S_b / Vt_b reused across b)
  for (int b = 0; b < NB; ++b) {
    const bf16* qkv_b = qkv + (size_t)b * NS * 3 * ND;
    mfma_gemm<128,128,0,0,0><<<dim3(NS/128, NS/128, NH), blk, 0, stream>>>(
        qkv_b, qkv_b + ND, nullptr, S_b, NDH, 3*ND, 3*ND, NS,
        0, NDH, 0, NDH, 0, (long long)NS*NS, 0.125f);
    softmax_kernel<<<dim3(NH*NS/4), blk, 0, stream>>>(S_b);
    transpose_v_kernel<<<dim3(NS/64, NH), blk, 0, stream>>>(qkv_b, Vt_b);
    mfma_gemm<256,64,0,0,0><<<dim3(1, NS/256, NH), blk, 0, stream>>>(
        S_b, Vt_b, nullptr, ctx + (size_t)b * NS * ND, NS, NS, NS, ND,
        0, (long long)NS*NS, 0, (long long)NDH*NS, 0, NDH, 1.f);
  }

  // 3. dense_output = ctx @ out_proj^T + b  (bf16)
  mfma_gemm<128,128,1,0,0><<<dim3(ND/128, NM/128, 1), blk, 0, stream>>>(
      ctx, w_out, out_proj_b, dense, ND, ND, ND, ND, 0,0, 0,0, 0,0, 1.f);
  // 4. QKs = src @ [Qp;Kp]^T + b  (fp32 [4096][128])
  mfma_gemm<128,128,1,0,1><<<dim3(1, NM/128, 1), blk, 0, stream>>>(
      src_bf, w_qk, bias_qk, QKs, ND, ND, ND, 128, 0,0, 0,0, 0,0, 1.f);
  // 5. Vsp = src @ Vp^T + b  (bf16)
  mfma_gemm<128,128,1,0,0><<<dim3(ND/128, NM/128, 1), blk, 0, stream>>>(
      src_bf, w_vp, Vp_b, Vsp, ND, ND, ND, ND, 0,0, 0,0, 0,0, 1.f);
  // 5b. Vsp_t[b][d][s] = Vsp[b][s][d]   (ctx slot reused)
  transpose_sq_kernel<<<dim3(NS/64, ND/64, NB), blk, 0, stream>>>(Vsp, Vsp_t);
  // 6a. sparse top-k weights -> dense normalized rows aw (bf16)
  sparse_weights_kernel<<<dim3(NS, NB), blk, 0, stream>>>(QKs, aw);
  // 6b. sparse = aw @ Vsp^T  (batched per b, MFMA)
  mfma_gemm<128,128,0,0,0><<<dim3(ND/128, NS/128, NB), blk, 0, stream>>>(
      aw, Vsp_t, nullptr, sparse, NS, NS, NS, ND,
      0, (long long)NS*ND, 0, (long long)ND*NS, 0, (long long)NS*ND, 1.f);
  // 7. fuse + residual + LN1 -> x1 (bf16)  [qkv/S_b dead; x1 aliases them]
  fuse_ln1_kernel<<<dim3(NM), blk, 0, stream>>>(src, dense, sparse, lam, ln1_g, ln1_b, x1);
  // 8. h1 = relu(x1 @ ff1^T + b)  (bf16)
  mfma_gemm<128,128,1,1,0><<<dim3(NDFF/128, NM/128, 1), blk, 0, stream>>>(
      x1, w_ff1, ff1_b, h1, ND, ND, ND, NDFF, 0,0, 0,0, 0,0, 1.f);
  // 9. ff = h1 @ ff2^T + b  (bf16)
  mfma_gemm<128,128,1,0,0><<<dim3(ND/128, NM/128, 1), blk, 0, stream>>>(
      h1, w_ff2, ff2_b, ffout, NDFF, NDFF, NDFF, ND, 0,0, 0,0, 0,0, 1.f);
  // 10. out = LN2(x1 + ff)  (fp32)
  ln2_kernel<<<dim3(NM), blk, 0, stream>>>(x1, ffout, ln2_g, ln2_b, (float*)d_out);
}

// Round 6
// 1263.041 us; speedup vs baseline: 3.2166x; 1.1569x over previous
//
#include <hip/hip_runtime.h>
#include <hip/hip_bf16.h>
#include <math.h>

typedef __hip_bfloat16 bf16;
typedef __attribute__((ext_vector_type(8))) short short8;
typedef __attribute__((ext_vector_type(4))) float f32x4;

// Problem constants
#define NB 4
#define NS 1024
#define ND 1024
#define NH 16
#define NDH 64
#define NR 64
#define NDFF 4096
#define NM (NB*NS)     // 4096 rows
#define NTOPK 204      // int(1024*0.2)

static __device__ __forceinline__ float b2f(bf16 x) { return __bfloat162float(x); }
static __device__ __forceinline__ bf16  f2b(float x) { return __float2bfloat16(x); }
static __device__ __forceinline__ unsigned short bfbits(float x) {
  bf16 h = __float2bfloat16(x);
  return *reinterpret_cast<unsigned short*>(&h);
}

// 8 consecutive bf16 -> fp32 (one 16B load)
static __device__ __forceinline__ void ld8(const bf16* p, float* d) {
  const uint4 u = *(const uint4*)p;
  d[0] = __uint_as_float((u.x & 0xffffu) << 16);
  d[1] = __uint_as_float(u.x & 0xffff0000u);
  d[2] = __uint_as_float((u.y & 0xffffu) << 16);
  d[3] = __uint_as_float(u.y & 0xffff0000u);
  d[4] = __uint_as_float((u.z & 0xffffu) << 16);
  d[5] = __uint_as_float(u.z & 0xffff0000u);
  d[6] = __uint_as_float((u.w & 0xffffu) << 16);
  d[7] = __uint_as_float(u.w & 0xffff0000u);
}

static __device__ __forceinline__ float block_sum_256(float v, float* rbuf, int tid) {
  rbuf[tid] = v;
  __syncthreads();
  #pragma unroll
  for (int st = 128; st > 0; st >>= 1) {
    if (tid < st) rbuf[tid] += rbuf[tid + st];
    __syncthreads();
  }
  const float r = rbuf[0];
  __syncthreads();
  return r;
}

// ---------------------------------------------------------------------------
// fp32 -> bf16 cast (n multiple of 4)
// ---------------------------------------------------------------------------
__global__ __launch_bounds__(256) void cast_kernel(const float* __restrict__ in,
                                                   bf16* __restrict__ out, int n) {
  const int i = (blockIdx.x * 256 + threadIdx.x) * 4;
  if (i < n) {
    const float4 v = *(const float4*)(in + i);
    uint2 o;
    o.x = (unsigned)bfbits(v.x) | ((unsigned)bfbits(v.y) << 16);
    o.y = (unsigned)bfbits(v.z) | ((unsigned)bfbits(v.w) << 16);
    *(uint2*)(out + i) = o;
  }
}

// Concat Qp_w/Kp_w -> bf16 [128][1024], Qp_b/Kp_b -> fp32 [128]
__global__ __launch_bounds__(256) void pack_qk_kernel(
    const float* __restrict__ Qw, const float* __restrict__ Kw,
    const float* __restrict__ Qb, const float* __restrict__ Kb,
    bf16* __restrict__ w, float* __restrict__ bias) {
  const int r = blockIdx.x;  // 0..127
  const float* srcw = (r < 64) ? (Qw + (size_t)r * ND) : (Kw + (size_t)(r - 64) * ND);
  for (int i = threadIdx.x; i < ND; i += 256) w[(size_t)r * ND + i] = f2b(srcw[i]);
  if (r == 0)
    for (int i = threadIdx.x; i < 128; i += 256)
      bias[i] = (i < 64) ? Qb[i] : Kb[i - 64];
}

// ---------------------------------------------------------------------------
// Generic batched MFMA GEMM: C[m][n] = scale * sum_k A[m][k]*W[n][k] (+bias[n])
// A, W bf16 row-major, strides lda/ldb; batch z: off = (z>>4)*Hi + (z&15)*Lo.
// 256 threads = 4 waves; BMxBN tile with BM*BN == 4*64*64; wave = 64x64 via
// 4x4 grid of 16x16x32 MFMAs; BK=32. LDS rows padded to 40 bf16 (80 B) ->
// ds_read_b128 is 2-way bank-aliased only (free on CDNA4).
// ---------------------------------------------------------------------------
template<int BM, int BN, int BIAS, int RELU, int OUTF32>
__global__ __launch_bounds__(256) void mfma_gemm(
    const bf16* __restrict__ A, const bf16* __restrict__ W,
    const float* __restrict__ bias, void* __restrict__ C,
    int K, int lda, int ldb, int ldc,
    long long aHi, long long aLo, long long bHi, long long bLo,
    long long cHi, long long cLo, float scale)
{
  constexpr int LDT = 40;
  __shared__ short As[BM * LDT];
  __shared__ short Bs[BN * LDT];
  const int tid  = threadIdx.x;
  const int lane = tid & 63;
  const int w    = tid >> 6;
  const int z    = blockIdx.z;
  const long long aOff = (long long)(z >> 4) * aHi + (long long)(z & 15) * aLo;
  const long long bOff = (long long)(z >> 4) * bHi + (long long)(z & 15) * bLo;
  const long long cOff = (long long)(z >> 4) * cHi + (long long)(z & 15) * cLo;
  const int m0 = blockIdx.y * BM;
  const int n0 = blockIdx.x * BN;
  constexpr int WN = BN / 64;
  const int wr = w / WN, wc = w % WN;
  const int lm = lane & 15, quad = lane >> 4;

  f32x4 acc[4][4];
  #pragma unroll
  for (int i = 0; i < 4; ++i)
    #pragma unroll
    for (int j = 0; j < 4; ++j) acc[i][j] = (f32x4){0.f, 0.f, 0.f, 0.f};

  const int sr = tid >> 2;        // 0..63
  const int sc = (tid & 3) << 3;  // 0,8,16,24
  const bf16* Ab = A + aOff;
  const bf16* Bb = W + bOff;

  for (int k0 = 0; k0 < K; k0 += 32) {
    uint4 ar[BM / 64], br[BN / 64];
    #pragma unroll
    for (int it = 0; it < BM / 64; ++it)
      ar[it] = *(const uint4*)(Ab + (long long)(m0 + it * 64 + sr) * lda + k0 + sc);
    #pragma unroll
    for (int it = 0; it < BN / 64; ++it)
      br[it] = *(const uint4*)(Bb + (long long)(n0 + it * 64 + sr) * ldb + k0 + sc);
    __syncthreads();   // previous iter's LDS reads complete
    #pragma unroll
    for (int it = 0; it < BM / 64; ++it)
      *(uint4*)&As[(it * 64 + sr) * LDT + sc] = ar[it];
    #pragma unroll
    for (int it = 0; it < BN / 64; ++it)
      *(uint4*)&Bs[(it * 64 + sr) * LDT + sc] = br[it];
    __syncthreads();
    short8 af[4], bfr[4];
    #pragma unroll
    for (int i = 0; i < 4; ++i)
      af[i] = *(const short8*)&As[(wr * 64 + i * 16 + lm) * LDT + quad * 8];
    #pragma unroll
    for (int j = 0; j < 4; ++j)
      bfr[j] = *(const short8*)&Bs[(wc * 64 + j * 16 + lm) * LDT + quad * 8];
    #pragma unroll
    for (int i = 0; i < 4; ++i)
      #pragma unroll
      for (int j = 0; j < 4; ++j)
        acc[i][j] = __builtin_amdgcn_mfma_f32_16x16x32_bf16(af[i], bfr[j], acc[i][j], 0, 0, 0);
  }

  #pragma unroll
  for (int i = 0; i < 4; ++i) {
    #pragma unroll
    for (int j = 0; j < 4; ++j) {
      const int n = n0 + wc * 64 + j * 16 + lm;
      const float bj = BIAS ? bias[n] : 0.f;
      #pragma unroll
      for (int rr = 0; rr < 4; ++rr) {
        const int m = m0 + wr * 64 + i * 16 + quad * 4 + rr;
        float v = acc[i][j][rr] * scale + bj;
        if (RELU) v = fmaxf(v, 0.f);
        const long long co = cOff + (long long)m * ldc + n;
        if (OUTF32) ((float*)C)[co] = v;
        else        ((bf16*)C)[co] = f2b(v);
      }
    }
  }
}

// ---------------------------------------------------------------------------
// Row softmax in place over bf16 [rows][1024]; one wave per row.
// ---------------------------------------------------------------------------
__global__ __launch_bounds__(256) void softmax_kernel(bf16* __restrict__ P) {
  const int tid = threadIdx.x;
  const int lane = tid & 63;
  const int w = tid >> 6;
  const long long row = (long long)blockIdx.x * 4 + w;
  bf16* p = P + row * 1024 + lane * 16;
  float v[16];
  ld8(p, v); ld8(p + 8, v + 8);
  float m = v[0];
  #pragma unroll
  for (int t = 1; t < 16; ++t) m = fmaxf(m, v[t]);
  #pragma unroll
  for (int s = 1; s < 64; s <<= 1) m = fmaxf(m, __shfl_xor(m, s, 64));
  float sum = 0.f;
  #pragma unroll
  for (int t = 0; t < 16; ++t) { v[t] = __expf(v[t] - m); sum += v[t]; }
  #pragma unroll
  for (int s = 1; s < 64; s <<= 1) sum += __shfl_xor(sum, s, 64);
  const float inv = 1.f / sum;
  uint4 o0, o1;
  o0.x = (unsigned)bfbits(v[0]*inv)  | ((unsigned)bfbits(v[1]*inv)  << 16);
  o0.y = (unsigned)bfbits(v[2]*inv)  | ((unsigned)bfbits(v[3]*inv)  << 16);
  o0.z = (unsigned)bfbits(v[4]*inv)  | ((unsigned)bfbits(v[5]*inv)  << 16);
  o0.w = (unsigned)bfbits(v[6]*inv)  | ((unsigned)bfbits(v[7]*inv)  << 16);
  o1.x = (unsigned)bfbits(v[8]*inv)  | ((unsigned)bfbits(v[9]*inv)  << 16);
  o1.y = (unsigned)bfbits(v[10]*inv) | ((unsigned)bfbits(v[11]*inv) << 16);
  o1.z = (unsigned)bfbits(v[12]*inv) | ((unsigned)bfbits(v[13]*inv) << 16);
  o1.w = (unsigned)bfbits(v[14]*inv) | ((unsigned)bfbits(v[15]*inv) << 16);
  ((uint4*)p)[0] = o0; ((uint4*)p)[1] = o1;
}

// ---------------------------------------------------------------------------
// Per-batch: Vt_b[h][d][s] = qkv_b[s, 2048 + h*64 + d]  (64x64 LDS transpose)
// ---------------------------------------------------------------------------
__global__ __launch_bounds__(256) void transpose_v_kernel(
    const bf16* __restrict__ qkv_b, bf16* __restrict__ Vt_b) {
  __shared__ short T[64][72];
  const int tid = threadIdx.x;
  const int h = blockIdx.y;
  const int s0 = blockIdx.x * 64;
  const bf16* src = qkv_b + (long long)s0 * 3072 + 2 * ND + h * 64;
  {
    const int s = tid >> 2, c = (tid & 3) * 16;
    const uint4 a0 = *(const uint4*)(src + (long long)s * 3072 + c);
    const uint4 a1 = *(const uint4*)(src + (long long)s * 3072 + c + 8);
    *(uint4*)&T[s][c] = a0; *(uint4*)&T[s][c + 8] = a1;
  }
  __syncthreads();
  {
    const int d = tid >> 2, c = (tid & 3) * 16;
    unsigned wds[8];
    #pragma unroll
    for (int u = 0; u < 8; ++u) {
      const unsigned lo = (unsigned short)T[c + 2 * u][d];
      const unsigned hi = (unsigned short)T[c + 2 * u + 1][d];
      wds[u] = lo | (hi << 16);
    }
    bf16* dst = Vt_b + (long long)h * (NDH * NS) + (long long)d * NS + s0 + c;
    uint4 o0, o1;
    o0.x = wds[0]; o0.y = wds[1]; o0.z = wds[2]; o0.w = wds[3];
    o1.x = wds[4]; o1.y = wds[5]; o1.z = wds[6]; o1.w = wds[7];
    ((uint4*)dst)[0] = o0; ((uint4*)dst)[1] = o1;
  }
}

// ---------------------------------------------------------------------------
// Batched 1024x1024 bf16 transpose: dst[b][d][s] = src[b][s][d]
// ---------------------------------------------------------------------------
__global__ __launch_bounds__(256) void transpose_sq_kernel(
    const bf16* __restrict__ src, bf16* __restrict__ dst) {
  __shared__ short T[64][72];
  const int tid = threadIdx.x;
  const int b = blockIdx.z;
  const int s0 = blockIdx.x * 64, d0 = blockIdx.y * 64;
  const bf16* sp = src + ((long long)b * NS + s0) * ND + d0;
  {
    const int s = tid >> 2, c = (tid & 3) * 16;
    const uint4 a0 = *(const uint4*)(sp + (long long)s * ND + c);
    const uint4 a1 = *(const uint4*)(sp + (long long)s * ND + c + 8);
    *(uint4*)&T[s][c] = a0; *(uint4*)&T[s][c + 8] = a1;
  }
  __syncthreads();
  {
    const int d = tid >> 2, c = (tid & 3) * 16;
    unsigned wds[8];
    #pragma unroll
    for (int u = 0; u < 8; ++u) {
      const unsigned lo = (unsigned short)T[c + 2 * u][d];
      const unsigned hi = (unsigned short)T[c + 2 * u + 1][d];
      wds[u] = lo | (hi << 16);
    }
    bf16* dp = dst + ((long long)b * ND + d0 + d) * NS + s0 + c;
    uint4 o0, o1;
    o0.x = wds[0]; o0.y = wds[1]; o0.z = wds[2]; o0.w = wds[3];
    o1.x = wds[4]; o1.y = wds[5]; o1.z = wds[6]; o1.w = wds[7];
    ((uint4*)dp)[0] = o0; ((uint4*)dp)[1] = o1;
  }
}

// ---------------------------------------------------------------------------
// Sparse top-k selection from precomputed fp32 scores S[row][1024].
// One WAVE per row (4 rows/block). Radix-select (4x8-bit, MSB->LSB) done
// wave-locally: per-wave LDS histogram, crossing search via ballot+shfl
// (registers only). Writes dense normalized bf16 weight row aw[row][1024]
// (restricted softmax over top-204; 1e-9 denominator term preserved via
// sumAll; exp reference point thr cancels in the ratio).
// ---------------------------------------------------------------------------
__global__ __launch_bounds__(256) void sparse_select_kernel(
    const float* __restrict__ S, bf16* __restrict__ aw)
{
  __shared__ unsigned hist[4][256];
  const int tid = threadIdx.x;
  const int lane = tid & 63;
  const int wv = tid >> 6;
  const long long row = (long long)blockIdx.x * 4 + wv;

  // load 16 scores (lane-contiguous float4s)
  float sv[16];
  const float* sp = S + row * 1024 + lane * 16;
  #pragma unroll
  for (int c = 0; c < 4; ++c) {
    const float4 v = ((const float4*)sp)[c];
    sv[4*c] = v.x; sv[4*c+1] = v.y; sv[4*c+2] = v.z; sv[4*c+3] = v.w;
  }
  unsigned key[16];
  #pragma unroll
  for (int j = 0; j < 16; ++j) {
    const unsigned u = __float_as_uint(sv[j]);
    key[j] = (u & 0x80000000u) ? ~u : (u | 0x80000000u);  // order-preserving
  }

  unsigned pref = 0u;
  int need = NTOPK;
  #pragma unroll
  for (int p = 3; p >= 0; --p) {
    *(uint4*)&hist[wv][lane * 4] = (uint4){0u, 0u, 0u, 0u};
    __syncthreads();
    const int sh = (p + 1) * 8;
    #pragma unroll
    for (int j = 0; j < 16; ++j) {
      const bool part = (p == 3) || ((key[j] >> sh) == pref);
      if (part) atomicAdd(&hist[wv][(key[j] >> (p * 8)) & 255u], 1u);
    }
    __syncthreads();
    const unsigned h0 = hist[wv][4*lane],     h1 = hist[wv][4*lane + 1];
    const unsigned h2 = hist[wv][4*lane + 2], h3 = hist[wv][4*lane + 3];
    const unsigned s3 = h3, s2 = h2 + s3, s1 = h1 + s2, s0 = h0 + s1;
    unsigned sum = s0;                      // suffix sum over lanes >= lane
    #pragma unroll
    for (int d2 = 1; d2 < 64; d2 <<= 1) {
      const unsigned t = __shfl_down(sum, d2, 64);
      if (lane < 64 - d2) sum += t;
    }
    const unsigned above = sum - s0;        // count in bins of higher lanes
    const unsigned cum[4]  = {above + s0, above + s1, above + s2, above + s3};
    const unsigned next[4] = {above + s1, above + s2, above + s3, above};
    unsigned candPref = 0u; int candNeed = 0; bool has = false;
    #pragma unroll
    for (int i = 0; i < 4; ++i) {
      if ((int)cum[i] >= need && (int)next[i] < need) {
        has = true;
        candPref = (pref << 8) | (unsigned)(4 * lane + i);
        candNeed = need - (int)next[i];
      }
    }
    const unsigned long long m = __ballot(has);
    const int srcLane = (int)(__ffsll((long long)m) - 1);
    pref = (unsigned)__shfl((int)candPref, srcLane, 64);
    need = __shfl(candNeed, srcLane, 64);
  }

  const unsigned T = pref;                  // 204th-largest key
  const unsigned tb = (T & 0x80000000u) ? (T ^ 0x80000000u) : ~T;
  const float thr = __uint_as_float(tb);

  float wvv[16];
  float psTop = 0.f, psAll = 0.f;
  #pragma unroll
  for (int j = 0; j < 16; ++j) {
    const float e = __expf(sv[j] - thr);
    psAll += e;
    const float wt = (key[j] >= T) ? e : 0.f;
    psTop += wt;
    wvv[j] = wt;
  }
  #pragma unroll
  for (int s = 1; s < 64; s <<= 1) {
    psTop += __shfl_xor(psTop, s, 64);
    psAll += __shfl_xor(psAll, s, 64);
  }
  const float inv = 1.f / (psTop + 1e-9f * psAll);

  uint4 o0, o1;
  o0.x = (unsigned)bfbits(wvv[0]*inv)  | ((unsigned)bfbits(wvv[1]*inv)  << 16);
  o0.y = (unsigned)bfbits(wvv[2]*inv)  | ((unsigned)bfbits(wvv[3]*inv)  << 16);
  o0.z = (unsigned)bfbits(wvv[4]*inv)  | ((unsigned)bfbits(wvv[5]*inv)  << 16);
  o0.w = (unsigned)bfbits(wvv[6]*inv)  | ((unsigned)bfbits(wvv[7]*inv)  << 16);
  o1.x = (unsigned)bfbits(wvv[8]*inv)  | ((unsigned)bfbits(wvv[9]*inv)  << 16);
  o1.y = (unsigned)bfbits(wvv[10]*inv) | ((unsigned)bfbits(wvv[11]*inv) << 16);
  o1.z = (unsigned)bfbits(wvv[12]*inv) | ((unsigned)bfbits(wvv[13]*inv) << 16);
  o1.w = (unsigned)bfbits(wvv[14]*inv) | ((unsigned)bfbits(wvv[15]*inv) << 16);
  bf16* op = aw + row * 1024 + lane * 16;
  ((uint4*)op)[0] = o0; ((uint4*)op)[1] = o1;
}

// ---------------------------------------------------------------------------
// fused = sig*dense + (1-sig)*sparse ; x1 = LN1(src + fused)  (bf16 out)
// ---------------------------------------------------------------------------
__global__ __launch_bounds__(256) void fuse_ln1_kernel(
    const float* __restrict__ src, const bf16* __restrict__ dense,
    const bf16* __restrict__ sparse, const float* __restrict__ lam,
    const float* __restrict__ g, const float* __restrict__ beta,
    bf16* __restrict__ x1)
{
  __shared__ float y[ND];
  __shared__ float rbuf[256];
  const int tid = threadIdx.x;
  const size_t base = (size_t)blockIdx.x * ND;
  const float sig = 1.f / (1.f + __expf(-lam[0]));
  const float c1 = 1.f - sig;
  float s1 = 0.f, s2 = 0.f;
  #pragma unroll
  for (int j = 0; j < 4; ++j) {
    const int i = tid + (j << 8);
    const float v = src[base + i] + sig * b2f(dense[base + i]) + c1 * b2f(sparse[base + i]);
    y[i] = v; s1 += v; s2 += v * v;
  }
  const float sum1 = block_sum_256(s1, rbuf, tid);
  const float sum2 = block_sum_256(s2, rbuf, tid);
  const float mean = sum1 * (1.f / ND);
  const float var  = sum2 * (1.f / ND) - mean * mean;
  const float rstd = rsqrtf(var + 1e-5f);
  #pragma unroll
  for (int j = 0; j < 4; ++j) {
    const int i = tid + (j << 8);
    x1[base + i] = f2b((y[i] - mean) * rstd * g[i] + beta[i]);
  }
}

// out = LN2(x1 + ff)  (fp32 out; ff is bf16)
__global__ __launch_bounds__(256) void ln2_kernel(
    const bf16* __restrict__ x1, const bf16* __restrict__ ff,
    const float* __restrict__ g, const float* __restrict__ beta,
    float* __restrict__ outp)
{
  __shared__ float y[ND];
  __shared__ float rbuf[256];
  const int tid = threadIdx.x;
  const size_t base = (size_t)blockIdx.x * ND;
  float s1 = 0.f, s2 = 0.f;
  #pragma unroll
  for (int j = 0; j < 4; ++j) {
    const int i = tid + (j << 8);
    const float v = b2f(x1[base + i]) + b2f(ff[base + i]);
    y[i] = v; s1 += v; s2 += v * v;
  }
  const float sum1 = block_sum_256(s1, rbuf, tid);
  const float sum2 = block_sum_256(s2, rbuf, tid);
  const float mean = sum1 * (1.f / ND);
  const float var  = sum2 * (1.f / ND) - mean * mean;
  const float rstd = rsqrtf(var + 1e-5f);
  #pragma unroll
  for (int j = 0; j < 4; ++j) {
    const int i = tid + (j << 8);
    outp[base + i] = (y[i] - mean) * rstd * g[i] + beta[i];
  }
}

// ---------------------------------------------------------------------------
extern "C" void kernel_launch(void* const* d_in, const int* in_sizes, int n_in,
                              void* d_out, int out_size, void* d_ws, size_t ws_size,
                              hipStream_t stream)
{
  const float* src        = (const float*)d_in[0];
  const float* in_proj_w  = (const float*)d_in[1];
  const float* in_proj_b  = (const float*)d_in[2];
  const float* out_proj_w = (const float*)d_in[3];
  const float* out_proj_b = (const float*)d_in[4];
  const float* Qp_w  = (const float*)d_in[5];
  const float* Qp_b  = (const float*)d_in[6];
  const float* Kp_w  = (const float*)d_in[7];
  const float* Kp_b  = (const float*)d_in[8];
  const float* Vp_w  = (const float*)d_in[9];
  const float* Vp_b  = (const float*)d_in[10];
  const float* lam   = (const float*)d_in[11];
  const float* ff1_w = (const float*)d_in[12];
  const float* ff1_b = (const float*)d_in[13];
  const float* ff2_w = (const float*)d_in[14];
  const float* ff2_b = (const float*)d_in[15];
  const float* ln1_g = (const float*)d_in[16];
  const float* ln1_b = (const float*)d_in[17];
  const float* ln2_g = (const float*)d_in[18];
  const float* ln2_b = (const float*)d_in[19];
  (void)in_sizes; (void)n_in; (void)out_size; (void)ws_size;

  // --------- workspace layout (total ~131.5 MB; 136.3 MB proven safe in R2)
  char* ws = (char*)d_ws;
  size_t off = 0;
  auto take = [&](size_t bytes) -> void* {
    void* p = ws + off; off += (bytes + 255) & ~(size_t)255; return p;
  };
  bf16*  src_bf  = (bf16*) take((size_t)NM * ND * 2);          //  8.4 MB
  bf16*  w_qkv   = (bf16*) take((size_t)3 * ND * ND * 2);      //  6.3 MB
  bf16*  w_out   = (bf16*) take((size_t)ND * ND * 2);          //  2.1 MB
  bf16*  w_vp    = (bf16*) take((size_t)ND * ND * 2);          //  2.1 MB
  bf16*  w_ff1   = (bf16*) take((size_t)NDFF * ND * 2);        //  8.4 MB
  bf16*  w_ff2   = (bf16*) take((size_t)ND * NDFF * 2);        //  8.4 MB
  bf16*  w_qk    = (bf16*) take((size_t)128 * ND * 2);         //  0.26 MB
  float* bias_qk = (float*)take(128 * 4);
  const size_t mark = off;                                     // reuse point
  bf16*  qkv     = (bf16*) take((size_t)NM * 3 * ND * 2);      // 25.2 MB [dead after attn]
  bf16*  S_b     = (bf16*) take((size_t)NH * NS * NS * 2);     // 33.5 MB [dead after attn]
  bf16*  Vt_b    = (bf16*) take((size_t)NH * NDH * NS * 2);    //  2.1 MB [dead after attn]
  bf16*  ctx     = (bf16*) take((size_t)NM * ND * 2);          //  8.4 MB [dead after step 3]
  bf16*  dense   = (bf16*) take((size_t)NM * ND * 2);          //  8.4 MB
  bf16*  QKs_bf  = (bf16*) take((size_t)NM * 128 * 2);         //  1.05 MB
  bf16*  Vsp     = (bf16*) take((size_t)NM * ND * 2);          //  8.4 MB
  bf16*  sparse  = (bf16*) take((size_t)NM * ND * 2);          //  8.4 MB
  // aliases into dead regions (qkv+S_b dead after the attention loop):
  bf16*  x1    = (bf16*)(ws + mark);                                       // [0, 8.4M)
  bf16*  h1    = (bf16*)(ws + mark + (size_t)NM * ND * 2);                 // [8.4, 42.0M)
  bf16*  ffout = (bf16*)(ws + mark + (size_t)NM * ND * 2 + (size_t)NM * NDFF * 2); // [42.0, 50.4M)
  bf16*  aw    = (bf16*)(ws + mark + 2 * (size_t)NM * ND * 2 + (size_t)NM * NDFF * 2); // [50.4, 58.8M)
  float* S_sp  = (float*)(ws + mark + (size_t)NM * ND * 2);    // [8.4, 25.2M): written step 4b,
                                                               // read 6a, dead before h1 (step 8)
  bf16*  Vsp_t = (bf16*)ctx;  // ctx dead after step 3

  const dim3 blk(256);
  auto cast = [&](const float* in, bf16* out, int n) {
    cast_kernel<<<dim3((n + 1023) / 1024), blk, 0, stream>>>(in, out, n);
  };
  // 0. fp32 -> bf16 conversions
  cast(src,        src_bf, NM * ND);
  cast(in_proj_w,  w_qkv,  3 * ND * ND);
  cast(out_proj_w, w_out,  ND * ND);
  cast(Vp_w,       w_vp,   ND * ND);
  cast(ff1_w,      w_ff1,  NDFF * ND);
  cast(ff2_w,      w_ff2,  ND * NDFF);
  pack_qk_kernel<<<dim3(128), blk, 0, stream>>>(Qp_w, Kp_w, Qp_b, Kp_b, w_qk, bias_qk);

  // 1. qkv = src @ in_proj^T + b   [4096,3072] bf16
  mfma_gemm<128,128,1,0,0><<<dim3(3*ND/128, NM/128, 1), blk, 0, stream>>>(
      src_bf, w_qkv, in_proj_b, qkv, ND, ND, ND, 3*ND, 0,0, 0,0, 0,0, 1.f);

  // 2. dense MHA, per batch (S_b / Vt_b reused across b)
  for (int b = 0; b < NB; ++b) {
    const bf16* qkv_b = qkv + (size_t)b * NS * 3 * ND;
    mfma_gemm<128,128,0,0,0><<<dim3(NS/128, NS/128, NH), blk, 0, stream>>>(
        qkv_b, qkv_b + ND, nullptr, S_b, NDH, 3*ND, 3*ND, NS,
        0, NDH, 0, NDH, 0, (long long)NS*NS, 0.125f);
    softmax_kernel<<<dim3(NH*NS/4), blk, 0, stream>>>(S_b);
    transpose_v_kernel<<<dim3(NS/64, NH), blk, 0, stream>>>(qkv_b, Vt_b);
    mfma_gemm<256,64,0,0,0><<<dim3(1, NS/256, NH), blk, 0, stream>>>(
        S_b, Vt_b, nullptr, ctx + (size_t)b * NS * ND, NS, NS, NS, ND,
        0, (long long)NS*NS, 0, (long long)NDH*NS, 0, NDH, 1.f);
  }

  // 3. dense_output = ctx @ out_proj^T + b  (bf16)
  mfma_gemm<128,128,1,0,0><<<dim3(ND/128, NM/128, 1), blk, 0, stream>>>(
      ctx, w_out, out_proj_b, dense, ND, ND, ND, ND, 0,0, 0,0, 0,0, 1.f);
  // 4. QKs_bf = src @ [Qp;Kp]^T + b  (bf16 [4096][128])
  mfma_gemm<128,128,1,0,0><<<dim3(1, NM/128, 1), blk, 0, stream>>>(
      src_bf, w_qk, bias_qk, QKs_bf, ND, ND, ND, 128, 0,0, 0,0, 0,0, 1.f);
  // 4b. S_sp[b] = (Qs Ks^T)/8  fp32, batched over b  (M=N=1024, K=64)
  mfma_gemm<128,128,0,0,1><<<dim3(NS/128, NS/128, NB), blk, 0, stream>>>(
      QKs_bf, QKs_bf + 64, nullptr, S_sp, 64, 128, 128, NS,
      0, (long long)NS*128, 0, (long long)NS*128, 0, (long long)NS*NS, 0.125f);
  // 5. Vsp = src @ Vp^T + b  (bf16)
  mfma_gemm<128,128,1,0,0><<<dim3(ND/128, NM/128, 1), blk, 0, stream>>>(
      src_bf, w_vp, Vp_b, Vsp, ND, ND, ND, ND, 0,0, 0,0, 0,0, 1.f);
  // 5b. Vsp_t[b][d][s] = Vsp[b][s][d]   (ctx slot reused)
  transpose_sq_kernel<<<dim3(NS/64, ND/64, NB), blk, 0, stream>>>(Vsp, Vsp_t);
  // 6a. top-k select + normalized weights -> aw (bf16), one wave per row
  sparse_select_kernel<<<dim3(NM/4), blk, 0, stream>>>(S_sp, aw);
  // 6b. sparse = aw @ Vsp^T  (batched per b, MFMA)
  mfma_gemm<128,128,0,0,0><<<dim3(ND/128, NS/128, NB), blk, 0, stream>>>(
      aw, Vsp_t, nullptr, sparse, NS, NS, NS, ND,
      0, (long long)NS*ND, 0, (long long)ND*NS, 0, (long long)NS*ND, 1.f);
  // 7. fuse + residual + LN1 -> x1 (bf16)  [qkv/S_b dead; x1 aliases them]
  fuse_ln1_kernel<<<dim3(NM), blk, 0, stream>>>(src, dense, sparse, lam, ln1_g, ln1_b, x1);
  // 8. h1 = relu(x1 @ ff1^T + b)  (bf16)
  mfma_gemm<128,128,1,1,0><<<dim3(NDFF/128, NM/128, 1), blk, 0, stream>>>(
      x1, w_ff1, ff1_b, h1, ND, ND, ND, NDFF, 0,0, 0,0, 0,0, 1.f);
  // 9. ff = h1 @ ff2^T + b  (bf16)
  mfma_gemm<128,128,1,0,0><<<dim3(ND/128, NM/128, 1), blk, 0, stream>>>(
      h1, w_ff2, ff2_b, ffout, NDFF, NDFF, NDFF, ND, 0,0, 0,0, 0,0, 1.f);
  // 10. out = LN2(x1 + ff)  (fp32)
  ln2_kernel<<<dim3(NM), blk, 0, stream>>>(x1, ffout, ln2_g, ln2_b, (float*)d_out);
}

// Round 7
// 722.606 us; speedup vs baseline: 5.6223x; 1.7479x over previous
//
#include <hip/hip_runtime.h>
#include <hip/hip_bf16.h>
#include <math.h>

typedef __hip_bfloat16 bf16;
typedef __attribute__((ext_vector_type(8))) short short8;
typedef __attribute__((ext_vector_type(4))) float f32x4;

// Problem constants
#define NB 4
#define NS 1024
#define ND 1024
#define NH 16
#define NDH 64
#define NR 64
#define NDFF 4096
#define NM (NB*NS)     // 4096 rows
#define NTOPK 204      // int(1024*0.2)

static __device__ __forceinline__ float b2f(bf16 x) { return __bfloat162float(x); }
static __device__ __forceinline__ bf16  f2b(float x) { return __float2bfloat16(x); }
static __device__ __forceinline__ unsigned short bfbits(float x) {
  bf16 h = __float2bfloat16(x);
  return *reinterpret_cast<unsigned short*>(&h);
}

// async global->LDS, 16B per lane; LDS dest = wave-uniform base + lane*16
static __device__ __forceinline__ void gload_lds16(const void* g, void* l) {
  __builtin_amdgcn_global_load_lds(
      (const __attribute__((address_space(1))) void*)g,
      (__attribute__((address_space(3))) void*)l, 16, 0, 0);
}

// 8 consecutive bf16 -> fp32 (one 16B load)
static __device__ __forceinline__ void ld8(const bf16* p, float* d) {
  const uint4 u = *(const uint4*)p;
  d[0] = __uint_as_float((u.x & 0xffffu) << 16);
  d[1] = __uint_as_float(u.x & 0xffff0000u);
  d[2] = __uint_as_float((u.y & 0xffffu) << 16);
  d[3] = __uint_as_float(u.y & 0xffff0000u);
  d[4] = __uint_as_float((u.z & 0xffffu) << 16);
  d[5] = __uint_as_float(u.z & 0xffff0000u);
  d[6] = __uint_as_float((u.w & 0xffffu) << 16);
  d[7] = __uint_as_float(u.w & 0xffff0000u);
}

static __device__ __forceinline__ float block_sum_256(float v, float* rbuf, int tid) {
  rbuf[tid] = v;
  __syncthreads();
  #pragma unroll
  for (int st = 128; st > 0; st >>= 1) {
    if (tid < st) rbuf[tid] += rbuf[tid + st];
    __syncthreads();
  }
  const float r = rbuf[0];
  __syncthreads();
  return r;
}

// ---------------------------------------------------------------------------
// fp32 -> bf16 cast (n multiple of 4)
// ---------------------------------------------------------------------------
__global__ __launch_bounds__(256) void cast_kernel(const float* __restrict__ in,
                                                   bf16* __restrict__ out, int n) {
  const int i = (blockIdx.x * 256 + threadIdx.x) * 4;
  if (i < n) {
    const float4 v = *(const float4*)(in + i);
    uint2 o;
    o.x = (unsigned)bfbits(v.x) | ((unsigned)bfbits(v.y) << 16);
    o.y = (unsigned)bfbits(v.z) | ((unsigned)bfbits(v.w) << 16);
    *(uint2*)(out + i) = o;
  }
}

// Concat Qp_w/Kp_w -> bf16 [128][1024], Qp_b/Kp_b -> fp32 [128]
__global__ __launch_bounds__(256) void pack_qk_kernel(
    const float* __restrict__ Qw, const float* __restrict__ Kw,
    const float* __restrict__ Qb, const float* __restrict__ Kb,
    bf16* __restrict__ w, float* __restrict__ bias) {
  const int r = blockIdx.x;  // 0..127
  const float* srcw = (r < 64) ? (Qw + (size_t)r * ND) : (Kw + (size_t)(r - 64) * ND);
  for (int i = threadIdx.x; i < ND; i += 256) w[(size_t)r * ND + i] = f2b(srcw[i]);
  if (r == 0)
    for (int i = threadIdx.x; i < 128; i += 256)
      bias[i] = (i < 64) ? Qb[i] : Kb[i - 64];
}

// ---------------------------------------------------------------------------
// Generic batched MFMA GEMM (m97-style): C = scale*(A @ W^T) (+bias), bf16 in.
// Staging via global_load_lds width=16 into unpadded As[BM][32]/Bs[BN][32]
// (LDS dest is wave-uniform base + lane*16; lane l covers row l>>2, col
// (l&3)*8 of a 16x32 segment). 2-barrier K-loop, BK=32.
// 256 threads = 4 waves, wave = 64x64 via 4x4 16x16x32 MFMAs; BM*BN = 16384.
// Batch z: off = (z>>4)*Hi + (z&15)*Lo.
// ---------------------------------------------------------------------------
template<int BM, int BN, int BIAS, int RELU, int OUTF32>
__global__ __launch_bounds__(256) void mfma_gemm(
    const bf16* __restrict__ A, const bf16* __restrict__ W,
    const float* __restrict__ bias, void* __restrict__ C,
    int K, int lda, int ldb, int ldc,
    long long aHi, long long aLo, long long bHi, long long bLo,
    long long cHi, long long cLo, float scale)
{
  __shared__ short As[BM * 32];
  __shared__ short Bs[BN * 32];
  const int tid  = threadIdx.x;
  const int lane = tid & 63;
  const int w    = tid >> 6;
  const int z    = blockIdx.z;
  const long long aOff = (long long)(z >> 4) * aHi + (long long)(z & 15) * aLo;
  const long long bOff = (long long)(z >> 4) * bHi + (long long)(z & 15) * bLo;
  const long long cOff = (long long)(z >> 4) * cHi + (long long)(z & 15) * cLo;
  const int m0 = blockIdx.y * BM;
  const int n0 = blockIdx.x * BN;
  constexpr int WN = BN / 64;
  const int wr = w / WN, wc = w % WN;
  const int lm = lane & 15, quad = lane >> 4;

  f32x4 acc[4][4];
  #pragma unroll
  for (int i = 0; i < 4; ++i)
    #pragma unroll
    for (int j = 0; j < 4; ++j) acc[i][j] = (f32x4){0.f, 0.f, 0.f, 0.f};

  const int sr = lane >> 2;        // 0..15 (row within 16-row staging segment)
  const int sc = (lane & 3) << 3;  // 0,8,16,24 (element col)
  const bf16* Ab = A + aOff;
  const bf16* Bb = W + bOff;

  for (int k0 = 0; k0 < K; k0 += 32) {
    __syncthreads();   // all waves done reading LDS from previous iteration
    #pragma unroll
    for (int t = 0; t < BM / 64; ++t) {
      const int row = w * (BM / 4) + t * 16;
      gload_lds16(Ab + (long long)(m0 + row + sr) * lda + k0 + sc, &As[row * 32]);
    }
    #pragma unroll
    for (int t = 0; t < BN / 64; ++t) {
      const int row = w * (BN / 4) + t * 16;
      gload_lds16(Bb + (long long)(n0 + row + sr) * ldb + k0 + sc, &Bs[row * 32]);
    }
    __syncthreads();   // drains vmcnt -> staged data visible to all waves
    short8 af[4], bfr[4];
    #pragma unroll
    for (int i = 0; i < 4; ++i)
      af[i] = *(const short8*)&As[(wr * 64 + i * 16 + lm) * 32 + quad * 8];
    #pragma unroll
    for (int j = 0; j < 4; ++j)
      bfr[j] = *(const short8*)&Bs[(wc * 64 + j * 16 + lm) * 32 + quad * 8];
    #pragma unroll
    for (int i = 0; i < 4; ++i)
      #pragma unroll
      for (int j = 0; j < 4; ++j)
        acc[i][j] = __builtin_amdgcn_mfma_f32_16x16x32_bf16(af[i], bfr[j], acc[i][j], 0, 0, 0);
  }

  #pragma unroll
  for (int i = 0; i < 4; ++i) {
    #pragma unroll
    for (int j = 0; j < 4; ++j) {
      const int n = n0 + wc * 64 + j * 16 + lm;
      const float bj = BIAS ? bias[n] : 0.f;
      #pragma unroll
      for (int rr = 0; rr < 4; ++rr) {
        const int m = m0 + wr * 64 + i * 16 + quad * 4 + rr;
        float v = acc[i][j][rr] * scale + bj;
        if (RELU) v = fmaxf(v, 0.f);
        const long long co = cOff + (long long)m * ldc + n;
        if (OUTF32) ((float*)C)[co] = v;
        else        ((bf16*)C)[co] = f2b(v);
      }
    }
  }
}

// ---------------------------------------------------------------------------
// Row softmax in place over bf16 [rows][1024]; one wave per row.
// ---------------------------------------------------------------------------
__global__ __launch_bounds__(256) void softmax_kernel(bf16* __restrict__ P) {
  const int tid = threadIdx.x;
  const int lane = tid & 63;
  const int w = tid >> 6;
  const long long row = (long long)blockIdx.x * 4 + w;
  bf16* p = P + row * 1024 + lane * 16;
  float v[16];
  ld8(p, v); ld8(p + 8, v + 8);
  float m = v[0];
  #pragma unroll
  for (int t = 1; t < 16; ++t) m = fmaxf(m, v[t]);
  #pragma unroll
  for (int s = 1; s < 64; s <<= 1) m = fmaxf(m, __shfl_xor(m, s, 64));
  float sum = 0.f;
  #pragma unroll
  for (int t = 0; t < 16; ++t) { v[t] = __expf(v[t] - m); sum += v[t]; }
  #pragma unroll
  for (int s = 1; s < 64; s <<= 1) sum += __shfl_xor(sum, s, 64);
  const float inv = 1.f / sum;
  uint4 o0, o1;
  o0.x = (unsigned)bfbits(v[0]*inv)  | ((unsigned)bfbits(v[1]*inv)  << 16);
  o0.y = (unsigned)bfbits(v[2]*inv)  | ((unsigned)bfbits(v[3]*inv)  << 16);
  o0.z = (unsigned)bfbits(v[4]*inv)  | ((unsigned)bfbits(v[5]*inv)  << 16);
  o0.w = (unsigned)bfbits(v[6]*inv)  | ((unsigned)bfbits(v[7]*inv)  << 16);
  o1.x = (unsigned)bfbits(v[8]*inv)  | ((unsigned)bfbits(v[9]*inv)  << 16);
  o1.y = (unsigned)bfbits(v[10]*inv) | ((unsigned)bfbits(v[11]*inv) << 16);
  o1.z = (unsigned)bfbits(v[12]*inv) | ((unsigned)bfbits(v[13]*inv) << 16);
  o1.w = (unsigned)bfbits(v[14]*inv) | ((unsigned)bfbits(v[15]*inv) << 16);
  ((uint4*)p)[0] = o0; ((uint4*)p)[1] = o1;
}

// ---------------------------------------------------------------------------
// Per-batch: Vt_b[h][d][s] = qkv_b[s, 2048 + h*64 + d]  (64x64 LDS transpose)
// ---------------------------------------------------------------------------
__global__ __launch_bounds__(256) void transpose_v_kernel(
    const bf16* __restrict__ qkv_b, bf16* __restrict__ Vt_b) {
  __shared__ short T[64][72];
  const int tid = threadIdx.x;
  const int h = blockIdx.y;
  const int s0 = blockIdx.x * 64;
  const bf16* src = qkv_b + (long long)s0 * 3072 + 2 * ND + h * 64;
  {
    const int s = tid >> 2, c = (tid & 3) * 16;
    const uint4 a0 = *(const uint4*)(src + (long long)s * 3072 + c);
    const uint4 a1 = *(const uint4*)(src + (long long)s * 3072 + c + 8);
    *(uint4*)&T[s][c] = a0; *(uint4*)&T[s][c + 8] = a1;
  }
  __syncthreads();
  {
    const int d = tid >> 2, c = (tid & 3) * 16;
    unsigned wds[8];
    #pragma unroll
    for (int u = 0; u < 8; ++u) {
      const unsigned lo = (unsigned short)T[c + 2 * u][d];
      const unsigned hi = (unsigned short)T[c + 2 * u + 1][d];
      wds[u] = lo | (hi << 16);
    }
    bf16* dst = Vt_b + (long long)h * (NDH * NS) + (long long)d * NS + s0 + c;
    uint4 o0, o1;
    o0.x = wds[0]; o0.y = wds[1]; o0.z = wds[2]; o0.w = wds[3];
    o1.x = wds[4]; o1.y = wds[5]; o1.z = wds[6]; o1.w = wds[7];
    ((uint4*)dst)[0] = o0; ((uint4*)dst)[1] = o1;
  }
}

// ---------------------------------------------------------------------------
// Batched 1024x1024 bf16 transpose: dst[b][d][s] = src[b][s][d]
// ---------------------------------------------------------------------------
__global__ __launch_bounds__(256) void transpose_sq_kernel(
    const bf16* __restrict__ src, bf16* __restrict__ dst) {
  __shared__ short T[64][72];
  const int tid = threadIdx.x;
  const int b = blockIdx.z;
  const int s0 = blockIdx.x * 64, d0 = blockIdx.y * 64;
  const bf16* sp = src + ((long long)b * NS + s0) * ND + d0;
  {
    const int s = tid >> 2, c = (tid & 3) * 16;
    const uint4 a0 = *(const uint4*)(sp + (long long)s * ND + c);
    const uint4 a1 = *(const uint4*)(sp + (long long)s * ND + c + 8);
    *(uint4*)&T[s][c] = a0; *(uint4*)&T[s][c + 8] = a1;
  }
  __syncthreads();
  {
    const int d = tid >> 2, c = (tid & 3) * 16;
    unsigned wds[8];
    #pragma unroll
    for (int u = 0; u < 8; ++u) {
      const unsigned lo = (unsigned short)T[c + 2 * u][d];
      const unsigned hi = (unsigned short)T[c + 2 * u + 1][d];
      wds[u] = lo | (hi << 16);
    }
    bf16* dp = dst + ((long long)b * ND + d0 + d) * NS + s0 + c;
    uint4 o0, o1;
    o0.x = wds[0]; o0.y = wds[1]; o0.z = wds[2]; o0.w = wds[3];
    o1.x = wds[4]; o1.y = wds[5]; o1.z = wds[6]; o1.w = wds[7];
    ((uint4*)dp)[0] = o0; ((uint4*)dp)[1] = o1;
  }
}

// ---------------------------------------------------------------------------
// Sparse top-k selection from precomputed fp32 scores S[row][1024].
// One WAVE per row (4 rows/block); wave-local radix select.
// ---------------------------------------------------------------------------
__global__ __launch_bounds__(256) void sparse_select_kernel(
    const float* __restrict__ S, bf16* __restrict__ aw)
{
  __shared__ unsigned hist[4][256];
  const int tid = threadIdx.x;
  const int lane = tid & 63;
  const int wv = tid >> 6;
  const long long row = (long long)blockIdx.x * 4 + wv;

  float sv[16];
  const float* sp = S + row * 1024 + lane * 16;
  #pragma unroll
  for (int c = 0; c < 4; ++c) {
    const float4 v = ((const float4*)sp)[c];
    sv[4*c] = v.x; sv[4*c+1] = v.y; sv[4*c+2] = v.z; sv[4*c+3] = v.w;
  }
  unsigned key[16];
  #pragma unroll
  for (int j = 0; j < 16; ++j) {
    const unsigned u = __float_as_uint(sv[j]);
    key[j] = (u & 0x80000000u) ? ~u : (u | 0x80000000u);  // order-preserving
  }

  unsigned pref = 0u;
  int need = NTOPK;
  #pragma unroll
  for (int p = 3; p >= 0; --p) {
    *(uint4*)&hist[wv][lane * 4] = (uint4){0u, 0u, 0u, 0u};
    __syncthreads();
    const int sh = (p + 1) * 8;
    #pragma unroll
    for (int j = 0; j < 16; ++j) {
      const bool part = (p == 3) || ((key[j] >> sh) == pref);
      if (part) atomicAdd(&hist[wv][(key[j] >> (p * 8)) & 255u], 1u);
    }
    __syncthreads();
    const unsigned h0 = hist[wv][4*lane],     h1 = hist[wv][4*lane + 1];
    const unsigned h2 = hist[wv][4*lane + 2], h3 = hist[wv][4*lane + 3];
    const unsigned s3 = h3, s2 = h2 + s3, s1 = h1 + s2, s0 = h0 + s1;
    unsigned sum = s0;                      // suffix sum over lanes >= lane
    #pragma unroll
    for (int d2 = 1; d2 < 64; d2 <<= 1) {
      const unsigned t = __shfl_down(sum, d2, 64);
      if (lane < 64 - d2) sum += t;
    }
    const unsigned above = sum - s0;
    const unsigned cum[4]  = {above + s0, above + s1, above + s2, above + s3};
    const unsigned next[4] = {above + s1, above + s2, above + s3, above};
    unsigned candPref = 0u; int candNeed = 0; bool has = false;
    #pragma unroll
    for (int i = 0; i < 4; ++i) {
      if ((int)cum[i] >= need && (int)next[i] < need) {
        has = true;
        candPref = (pref << 8) | (unsigned)(4 * lane + i);
        candNeed = need - (int)next[i];
      }
    }
    const unsigned long long m = __ballot(has);
    const int srcLane = (int)(__ffsll((long long)m) - 1);
    pref = (unsigned)__shfl((int)candPref, srcLane, 64);
    need = __shfl(candNeed, srcLane, 64);
  }

  const unsigned T = pref;                  // 204th-largest key
  const unsigned tb = (T & 0x80000000u) ? (T ^ 0x80000000u) : ~T;
  const float thr = __uint_as_float(tb);

  float wvv[16];
  float psTop = 0.f, psAll = 0.f;
  #pragma unroll
  for (int j = 0; j < 16; ++j) {
    const float e = __expf(sv[j] - thr);
    psAll += e;
    const float wt = (key[j] >= T) ? e : 0.f;
    psTop += wt;
    wvv[j] = wt;
  }
  #pragma unroll
  for (int s = 1; s < 64; s <<= 1) {
    psTop += __shfl_xor(psTop, s, 64);
    psAll += __shfl_xor(psAll, s, 64);
  }
  const float inv = 1.f / (psTop + 1e-9f * psAll);

  uint4 o0, o1;
  o0.x = (unsigned)bfbits(wvv[0]*inv)  | ((unsigned)bfbits(wvv[1]*inv)  << 16);
  o0.y = (unsigned)bfbits(wvv[2]*inv)  | ((unsigned)bfbits(wvv[3]*inv)  << 16);
  o0.z = (unsigned)bfbits(wvv[4]*inv)  | ((unsigned)bfbits(wvv[5]*inv)  << 16);
  o0.w = (unsigned)bfbits(wvv[6]*inv)  | ((unsigned)bfbits(wvv[7]*inv)  << 16);
  o1.x = (unsigned)bfbits(wvv[8]*inv)  | ((unsigned)bfbits(wvv[9]*inv)  << 16);
  o1.y = (unsigned)bfbits(wvv[10]*inv) | ((unsigned)bfbits(wvv[11]*inv) << 16);
  o1.z = (unsigned)bfbits(wvv[12]*inv) | ((unsigned)bfbits(wvv[13]*inv) << 16);
  o1.w = (unsigned)bfbits(wvv[14]*inv) | ((unsigned)bfbits(wvv[15]*inv) << 16);
  bf16* op = aw + row * 1024 + lane * 16;
  ((uint4*)op)[0] = o0; ((uint4*)op)[1] = o1;
}

// ---------------------------------------------------------------------------
// fused = sig*dense + (1-sig)*sparse ; x1 = LN1(src + fused)  (bf16 out)
// ---------------------------------------------------------------------------
__global__ __launch_bounds__(256) void fuse_ln1_kernel(
    const float* __restrict__ src, const bf16* __restrict__ dense,
    const bf16* __restrict__ sparse, const float* __restrict__ lam,
    const float* __restrict__ g, const float* __restrict__ beta,
    bf16* __restrict__ x1)
{
  __shared__ float y[ND];
  __shared__ float rbuf[256];
  const int tid = threadIdx.x;
  const size_t base = (size_t)blockIdx.x * ND;
  const float sig = 1.f / (1.f + __expf(-lam[0]));
  const float c1 = 1.f - sig;
  float s1 = 0.f, s2 = 0.f;
  #pragma unroll
  for (int j = 0; j < 4; ++j) {
    const int i = tid + (j << 8);
    const float v = src[base + i] + sig * b2f(dense[base + i]) + c1 * b2f(sparse[base + i]);
    y[i] = v; s1 += v; s2 += v * v;
  }
  const float sum1 = block_sum_256(s1, rbuf, tid);
  const float sum2 = block_sum_256(s2, rbuf, tid);
  const float mean = sum1 * (1.f / ND);
  const float var  = sum2 * (1.f / ND) - mean * mean;
  const float rstd = rsqrtf(var + 1e-5f);
  #pragma unroll
  for (int j = 0; j < 4; ++j) {
    const int i = tid + (j << 8);
    x1[base + i] = f2b((y[i] - mean) * rstd * g[i] + beta[i]);
  }
}

// out = LN2(x1 + ff)  (fp32 out; ff is bf16)
__global__ __launch_bounds__(256) void ln2_kernel(
    const bf16* __restrict__ x1, const bf16* __restrict__ ff,
    const float* __restrict__ g, const float* __restrict__ beta,
    float* __restrict__ outp)
{
  __shared__ float y[ND];
  __shared__ float rbuf[256];
  const int tid = threadIdx.x;
  const size_t base = (size_t)blockIdx.x * ND;
  float s1 = 0.f, s2 = 0.f;
  #pragma unroll
  for (int j = 0; j < 4; ++j) {
    const int i = tid + (j << 8);
    const float v = b2f(x1[base + i]) + b2f(ff[base + i]);
    y[i] = v; s1 += v; s2 += v * v;
  }
  const float sum1 = block_sum_256(s1, rbuf, tid);
  const float sum2 = block_sum_256(s2, rbuf, tid);
  const float mean = sum1 * (1.f / ND);
  const float var  = sum2 * (1.f / ND) - mean * mean;
  const float rstd = rsqrtf(var + 1e-5f);
  #pragma unroll
  for (int j = 0; j < 4; ++j) {
    const int i = tid + (j << 8);
    outp[base + i] = (y[i] - mean) * rstd * g[i] + beta[i];
  }
}

// ---------------------------------------------------------------------------
extern "C" void kernel_launch(void* const* d_in, const int* in_sizes, int n_in,
                              void* d_out, int out_size, void* d_ws, size_t ws_size,
                              hipStream_t stream)
{
  const float* src        = (const float*)d_in[0];
  const float* in_proj_w  = (const float*)d_in[1];
  const float* in_proj_b  = (const float*)d_in[2];
  const float* out_proj_w = (const float*)d_in[3];
  const float* out_proj_b = (const float*)d_in[4];
  const float* Qp_w  = (const float*)d_in[5];
  const float* Qp_b  = (const float*)d_in[6];
  const float* Kp_w  = (const float*)d_in[7];
  const float* Kp_b  = (const float*)d_in[8];
  const float* Vp_w  = (const float*)d_in[9];
  const float* Vp_b  = (const float*)d_in[10];
  const float* lam   = (const float*)d_in[11];
  const float* ff1_w = (const float*)d_in[12];
  const float* ff1_b = (const float*)d_in[13];
  const float* ff2_w = (const float*)d_in[14];
  const float* ff2_b = (const float*)d_in[15];
  const float* ln1_g = (const float*)d_in[16];
  const float* ln1_b = (const float*)d_in[17];
  const float* ln2_g = (const float*)d_in[18];
  const float* ln2_b = (const float*)d_in[19];
  (void)in_sizes; (void)n_in; (void)out_size; (void)ws_size;

  // --------- workspace layout (total ~131.5 MB; 136.3 MB proven safe in R2)
  char* ws = (char*)d_ws;
  size_t off = 0;
  auto take = [&](size_t bytes) -> void* {
    void* p = ws + off; off += (bytes + 255) & ~(size_t)255; return p;
  };
  bf16*  src_bf  = (bf16*) take((size_t)NM * ND * 2);          //  8.4 MB
  bf16*  w_qkv   = (bf16*) take((size_t)3 * ND * ND * 2);      //  6.3 MB
  bf16*  w_out   = (bf16*) take((size_t)ND * ND * 2);          //  2.1 MB
  bf16*  w_vp    = (bf16*) take((size_t)ND * ND * 2);          //  2.1 MB
  bf16*  w_ff1   = (bf16*) take((size_t)NDFF * ND * 2);        //  8.4 MB
  bf16*  w_ff2   = (bf16*) take((size_t)ND * NDFF * 2);        //  8.4 MB
  bf16*  w_qk    = (bf16*) take((size_t)128 * ND * 2);         //  0.26 MB
  float* bias_qk = (float*)take(128 * 4);
  const size_t mark = off;                                     // reuse point
  bf16*  qkv     = (bf16*) take((size_t)NM * 3 * ND * 2);      // 25.2 MB [dead after attn]
  bf16*  S_b     = (bf16*) take((size_t)NH * NS * NS * 2);     // 33.5 MB [dead after attn]
  bf16*  Vt_b    = (bf16*) take((size_t)NH * NDH * NS * 2);    //  2.1 MB [dead after attn]
  bf16*  ctx     = (bf16*) take((size_t)NM * ND * 2);          //  8.4 MB [dead after step 3]
  bf16*  dense   = (bf16*) take((size_t)NM * ND * 2);          //  8.4 MB
  bf16*  QKs_bf  = (bf16*) take((size_t)NM * 128 * 2);         //  1.05 MB
  bf16*  Vsp     = (bf16*) take((size_t)NM * ND * 2);          //  8.4 MB
  bf16*  sparse  = (bf16*) take((size_t)NM * ND * 2);          //  8.4 MB
  // aliases into dead regions (qkv+S_b dead after the attention loop):
  bf16*  x1    = (bf16*)(ws + mark);                                       // [0, 8.4M)
  bf16*  h1    = (bf16*)(ws + mark + (size_t)NM * ND * 2);                 // [8.4, 42.0M)
  bf16*  ffout = (bf16*)(ws + mark + (size_t)NM * ND * 2 + (size_t)NM * NDFF * 2); // [42.0, 50.4M)
  bf16*  aw    = (bf16*)(ws + mark + 2 * (size_t)NM * ND * 2 + (size_t)NM * NDFF * 2); // [50.4, 58.8M)
  float* S_sp  = (float*)(ws + mark + (size_t)NM * ND * 2);    // [8.4, 25.2M): written 4b,
                                                               // read 6a, dead before h1
  bf16*  Vsp_t = (bf16*)ctx;  // ctx dead after step 3

  const dim3 blk(256);
  auto cast = [&](const float* in, bf16* out, int n) {
    cast_kernel<<<dim3((n + 1023) / 1024), blk, 0, stream>>>(in, out, n);
  };
  // 0. fp32 -> bf16 conversions
  cast(src,        src_bf, NM * ND);
  cast(in_proj_w,  w_qkv,  3 * ND * ND);
  cast(out_proj_w, w_out,  ND * ND);
  cast(Vp_w,       w_vp,   ND * ND);
  cast(ff1_w,      w_ff1,  NDFF * ND);
  cast(ff2_w,      w_ff2,  ND * NDFF);
  pack_qk_kernel<<<dim3(128), blk, 0, stream>>>(Qp_w, Kp_w, Qp_b, Kp_b, w_qk, bias_qk);

  // 1. qkv = src @ in_proj^T + b   [4096,3072] bf16
  mfma_gemm<128,128,1,0,0><<<dim3(3*ND/128, NM/128, 1), blk, 0, stream>>>(
      src_bf, w_qkv, in_proj_b, qkv, ND, ND, ND, 3*ND, 0,0, 0,0, 0,0, 1.f);

  // 2. dense MHA, per batch (S_b / Vt_b reused across b)
  for (int b = 0; b < NB; ++b) {
    const bf16* qkv_b = qkv + (size_t)b * NS * 3 * ND;
    mfma_gemm<128,128,0,0,0><<<dim3(NS/128, NS/128, NH), blk, 0, stream>>>(
        qkv_b, qkv_b + ND, nullptr, S_b, NDH, 3*ND, 3*ND, NS,
        0, NDH, 0, NDH, 0, (long long)NS*NS, 0.125f);
    softmax_kernel<<<dim3(NH*NS/4), blk, 0, stream>>>(S_b);
    transpose_v_kernel<<<dim3(NS/64, NH), blk, 0, stream>>>(qkv_b, Vt_b);
    mfma_gemm<256,64,0,0,0><<<dim3(1, NS/256, NH), blk, 0, stream>>>(
        S_b, Vt_b, nullptr, ctx + (size_t)b * NS * ND, NS, NS, NS, ND,
        0, (long long)NS*NS, 0, (long long)NDH*NS, 0, NDH, 1.f);
  }

  // 3. dense_output = ctx @ out_proj^T + b  (bf16)
  mfma_gemm<128,128,1,0,0><<<dim3(ND/128, NM/128, 1), blk, 0, stream>>>(
      ctx, w_out, out_proj_b, dense, ND, ND, ND, ND, 0,0, 0,0, 0,0, 1.f);
  // 4. QKs_bf = src @ [Qp;Kp]^T + b  (bf16 [4096][128])
  mfma_gemm<128,128,1,0,0><<<dim3(1, NM/128, 1), blk, 0, stream>>>(
      src_bf, w_qk, bias_qk, QKs_bf, ND, ND, ND, 128, 0,0, 0,0, 0,0, 1.f);
  // 4b. S_sp[b] = (Qs Ks^T)/8  fp32, batched over b  (M=N=1024, K=64)
  mfma_gemm<128,128,0,0,1><<<dim3(NS/128, NS/128, NB), blk, 0, stream>>>(
      QKs_bf, QKs_bf + 64, nullptr, S_sp, 64, 128, 128, NS,
      0, (long long)NS*128, 0, (long long)NS*128, 0, (long long)NS*NS, 0.125f);
  // 5. Vsp = src @ Vp^T + b  (bf16)
  mfma_gemm<128,128,1,0,0><<<dim3(ND/128, NM/128, 1), blk, 0, stream>>>(
      src_bf, w_vp, Vp_b, Vsp, ND, ND, ND, ND, 0,0, 0,0, 0,0, 1.f);
  // 5b. Vsp_t[b][d][s] = Vsp[b][s][d]   (ctx slot reused)
  transpose_sq_kernel<<<dim3(NS/64, ND/64, NB), blk, 0, stream>>>(Vsp, Vsp_t);
  // 6a. top-k select + normalized weights -> aw (bf16), one wave per row
  sparse_select_kernel<<<dim3(NM/4), blk, 0, stream>>>(S_sp, aw);
  // 6b. sparse = aw @ Vsp^T  (batched per b, MFMA)
  mfma_gemm<128,128,0,0,0><<<dim3(ND/128, NS/128, NB), blk, 0, stream>>>(
      aw, Vsp_t, nullptr, sparse, NS, NS, NS, ND,
      0, (long long)NS*ND, 0, (long long)ND*NS, 0, (long long)NS*ND, 1.f);
  // 7. fuse + residual + LN1 -> x1 (bf16)  [qkv/S_b dead; x1 aliases them]
  fuse_ln1_kernel<<<dim3(NM), blk, 0, stream>>>(src, dense, sparse, lam, ln1_g, ln1_b, x1);
  // 8. h1 = relu(x1 @ ff1^T + b)  (bf16)
  mfma_gemm<128,128,1,1,0><<<dim3(NDFF/128, NM/128, 1), blk, 0, stream>>>(
      x1, w_ff1, ff1_b, h1, ND, ND, ND, NDFF, 0,0, 0,0, 0,0, 1.f);
  // 9. ff = h1 @ ff2^T + b  (bf16)
  mfma_gemm<128,128,1,0,0><<<dim3(ND/128, NM/128, 1), blk, 0, stream>>>(
      h1, w_ff2, ff2_b, ffout, NDFF, NDFF, NDFF, ND, 0,0, 0,0, 0,0, 1.f);
  // 10. out = LN2(x1 + ff)  (fp32)
  ln2_kernel<<<dim3(NM), blk, 0, stream>>>(x1, ffout, ln2_g, ln2_b, (float*)d_out);
}

// Round 8
// 679.575 us; speedup vs baseline: 5.9784x; 1.0633x over previous
//
#include <hip/hip_runtime.h>
#include <hip/hip_bf16.h>
#include <math.h>

typedef __hip_bfloat16 bf16;
typedef __attribute__((ext_vector_type(8))) short short8;
typedef __attribute__((ext_vector_type(4))) float f32x4;

// Problem constants
#define NB 4
#define NS 1024
#define ND 1024
#define NH 16
#define NDH 64
#define NR 64
#define NDFF 4096
#define NM (NB*NS)     // 4096 rows
#define NTOPK 204      // int(1024*0.2)

static __device__ __forceinline__ float b2f(bf16 x) { return __bfloat162float(x); }
static __device__ __forceinline__ bf16  f2b(float x) { return __float2bfloat16(x); }
static __device__ __forceinline__ unsigned short bfbits(float x) {
  bf16 h = __float2bfloat16(x);
  return *reinterpret_cast<unsigned short*>(&h);
}

// async global->LDS, 16B per lane; LDS dest = wave-uniform base + lane*16
static __device__ __forceinline__ void gload_lds16(const void* g, void* l) {
  __builtin_amdgcn_global_load_lds(
      (const __attribute__((address_space(1))) void*)g,
      (__attribute__((address_space(3))) void*)l, 16, 0, 0);
}

// 8 consecutive bf16 -> fp32 (one 16B load)
static __device__ __forceinline__ void ld8(const bf16* p, float* d) {
  const uint4 u = *(const uint4*)p;
  d[0] = __uint_as_float((u.x & 0xffffu) << 16);
  d[1] = __uint_as_float(u.x & 0xffff0000u);
  d[2] = __uint_as_float((u.y & 0xffffu) << 16);
  d[3] = __uint_as_float(u.y & 0xffff0000u);
  d[4] = __uint_as_float((u.z & 0xffffu) << 16);
  d[5] = __uint_as_float(u.z & 0xffff0000u);
  d[6] = __uint_as_float((u.w & 0xffffu) << 16);
  d[7] = __uint_as_float(u.w & 0xffff0000u);
}

static __device__ __forceinline__ float block_sum_256(float v, float* rbuf, int tid) {
  rbuf[tid] = v;
  __syncthreads();
  #pragma unroll
  for (int st = 128; st > 0; st >>= 1) {
    if (tid < st) rbuf[tid] += rbuf[tid + st];
    __syncthreads();
  }
  const float r = rbuf[0];
  __syncthreads();
  return r;
}

// ---------------------------------------------------------------------------
// fp32 -> bf16 cast (n multiple of 4)
// ---------------------------------------------------------------------------
__global__ __launch_bounds__(256) void cast_kernel(const float* __restrict__ in,
                                                   bf16* __restrict__ out, int n) {
  const int i = (blockIdx.x * 256 + threadIdx.x) * 4;
  if (i < n) {
    const float4 v = *(const float4*)(in + i);
    uint2 o;
    o.x = (unsigned)bfbits(v.x) | ((unsigned)bfbits(v.y) << 16);
    o.y = (unsigned)bfbits(v.z) | ((unsigned)bfbits(v.w) << 16);
    *(uint2*)(out + i) = o;
  }
}

// Concat Qp_w/Kp_w -> bf16 [128][1024], Qp_b/Kp_b -> fp32 [128]
__global__ __launch_bounds__(256) void pack_qk_kernel(
    const float* __restrict__ Qw, const float* __restrict__ Kw,
    const float* __restrict__ Qb, const float* __restrict__ Kb,
    bf16* __restrict__ w, float* __restrict__ bias) {
  const int r = blockIdx.x;  // 0..127
  const float* srcw = (r < 64) ? (Qw + (size_t)r * ND) : (Kw + (size_t)(r - 64) * ND);
  for (int i = threadIdx.x; i < ND; i += 256) w[(size_t)r * ND + i] = f2b(srcw[i]);
  if (r == 0)
    for (int i = threadIdx.x; i < 128; i += 256)
      bias[i] = (i < 64) ? Qb[i] : Kb[i - 64];
}

// ---------------------------------------------------------------------------
// Generic batched MFMA GEMM: C = scale*(A @ W^T) (+bias), bf16 in.
// BK=64 as two side-by-side m97-geometry BK=32 half-buffers (As[2][BM*32]):
// 32 MFMAs per barrier pair, unchanged LDS conflict profile, staging legal
// for global_load_lds (wave-uniform base + lane*16).
// XCD-compact swizzle when gridDim.x%8==0: blocks with lin%8==x (same XCD
// under round-robin dispatch) cover a contiguous column strip -> per-XCD L2
// reuse of the A/W panels (cuts the 8x HBM over-fetch).
// 256 threads = 4 waves, wave = 64x64 via 4x4 16x16x32 MFMAs; BM*BN = 16384.
// Batch z: off = (z>>4)*Hi + (z&15)*Lo.  K must be a multiple of 64.
// ---------------------------------------------------------------------------
template<int BM, int BN, int BIAS, int RELU, int OUTF32>
__global__ __launch_bounds__(256) void mfma_gemm(
    const bf16* __restrict__ A, const bf16* __restrict__ W,
    const float* __restrict__ bias, void* __restrict__ C,
    int K, int lda, int ldb, int ldc,
    long long aHi, long long aLo, long long bHi, long long bLo,
    long long cHi, long long cLo, float scale)
{
  __shared__ short As[2][BM * 32];
  __shared__ short Bs[2][BN * 32];
  const int tid  = threadIdx.x;
  const int lane = tid & 63;
  const int w    = tid >> 6;
  const int z    = blockIdx.z;
  const long long aOff = (long long)(z >> 4) * aHi + (long long)(z & 15) * aLo;
  const long long bOff = (long long)(z >> 4) * bHi + (long long)(z & 15) * bLo;
  const long long cOff = (long long)(z >> 4) * cHi + (long long)(z & 15) * cLo;

  // XCD-compact swizzle (perf heuristic only; bijective when gridDim.x%8==0)
  int bx = blockIdx.x, by = blockIdx.y;
  if ((gridDim.x & 7) == 0) {
    const unsigned lin = blockIdx.y * gridDim.x + blockIdx.x;
    const unsigned Wd = gridDim.x >> 3;
    const unsigned xcd = lin & 7, i = lin >> 3;
    bx = (int)(xcd * Wd + (i % Wd));
    by = (int)(i / Wd);
  }
  const int m0 = by * BM;
  const int n0 = bx * BN;
  constexpr int WN = BN / 64;
  const int wr = w / WN, wc = w % WN;
  const int lm = lane & 15, quad = lane >> 4;

  f32x4 acc[4][4];
  #pragma unroll
  for (int i = 0; i < 4; ++i)
    #pragma unroll
    for (int j = 0; j < 4; ++j) acc[i][j] = (f32x4){0.f, 0.f, 0.f, 0.f};

  const int sr = lane >> 2;        // 0..15 (row within 16-row staging segment)
  const int sc = (lane & 3) << 3;  // 0,8,16,24 (element col within 32-col half)
  const bf16* Ab = A + aOff;
  const bf16* Bb = W + bOff;

  for (int k0 = 0; k0 < K; k0 += 64) {
    __syncthreads();   // all waves done reading LDS from previous iteration
    #pragma unroll
    for (int h = 0; h < 2; ++h) {
      const int kk = k0 + h * 32;
      #pragma unroll
      for (int t = 0; t < BM / 64; ++t) {
        const int row = w * (BM / 4) + t * 16;
        gload_lds16(Ab + (long long)(m0 + row + sr) * lda + kk + sc, &As[h][row * 32]);
      }
      #pragma unroll
      for (int t = 0; t < BN / 64; ++t) {
        const int row = w * (BN / 4) + t * 16;
        gload_lds16(Bb + (long long)(n0 + row + sr) * ldb + kk + sc, &Bs[h][row * 32]);
      }
    }
    __syncthreads();   // drains vmcnt -> staged data visible to all waves
    #pragma unroll
    for (int h = 0; h < 2; ++h) {
      short8 af[4], bfr[4];
      #pragma unroll
      for (int i = 0; i < 4; ++i)
        af[i] = *(const short8*)&As[h][(wr * 64 + i * 16 + lm) * 32 + quad * 8];
      #pragma unroll
      for (int j = 0; j < 4; ++j)
        bfr[j] = *(const short8*)&Bs[h][(wc * 64 + j * 16 + lm) * 32 + quad * 8];
      #pragma unroll
      for (int i = 0; i < 4; ++i)
        #pragma unroll
        for (int j = 0; j < 4; ++j)
          acc[i][j] = __builtin_amdgcn_mfma_f32_16x16x32_bf16(af[i], bfr[j], acc[i][j], 0, 0, 0);
    }
  }

  #pragma unroll
  for (int i = 0; i < 4; ++i) {
    #pragma unroll
    for (int j = 0; j < 4; ++j) {
      const int n = n0 + wc * 64 + j * 16 + lm;
      const float bj = BIAS ? bias[n] : 0.f;
      #pragma unroll
      for (int rr = 0; rr < 4; ++rr) {
        const int m = m0 + wr * 64 + i * 16 + quad * 4 + rr;
        float v = acc[i][j][rr] * scale + bj;
        if (RELU) v = fmaxf(v, 0.f);
        const long long co = cOff + (long long)m * ldc + n;
        if (OUTF32) ((float*)C)[co] = v;
        else        ((bf16*)C)[co] = f2b(v);
      }
    }
  }
}

// ---------------------------------------------------------------------------
// Row softmax in place over bf16 [rows][1024]; one wave per row.
// ---------------------------------------------------------------------------
__global__ __launch_bounds__(256) void softmax_kernel(bf16* __restrict__ P) {
  const int tid = threadIdx.x;
  const int lane = tid & 63;
  const int w = tid >> 6;
  const long long row = (long long)blockIdx.x * 4 + w;
  bf16* p = P + row * 1024 + lane * 16;
  float v[16];
  ld8(p, v); ld8(p + 8, v + 8);
  float m = v[0];
  #pragma unroll
  for (int t = 1; t < 16; ++t) m = fmaxf(m, v[t]);
  #pragma unroll
  for (int s = 1; s < 64; s <<= 1) m = fmaxf(m, __shfl_xor(m, s, 64));
  float sum = 0.f;
  #pragma unroll
  for (int t = 0; t < 16; ++t) { v[t] = __expf(v[t] - m); sum += v[t]; }
  #pragma unroll
  for (int s = 1; s < 64; s <<= 1) sum += __shfl_xor(sum, s, 64);
  const float inv = 1.f / sum;
  uint4 o0, o1;
  o0.x = (unsigned)bfbits(v[0]*inv)  | ((unsigned)bfbits(v[1]*inv)  << 16);
  o0.y = (unsigned)bfbits(v[2]*inv)  | ((unsigned)bfbits(v[3]*inv)  << 16);
  o0.z = (unsigned)bfbits(v[4]*inv)  | ((unsigned)bfbits(v[5]*inv)  << 16);
  o0.w = (unsigned)bfbits(v[6]*inv)  | ((unsigned)bfbits(v[7]*inv)  << 16);
  o1.x = (unsigned)bfbits(v[8]*inv)  | ((unsigned)bfbits(v[9]*inv)  << 16);
  o1.y = (unsigned)bfbits(v[10]*inv) | ((unsigned)bfbits(v[11]*inv) << 16);
  o1.z = (unsigned)bfbits(v[12]*inv) | ((unsigned)bfbits(v[13]*inv) << 16);
  o1.w = (unsigned)bfbits(v[14]*inv) | ((unsigned)bfbits(v[15]*inv) << 16);
  ((uint4*)p)[0] = o0; ((uint4*)p)[1] = o1;
}

// ---------------------------------------------------------------------------
// Per-batch: Vt_b[h][d][s] = qkv_b[s, 2048 + h*64 + d]  (64x64 LDS transpose)
// ---------------------------------------------------------------------------
__global__ __launch_bounds__(256) void transpose_v_kernel(
    const bf16* __restrict__ qkv_b, bf16* __restrict__ Vt_b) {
  __shared__ short T[64][72];
  const int tid = threadIdx.x;
  const int h = blockIdx.y;
  const int s0 = blockIdx.x * 64;
  const bf16* src = qkv_b + (long long)s0 * 3072 + 2 * ND + h * 64;
  {
    const int s = tid >> 2, c = (tid & 3) * 16;
    const uint4 a0 = *(const uint4*)(src + (long long)s * 3072 + c);
    const uint4 a1 = *(const uint4*)(src + (long long)s * 3072 + c + 8);
    *(uint4*)&T[s][c] = a0; *(uint4*)&T[s][c + 8] = a1;
  }
  __syncthreads();
  {
    const int d = tid >> 2, c = (tid & 3) * 16;
    unsigned wds[8];
    #pragma unroll
    for (int u = 0; u < 8; ++u) {
      const unsigned lo = (unsigned short)T[c + 2 * u][d];
      const unsigned hi = (unsigned short)T[c + 2 * u + 1][d];
      wds[u] = lo | (hi << 16);
    }
    bf16* dst = Vt_b + (long long)h * (NDH * NS) + (long long)d * NS + s0 + c;
    uint4 o0, o1;
    o0.x = wds[0]; o0.y = wds[1]; o0.z = wds[2]; o0.w = wds[3];
    o1.x = wds[4]; o1.y = wds[5]; o1.z = wds[6]; o1.w = wds[7];
    ((uint4*)dst)[0] = o0; ((uint4*)dst)[1] = o1;
  }
}

// ---------------------------------------------------------------------------
// Batched 1024x1024 bf16 transpose: dst[b][d][s] = src[b][s][d]
// ---------------------------------------------------------------------------
__global__ __launch_bounds__(256) void transpose_sq_kernel(
    const bf16* __restrict__ src, bf16* __restrict__ dst) {
  __shared__ short T[64][72];
  const int tid = threadIdx.x;
  const int b = blockIdx.z;
  const int s0 = blockIdx.x * 64, d0 = blockIdx.y * 64;
  const bf16* sp = src + ((long long)b * NS + s0) * ND + d0;
  {
    const int s = tid >> 2, c = (tid & 3) * 16;
    const uint4 a0 = *(const uint4*)(sp + (long long)s * ND + c);
    const uint4 a1 = *(const uint4*)(sp + (long long)s * ND + c + 8);
    *(uint4*)&T[s][c] = a0; *(uint4*)&T[s][c + 8] = a1;
  }
  __syncthreads();
  {
    const int d = tid >> 2, c = (tid & 3) * 16;
    unsigned wds[8];
    #pragma unroll
    for (int u = 0; u < 8; ++u) {
      const unsigned lo = (unsigned short)T[c + 2 * u][d];
      const unsigned hi = (unsigned short)T[c + 2 * u + 1][d];
      wds[u] = lo | (hi << 16);
    }
    bf16* dp = dst + ((long long)b * ND + d0 + d) * NS + s0 + c;
    uint4 o0, o1;
    o0.x = wds[0]; o0.y = wds[1]; o0.z = wds[2]; o0.w = wds[3];
    o1.x = wds[4]; o1.y = wds[5]; o1.z = wds[6]; o1.w = wds[7];
    ((uint4*)dp)[0] = o0; ((uint4*)dp)[1] = o1;
  }
}

// ---------------------------------------------------------------------------
// Sparse top-k selection from precomputed fp32 scores S[row][1024].
// One WAVE per row (4 rows/block); wave-local radix select.
// ---------------------------------------------------------------------------
__global__ __launch_bounds__(256) void sparse_select_kernel(
    const float* __restrict__ S, bf16* __restrict__ aw)
{
  __shared__ unsigned hist[4][256];
  const int tid = threadIdx.x;
  const int lane = tid & 63;
  const int wv = tid >> 6;
  const long long row = (long long)blockIdx.x * 4 + wv;

  float sv[16];
  const float* sp = S + row * 1024 + lane * 16;
  #pragma unroll
  for (int c = 0; c < 4; ++c) {
    const float4 v = ((const float4*)sp)[c];
    sv[4*c] = v.x; sv[4*c+1] = v.y; sv[4*c+2] = v.z; sv[4*c+3] = v.w;
  }
  unsigned key[16];
  #pragma unroll
  for (int j = 0; j < 16; ++j) {
    const unsigned u = __float_as_uint(sv[j]);
    key[j] = (u & 0x80000000u) ? ~u : (u | 0x80000000u);  // order-preserving
  }

  unsigned pref = 0u;
  int need = NTOPK;
  #pragma unroll
  for (int p = 3; p >= 0; --p) {
    *(uint4*)&hist[wv][lane * 4] = (uint4){0u, 0u, 0u, 0u};
    __syncthreads();
    const int sh = (p + 1) * 8;
    #pragma unroll
    for (int j = 0; j < 16; ++j) {
      const bool part = (p == 3) || ((key[j] >> sh) == pref);
      if (part) atomicAdd(&hist[wv][(key[j] >> (p * 8)) & 255u], 1u);
    }
    __syncthreads();
    const unsigned h0 = hist[wv][4*lane],     h1 = hist[wv][4*lane + 1];
    const unsigned h2 = hist[wv][4*lane + 2], h3 = hist[wv][4*lane + 3];
    const unsigned s3 = h3, s2 = h2 + s3, s1 = h1 + s2, s0 = h0 + s1;
    unsigned sum = s0;                      // suffix sum over lanes >= lane
    #pragma unroll
    for (int d2 = 1; d2 < 64; d2 <<= 1) {
      const unsigned t = __shfl_down(sum, d2, 64);
      if (lane < 64 - d2) sum += t;
    }
    const unsigned above = sum - s0;
    const unsigned cum[4]  = {above + s0, above + s1, above + s2, above + s3};
    const unsigned next[4] = {above + s1, above + s2, above + s3, above};
    unsigned candPref = 0u; int candNeed = 0; bool has = false;
    #pragma unroll
    for (int i = 0; i < 4; ++i) {
      if ((int)cum[i] >= need && (int)next[i] < need) {
        has = true;
        candPref = (pref << 8) | (unsigned)(4 * lane + i);
        candNeed = need - (int)next[i];
      }
    }
    const unsigned long long m = __ballot(has);
    const int srcLane = (int)(__ffsll((long long)m) - 1);
    pref = (unsigned)__shfl((int)candPref, srcLane, 64);
    need = __shfl(candNeed, srcLane, 64);
  }

  const unsigned T = pref;                  // 204th-largest key
  const unsigned tb = (T & 0x80000000u) ? (T ^ 0x80000000u) : ~T;
  const float thr = __uint_as_float(tb);

  float wvv[16];
  float psTop = 0.f, psAll = 0.f;
  #pragma unroll
  for (int j = 0; j < 16; ++j) {
    const float e = __expf(sv[j] - thr);
    psAll += e;
    const float wt = (key[j] >= T) ? e : 0.f;
    psTop += wt;
    wvv[j] = wt;
  }
  #pragma unroll
  for (int s = 1; s < 64; s <<= 1) {
    psTop += __shfl_xor(psTop, s, 64);
    psAll += __shfl_xor(psAll, s, 64);
  }
  const float inv = 1.f / (psTop + 1e-9f * psAll);

  uint4 o0, o1;
  o0.x = (unsigned)bfbits(wvv[0]*inv)  | ((unsigned)bfbits(wvv[1]*inv)  << 16);
  o0.y = (unsigned)bfbits(wvv[2]*inv)  | ((unsigned)bfbits(wvv[3]*inv)  << 16);
  o0.z = (unsigned)bfbits(wvv[4]*inv)  | ((unsigned)bfbits(wvv[5]*inv)  << 16);
  o0.w = (unsigned)bfbits(wvv[6]*inv)  | ((unsigned)bfbits(wvv[7]*inv)  << 16);
  o1.x = (unsigned)bfbits(wvv[8]*inv)  | ((unsigned)bfbits(wvv[9]*inv)  << 16);
  o1.y = (unsigned)bfbits(wvv[10]*inv) | ((unsigned)bfbits(wvv[11]*inv) << 16);
  o1.z = (unsigned)bfbits(wvv[12]*inv) | ((unsigned)bfbits(wvv[13]*inv) << 16);
  o1.w = (unsigned)bfbits(wvv[14]*inv) | ((unsigned)bfbits(wvv[15]*inv) << 16);
  bf16* op = aw + row * 1024 + lane * 16;
  ((uint4*)op)[0] = o0; ((uint4*)op)[1] = o1;
}

// ---------------------------------------------------------------------------
// fused = sig*dense + (1-sig)*sparse ; x1 = LN1(src + fused)  (bf16 out)
// ---------------------------------------------------------------------------
__global__ __launch_bounds__(256) void fuse_ln1_kernel(
    const float* __restrict__ src, const bf16* __restrict__ dense,
    const bf16* __restrict__ sparse, const float* __restrict__ lam,
    const float* __restrict__ g, const float* __restrict__ beta,
    bf16* __restrict__ x1)
{
  __shared__ float y[ND];
  __shared__ float rbuf[256];
  const int tid = threadIdx.x;
  const size_t base = (size_t)blockIdx.x * ND;
  const float sig = 1.f / (1.f + __expf(-lam[0]));
  const float c1 = 1.f - sig;
  float s1 = 0.f, s2 = 0.f;
  #pragma unroll
  for (int j = 0; j < 4; ++j) {
    const int i = tid + (j << 8);
    const float v = src[base + i] + sig * b2f(dense[base + i]) + c1 * b2f(sparse[base + i]);
    y[i] = v; s1 += v; s2 += v * v;
  }
  const float sum1 = block_sum_256(s1, rbuf, tid);
  const float sum2 = block_sum_256(s2, rbuf, tid);
  const float mean = sum1 * (1.f / ND);
  const float var  = sum2 * (1.f / ND) - mean * mean;
  const float rstd = rsqrtf(var + 1e-5f);
  #pragma unroll
  for (int j = 0; j < 4; ++j) {
    const int i = tid + (j << 8);
    x1[base + i] = f2b((y[i] - mean) * rstd * g[i] + beta[i]);
  }
}

// out = LN2(x1 + ff)  (fp32 out; ff is bf16)
__global__ __launch_bounds__(256) void ln2_kernel(
    const bf16* __restrict__ x1, const bf16* __restrict__ ff,
    const float* __restrict__ g, const float* __restrict__ beta,
    float* __restrict__ outp)
{
  __shared__ float y[ND];
  __shared__ float rbuf[256];
  const int tid = threadIdx.x;
  const size_t base = (size_t)blockIdx.x * ND;
  float s1 = 0.f, s2 = 0.f;
  #pragma unroll
  for (int j = 0; j < 4; ++j) {
    const int i = tid + (j << 8);
    const float v = b2f(x1[base + i]) + b2f(ff[base + i]);
    y[i] = v; s1 += v; s2 += v * v;
  }
  const float sum1 = block_sum_256(s1, rbuf, tid);
  const float sum2 = block_sum_256(s2, rbuf, tid);
  const float mean = sum1 * (1.f / ND);
  const float var  = sum2 * (1.f / ND) - mean * mean;
  const float rstd = rsqrtf(var + 1e-5f);
  #pragma unroll
  for (int j = 0; j < 4; ++j) {
    const int i = tid + (j << 8);
    outp[base + i] = (y[i] - mean) * rstd * g[i] + beta[i];
  }
}

// ---------------------------------------------------------------------------
extern "C" void kernel_launch(void* const* d_in, const int* in_sizes, int n_in,
                              void* d_out, int out_size, void* d_ws, size_t ws_size,
                              hipStream_t stream)
{
  const float* src        = (const float*)d_in[0];
  const float* in_proj_w  = (const float*)d_in[1];
  const float* in_proj_b  = (const float*)d_in[2];
  const float* out_proj_w = (const float*)d_in[3];
  const float* out_proj_b = (const float*)d_in[4];
  const float* Qp_w  = (const float*)d_in[5];
  const float* Qp_b  = (const float*)d_in[6];
  const float* Kp_w  = (const float*)d_in[7];
  const float* Kp_b  = (const float*)d_in[8];
  const float* Vp_w  = (const float*)d_in[9];
  const float* Vp_b  = (const float*)d_in[10];
  const float* lam   = (const float*)d_in[11];
  const float* ff1_w = (const float*)d_in[12];
  const float* ff1_b = (const float*)d_in[13];
  const float* ff2_w = (const float*)d_in[14];
  const float* ff2_b = (const float*)d_in[15];
  const float* ln1_g = (const float*)d_in[16];
  const float* ln1_b = (const float*)d_in[17];
  const float* ln2_g = (const float*)d_in[18];
  const float* ln2_b = (const float*)d_in[19];
  (void)in_sizes; (void)n_in; (void)out_size; (void)ws_size;

  // --------- workspace layout (total ~131.5 MB; 136.3 MB proven safe in R2)
  char* ws = (char*)d_ws;
  size_t off = 0;
  auto take = [&](size_t bytes) -> void* {
    void* p = ws + off; off += (bytes + 255) & ~(size_t)255; return p;
  };
  bf16*  src_bf  = (bf16*) take((size_t)NM * ND * 2);          //  8.4 MB
  bf16*  w_qkv   = (bf16*) take((size_t)3 * ND * ND * 2);      //  6.3 MB
  bf16*  w_out   = (bf16*) take((size_t)ND * ND * 2);          //  2.1 MB
  bf16*  w_vp    = (bf16*) take((size_t)ND * ND * 2);          //  2.1 MB
  bf16*  w_ff1   = (bf16*) take((size_t)NDFF * ND * 2);        //  8.4 MB
  bf16*  w_ff2   = (bf16*) take((size_t)ND * NDFF * 2);        //  8.4 MB
  bf16*  w_qk    = (bf16*) take((size_t)128 * ND * 2);         //  0.26 MB
  float* bias_qk = (float*)take(128 * 4);
  const size_t mark = off;                                     // reuse point
  bf16*  qkv     = (bf16*) take((size_t)NM * 3 * ND * 2);      // 25.2 MB [dead after attn]
  bf16*  S_b     = (bf16*) take((size_t)NH * NS * NS * 2);     // 33.5 MB [dead after attn]
  bf16*  Vt_b    = (bf16*) take((size_t)NH * NDH * NS * 2);    //  2.1 MB [dead after attn]
  bf16*  ctx     = (bf16*) take((size_t)NM * ND * 2);          //  8.4 MB [dead after step 3]
  bf16*  dense   = (bf16*) take((size_t)NM * ND * 2);          //  8.4 MB
  bf16*  QKs_bf  = (bf16*) take((size_t)NM * 128 * 2);         //  1.05 MB
  bf16*  Vsp     = (bf16*) take((size_t)NM * ND * 2);          //  8.4 MB
  bf16*  sparse  = (bf16*) take((size_t)NM * ND * 2);          //  8.4 MB
  // aliases into dead regions (qkv+S_b dead after the attention loop):
  bf16*  x1    = (bf16*)(ws + mark);                                       // [0, 8.4M)
  bf16*  h1    = (bf16*)(ws + mark + (size_t)NM * ND * 2);                 // [8.4, 42.0M)
  bf16*  ffout = (bf16*)(ws + mark + (size_t)NM * ND * 2 + (size_t)NM * NDFF * 2); // [42.0, 50.4M)
  bf16*  aw    = (bf16*)(ws + mark + 2 * (size_t)NM * ND * 2 + (size_t)NM * NDFF * 2); // [50.4, 58.8M)
  float* S_sp  = (float*)(ws + mark + (size_t)NM * ND * 2);    // [8.4, 25.2M): written 4b,
                                                               // read 6a, dead before h1
  bf16*  Vsp_t = (bf16*)ctx;  // ctx dead after step 3

  const dim3 blk(256);
  auto cast = [&](const float* in, bf16* out, int n) {
    cast_kernel<<<dim3((n + 1023) / 1024), blk, 0, stream>>>(in, out, n);
  };
  // 0. fp32 -> bf16 conversions
  cast(src,        src_bf, NM * ND);
  cast(in_proj_w,  w_qkv,  3 * ND * ND);
  cast(out_proj_w, w_out,  ND * ND);
  cast(Vp_w,       w_vp,   ND * ND);
  cast(ff1_w,      w_ff1,  NDFF * ND);
  cast(ff2_w,      w_ff2,  ND * NDFF);
  pack_qk_kernel<<<dim3(128), blk, 0, stream>>>(Qp_w, Kp_w, Qp_b, Kp_b, w_qk, bias_qk);

  // 1. qkv = src @ in_proj^T + b   [4096,3072] bf16
  mfma_gemm<128,128,1,0,0><<<dim3(3*ND/128, NM/128, 1), blk, 0, stream>>>(
      src_bf, w_qkv, in_proj_b, qkv, ND, ND, ND, 3*ND, 0,0, 0,0, 0,0, 1.f);

  // 2. dense MHA, per batch (S_b / Vt_b reused across b)
  for (int b = 0; b < NB; ++b) {
    const bf16* qkv_b = qkv + (size_t)b * NS * 3 * ND;
    mfma_gemm<128,128,0,0,0><<<dim3(NS/128, NS/128, NH), blk, 0, stream>>>(
        qkv_b, qkv_b + ND, nullptr, S_b, NDH, 3*ND, 3*ND, NS,
        0, NDH, 0, NDH, 0, (long long)NS*NS, 0.125f);
    softmax_kernel<<<dim3(NH*NS/4), blk, 0, stream>>>(S_b);
    transpose_v_kernel<<<dim3(NS/64, NH), blk, 0, stream>>>(qkv_b, Vt_b);
    mfma_gemm<256,64,0,0,0><<<dim3(1, NS/256, NH), blk, 0, stream>>>(
        S_b, Vt_b, nullptr, ctx + (size_t)b * NS * ND, NS, NS, NS, ND,
        0, (long long)NS*NS, 0, (long long)NDH*NS, 0, NDH, 1.f);
  }

  // 3. dense_output = ctx @ out_proj^T + b  (bf16)
  mfma_gemm<128,128,1,0,0><<<dim3(ND/128, NM/128, 1), blk, 0, stream>>>(
      ctx, w_out, out_proj_b, dense, ND, ND, ND, ND, 0,0, 0,0, 0,0, 1.f);
  // 4. QKs_bf = src @ [Qp;Kp]^T + b  (bf16 [4096][128])
  mfma_gemm<128,128,1,0,0><<<dim3(1, NM/128, 1), blk, 0, stream>>>(
      src_bf, w_qk, bias_qk, QKs_bf, ND, ND, ND, 128, 0,0, 0,0, 0,0, 1.f);
  // 4b. S_sp[b] = (Qs Ks^T)/8  fp32, batched over b  (M=N=1024, K=64)
  mfma_gemm<128,128,0,0,1><<<dim3(NS/128, NS/128, NB), blk, 0, stream>>>(
      QKs_bf, QKs_bf + 64, nullptr, S_sp, 64, 128, 128, NS,
      0, (long long)NS*128, 0, (long long)NS*128, 0, (long long)NS*NS, 0.125f);
  // 5. Vsp = src @ Vp^T + b  (bf16)
  mfma_gemm<128,128,1,0,0><<<dim3(ND/128, NM/128, 1), blk, 0, stream>>>(
      src_bf, w_vp, Vp_b, Vsp, ND, ND, ND, ND, 0,0, 0,0, 0,0, 1.f);
  // 5b. Vsp_t[b][d][s] = Vsp[b][s][d]   (ctx slot reused)
  transpose_sq_kernel<<<dim3(NS/64, ND/64, NB), blk, 0, stream>>>(Vsp, Vsp_t);
  // 6a. top-k select + normalized weights -> aw (bf16), one wave per row
  sparse_select_kernel<<<dim3(NM/4), blk, 0, stream>>>(S_sp, aw);
  // 6b. sparse = aw @ Vsp^T  (batched per b, MFMA)
  mfma_gemm<128,128,0,0,0><<<dim3(ND/128, NS/128, NB), blk, 0, stream>>>(
      aw, Vsp_t, nullptr, sparse, NS, NS, NS, ND,
      0, (long long)NS*ND, 0, (long long)ND*NS, 0, (long long)NS*ND, 1.f);
  // 7. fuse + residual + LN1 -> x1 (bf16)  [qkv/S_b dead; x1 aliases them]
  fuse_ln1_kernel<<<dim3(NM), blk, 0, stream>>>(src, dense, sparse, lam, ln1_g, ln1_b, x1);
  // 8. h1 = relu(x1 @ ff1^T + b)  (bf16)
  mfma_gemm<128,128,1,1,0><<<dim3(NDFF/128, NM/128, 1), blk, 0, stream>>>(
      x1, w_ff1, ff1_b, h1, ND, ND, ND, NDFF, 0,0, 0,0, 0,0, 1.f);
  // 9. ff = h1 @ ff2^T + b  (bf16)
  mfma_gemm<128,128,1,0,0><<<dim3(ND/128, NM/128, 1), blk, 0, stream>>>(
      h1, w_ff2, ff2_b, ffout, NDFF, NDFF, NDFF, ND, 0,0, 0,0, 0,0, 1.f);
  // 10. out = LN2(x1 + ff)  (fp32)
  ln2_kernel<<<dim3(NM), blk, 0, stream>>>(x1, ffout, ln2_g, ln2_b, (float*)d_out);
}

// Round 9
// 639.883 us; speedup vs baseline: 6.3492x; 1.0620x over previous
//
#include <hip/hip_runtime.h>
#include <hip/hip_bf16.h>
#include <math.h>

typedef __hip_bfloat16 bf16;
typedef __attribute__((ext_vector_type(8))) short short8;
typedef __attribute__((ext_vector_type(4))) float f32x4;

// Problem constants
#define NB 4
#define NS 1024
#define ND 1024
#define NH 16
#define NDH 64
#define NR 64
#define NDFF 4096
#define NM (NB*NS)     // 4096 rows
#define NTOPK 204      // int(1024*0.2)

static __device__ __forceinline__ float b2f(bf16 x) { return __bfloat162float(x); }
static __device__ __forceinline__ bf16  f2b(float x) { return __float2bfloat16(x); }
static __device__ __forceinline__ unsigned short bfbits(float x) {
  bf16 h = __float2bfloat16(x);
  return *reinterpret_cast<unsigned short*>(&h);
}

// async global->LDS, 16B per lane; LDS dest = wave-uniform base + lane*16
static __device__ __forceinline__ void gload_lds16(const void* g, void* l) {
  __builtin_amdgcn_global_load_lds(
      (const __attribute__((address_space(1))) void*)g,
      (__attribute__((address_space(3))) void*)l, 16, 0, 0);
}

// 8 consecutive bf16 -> fp32 (one 16B load)
static __device__ __forceinline__ void ld8(const bf16* p, float* d) {
  const uint4 u = *(const uint4*)p;
  d[0] = __uint_as_float((u.x & 0xffffu) << 16);
  d[1] = __uint_as_float(u.x & 0xffff0000u);
  d[2] = __uint_as_float((u.y & 0xffffu) << 16);
  d[3] = __uint_as_float(u.y & 0xffff0000u);
  d[4] = __uint_as_float((u.z & 0xffffu) << 16);
  d[5] = __uint_as_float(u.z & 0xffff0000u);
  d[6] = __uint_as_float((u.w & 0xffffu) << 16);
  d[7] = __uint_as_float(u.w & 0xffff0000u);
}

static __device__ __forceinline__ float block_sum_256(float v, float* rbuf, int tid) {
  rbuf[tid] = v;
  __syncthreads();
  #pragma unroll
  for (int st = 128; st > 0; st >>= 1) {
    if (tid < st) rbuf[tid] += rbuf[tid + st];
    __syncthreads();
  }
  const float r = rbuf[0];
  __syncthreads();
  return r;
}

// ---------------------------------------------------------------------------
// fp32 -> bf16 cast (n multiple of 4)
// ---------------------------------------------------------------------------
__global__ __launch_bounds__(256) void cast_kernel(const float* __restrict__ in,
                                                   bf16* __restrict__ out, int n) {
  const int i = (blockIdx.x * 256 + threadIdx.x) * 4;
  if (i < n) {
    const float4 v = *(const float4*)(in + i);
    uint2 o;
    o.x = (unsigned)bfbits(v.x) | ((unsigned)bfbits(v.y) << 16);
    o.y = (unsigned)bfbits(v.z) | ((unsigned)bfbits(v.w) << 16);
    *(uint2*)(out + i) = o;
  }
}

// Concat Qp_w/Kp_w -> bf16 [128][1024], Qp_b/Kp_b -> fp32 [128]
__global__ __launch_bounds__(256) void pack_qk_kernel(
    const float* __restrict__ Qw, const float* __restrict__ Kw,
    const float* __restrict__ Qb, const float* __restrict__ Kb,
    bf16* __restrict__ w, float* __restrict__ bias) {
  const int r = blockIdx.x;  // 0..127
  const float* srcw = (r < 64) ? (Qw + (size_t)r * ND) : (Kw + (size_t)(r - 64) * ND);
  for (int i = threadIdx.x; i < ND; i += 256) w[(size_t)r * ND + i] = f2b(srcw[i]);
  if (r == 0)
    for (int i = threadIdx.x; i < 128; i += 256)
      bias[i] = (i < 64) ? Qb[i] : Kb[i - 64];
}

// ---------------------------------------------------------------------------
// Generic batched MFMA GEMM: C = scale*(A @ W^T) (+bias), bf16 in.
// Double-buffered BK=32 software pipeline: stage tile k+1 (global_load_lds
// width=16, m97 geometry) into the idle LDS buffer, run 16 MFMAs on tile k,
// then one barrier (its vmcnt drain overlaps the compute phase). One barrier
// per K-tile; LDS = 2x(BM+BN)x32 bf16.
// 256 threads = 4 waves in a 2x2 grid; wave tile = (BM/2)x(BN/2).
// Instantiated as 128x128 (wave 64x64, acc 4x4) and 128x64 (wave 64x32,
// acc 4x2 -> 512-block grids for the small GEMMs = 2 blocks/CU).
// Batch z: off = (z>>4)*Hi + (z&15)*Lo.  K multiple of 32, >= 64.
// XCD-compact swizzle when gridDim.x%8==0 (perf heuristic only).
// ---------------------------------------------------------------------------
template<int BM, int BN, int BIAS, int RELU, int OUTF32>
__global__ __launch_bounds__(256) void mfma_gemm(
    const bf16* __restrict__ A, const bf16* __restrict__ W,
    const float* __restrict__ bias, void* __restrict__ C,
    int K, int lda, int ldb, int ldc,
    long long aHi, long long aLo, long long bHi, long long bLo,
    long long cHi, long long cLo, float scale)
{
  constexpr int WTM = BM / 2;     // 64
  constexpr int WTN = BN / 2;     // 64 or 32
  constexpr int AM = WTM / 16;    // 4
  constexpr int AN = WTN / 16;    // 4 or 2
  __shared__ short As[2][BM * 32];
  __shared__ short Bs[2][BN * 32];
  const int tid  = threadIdx.x;
  const int lane = tid & 63;
  const int w    = tid >> 6;
  const int z    = blockIdx.z;
  const long long aOff = (long long)(z >> 4) * aHi + (long long)(z & 15) * aLo;
  const long long bOff = (long long)(z >> 4) * bHi + (long long)(z & 15) * bLo;
  const long long cOff = (long long)(z >> 4) * cHi + (long long)(z & 15) * cLo;

  int bx = blockIdx.x, by = blockIdx.y;
  if ((gridDim.x & 7) == 0) {
    const unsigned lin = blockIdx.y * gridDim.x + blockIdx.x;
    const unsigned Wd = gridDim.x >> 3;
    const unsigned xcd = lin & 7, i = lin >> 3;
    bx = (int)(xcd * Wd + (i % Wd));
    by = (int)(i / Wd);
  }
  const int m0 = by * BM;
  const int n0 = bx * BN;
  const int wr = w >> 1, wc = w & 1;
  const int lm = lane & 15, quad = lane >> 4;

  f32x4 acc[AM][AN];
  #pragma unroll
  for (int i = 0; i < AM; ++i)
    #pragma unroll
    for (int j = 0; j < AN; ++j) acc[i][j] = (f32x4){0.f, 0.f, 0.f, 0.f};

  const int sr = lane >> 2;        // 0..15 (row within 16-row staging segment)
  const int sc = (lane & 3) << 3;  // 0,8,16,24
  const bf16* Ab = A + aOff;
  const bf16* Bb = W + bOff;

  auto stage = [&](int buf, int k0) {
    #pragma unroll
    for (int t = 0; t < BM / 64; ++t) {
      const int row = w * (BM / 4) + t * 16;
      gload_lds16(Ab + (long long)(m0 + row + sr) * lda + k0 + sc, &As[buf][row * 32]);
    }
    #pragma unroll
    for (int t = 0; t < BN / 64; ++t) {
      const int row = w * (BN / 4) + t * 16;
      gload_lds16(Bb + (long long)(n0 + row + sr) * ldb + k0 + sc, &Bs[buf][row * 32]);
    }
  };
  auto compute = [&](int buf) {
    short8 af[AM], bfr[AN];
    #pragma unroll
    for (int i = 0; i < AM; ++i)
      af[i] = *(const short8*)&As[buf][(wr * WTM + i * 16 + lm) * 32 + quad * 8];
    #pragma unroll
    for (int j = 0; j < AN; ++j)
      bfr[j] = *(const short8*)&Bs[buf][(wc * WTN + j * 16 + lm) * 32 + quad * 8];
    #pragma unroll
    for (int i = 0; i < AM; ++i)
      #pragma unroll
      for (int j = 0; j < AN; ++j)
        acc[i][j] = __builtin_amdgcn_mfma_f32_16x16x32_bf16(af[i], bfr[j], acc[i][j], 0, 0, 0);
  };

  stage(0, 0);
  __syncthreads();               // drain preload
  int cur = 0;
  for (int k0 = 32; k0 < K; k0 += 32) {
    stage(cur ^ 1, k0);          // async prefetch into idle buffer
    compute(cur);                // MFMAs overlap the in-flight loads
    __syncthreads();             // drains prefetch; all reads of cur done
    cur ^= 1;
  }
  compute(cur);                  // last tile, no trailing barrier needed

  #pragma unroll
  for (int i = 0; i < AM; ++i) {
    #pragma unroll
    for (int j = 0; j < AN; ++j) {
      const int n = n0 + wc * WTN + j * 16 + lm;
      const float bj = BIAS ? bias[n] : 0.f;
      #pragma unroll
      for (int rr = 0; rr < 4; ++rr) {
        const int m = m0 + wr * WTM + i * 16 + quad * 4 + rr;
        float v = acc[i][j][rr] * scale + bj;
        if (RELU) v = fmaxf(v, 0.f);
        const long long co = cOff + (long long)m * ldc + n;
        if (OUTF32) ((float*)C)[co] = v;
        else        ((bf16*)C)[co] = f2b(v);
      }
    }
  }
}

// ---------------------------------------------------------------------------
// Row softmax in place over bf16 [rows][1024]; one wave per row.
// ---------------------------------------------------------------------------
__global__ __launch_bounds__(256) void softmax_kernel(bf16* __restrict__ P) {
  const int tid = threadIdx.x;
  const int lane = tid & 63;
  const int w = tid >> 6;
  const long long row = (long long)blockIdx.x * 4 + w;
  bf16* p = P + row * 1024 + lane * 16;
  float v[16];
  ld8(p, v); ld8(p + 8, v + 8);
  float m = v[0];
  #pragma unroll
  for (int t = 1; t < 16; ++t) m = fmaxf(m, v[t]);
  #pragma unroll
  for (int s = 1; s < 64; s <<= 1) m = fmaxf(m, __shfl_xor(m, s, 64));
  float sum = 0.f;
  #pragma unroll
  for (int t = 0; t < 16; ++t) { v[t] = __expf(v[t] - m); sum += v[t]; }
  #pragma unroll
  for (int s = 1; s < 64; s <<= 1) sum += __shfl_xor(sum, s, 64);
  const float inv = 1.f / sum;
  uint4 o0, o1;
  o0.x = (unsigned)bfbits(v[0]*inv)  | ((unsigned)bfbits(v[1]*inv)  << 16);
  o0.y = (unsigned)bfbits(v[2]*inv)  | ((unsigned)bfbits(v[3]*inv)  << 16);
  o0.z = (unsigned)bfbits(v[4]*inv)  | ((unsigned)bfbits(v[5]*inv)  << 16);
  o0.w = (unsigned)bfbits(v[6]*inv)  | ((unsigned)bfbits(v[7]*inv)  << 16);
  o1.x = (unsigned)bfbits(v[8]*inv)  | ((unsigned)bfbits(v[9]*inv)  << 16);
  o1.y = (unsigned)bfbits(v[10]*inv) | ((unsigned)bfbits(v[11]*inv) << 16);
  o1.z = (unsigned)bfbits(v[12]*inv) | ((unsigned)bfbits(v[13]*inv) << 16);
  o1.w = (unsigned)bfbits(v[14]*inv) | ((unsigned)bfbits(v[15]*inv) << 16);
  ((uint4*)p)[0] = o0; ((uint4*)p)[1] = o1;
}

// ---------------------------------------------------------------------------
// Per-batch: Vt_b[h][d][s] = qkv_b[s, 2048 + h*64 + d]  (64x64 LDS transpose)
// ---------------------------------------------------------------------------
__global__ __launch_bounds__(256) void transpose_v_kernel(
    const bf16* __restrict__ qkv_b, bf16* __restrict__ Vt_b) {
  __shared__ short T[64][72];
  const int tid = threadIdx.x;
  const int h = blockIdx.y;
  const int s0 = blockIdx.x * 64;
  const bf16* src = qkv_b + (long long)s0 * 3072 + 2 * ND + h * 64;
  {
    const int s = tid >> 2, c = (tid & 3) * 16;
    const uint4 a0 = *(const uint4*)(src + (long long)s * 3072 + c);
    const uint4 a1 = *(const uint4*)(src + (long long)s * 3072 + c + 8);
    *(uint4*)&T[s][c] = a0; *(uint4*)&T[s][c + 8] = a1;
  }
  __syncthreads();
  {
    const int d = tid >> 2, c = (tid & 3) * 16;
    unsigned wds[8];
    #pragma unroll
    for (int u = 0; u < 8; ++u) {
      const unsigned lo = (unsigned short)T[c + 2 * u][d];
      const unsigned hi = (unsigned short)T[c + 2 * u + 1][d];
      wds[u] = lo | (hi << 16);
    }
    bf16* dst = Vt_b + (long long)h * (NDH * NS) + (long long)d * NS + s0 + c;
    uint4 o0, o1;
    o0.x = wds[0]; o0.y = wds[1]; o0.z = wds[2]; o0.w = wds[3];
    o1.x = wds[4]; o1.y = wds[5]; o1.z = wds[6]; o1.w = wds[7];
    ((uint4*)dst)[0] = o0; ((uint4*)dst)[1] = o1;
  }
}

// ---------------------------------------------------------------------------
// Batched 1024x1024 bf16 transpose: dst[b][d][s] = src[b][s][d]
// ---------------------------------------------------------------------------
__global__ __launch_bounds__(256) void transpose_sq_kernel(
    const bf16* __restrict__ src, bf16* __restrict__ dst) {
  __shared__ short T[64][72];
  const int tid = threadIdx.x;
  const int b = blockIdx.z;
  const int s0 = blockIdx.x * 64, d0 = blockIdx.y * 64;
  const bf16* sp = src + ((long long)b * NS + s0) * ND + d0;
  {
    const int s = tid >> 2, c = (tid & 3) * 16;
    const uint4 a0 = *(const uint4*)(sp + (long long)s * ND + c);
    const uint4 a1 = *(const uint4*)(sp + (long long)s * ND + c + 8);
    *(uint4*)&T[s][c] = a0; *(uint4*)&T[s][c + 8] = a1;
  }
  __syncthreads();
  {
    const int d = tid >> 2, c = (tid & 3) * 16;
    unsigned wds[8];
    #pragma unroll
    for (int u = 0; u < 8; ++u) {
      const unsigned lo = (unsigned short)T[c + 2 * u][d];
      const unsigned hi = (unsigned short)T[c + 2 * u + 1][d];
      wds[u] = lo | (hi << 16);
    }
    bf16* dp = dst + ((long long)b * ND + d0 + d) * NS + s0 + c;
    uint4 o0, o1;
    o0.x = wds[0]; o0.y = wds[1]; o0.z = wds[2]; o0.w = wds[3];
    o1.x = wds[4]; o1.y = wds[5]; o1.z = wds[6]; o1.w = wds[7];
    ((uint4*)dp)[0] = o0; ((uint4*)dp)[1] = o1;
  }
}

// ---------------------------------------------------------------------------
// Sparse top-k selection from precomputed fp32 scores S[row][1024].
// One WAVE per row (4 rows/block); wave-local radix select.
// ---------------------------------------------------------------------------
__global__ __launch_bounds__(256) void sparse_select_kernel(
    const float* __restrict__ S, bf16* __restrict__ aw)
{
  __shared__ unsigned hist[4][256];
  const int tid = threadIdx.x;
  const int lane = tid & 63;
  const int wv = tid >> 6;
  const long long row = (long long)blockIdx.x * 4 + wv;

  float sv[16];
  const float* sp = S + row * 1024 + lane * 16;
  #pragma unroll
  for (int c = 0; c < 4; ++c) {
    const float4 v = ((const float4*)sp)[c];
    sv[4*c] = v.x; sv[4*c+1] = v.y; sv[4*c+2] = v.z; sv[4*c+3] = v.w;
  }
  unsigned key[16];
  #pragma unroll
  for (int j = 0; j < 16; ++j) {
    const unsigned u = __float_as_uint(sv[j]);
    key[j] = (u & 0x80000000u) ? ~u : (u | 0x80000000u);  // order-preserving
  }

  unsigned pref = 0u;
  int need = NTOPK;
  #pragma unroll
  for (int p = 3; p >= 0; --p) {
    *(uint4*)&hist[wv][lane * 4] = (uint4){0u, 0u, 0u, 0u};
    __syncthreads();
    const int sh = (p + 1) * 8;
    #pragma unroll
    for (int j = 0; j < 16; ++j) {
      const bool part = (p == 3) || ((key[j] >> sh) == pref);
      if (part) atomicAdd(&hist[wv][(key[j] >> (p * 8)) & 255u], 1u);
    }
    __syncthreads();
    const unsigned h0 = hist[wv][4*lane],     h1 = hist[wv][4*lane + 1];
    const unsigned h2 = hist[wv][4*lane + 2], h3 = hist[wv][4*lane + 3];
    const unsigned s3 = h3, s2 = h2 + s3, s1 = h1 + s2, s0 = h0 + s1;
    unsigned sum = s0;                      // suffix sum over lanes >= lane
    #pragma unroll
    for (int d2 = 1; d2 < 64; d2 <<= 1) {
      const unsigned t = __shfl_down(sum, d2, 64);
      if (lane < 64 - d2) sum += t;
    }
    const unsigned above = sum - s0;
    const unsigned cum[4]  = {above + s0, above + s1, above + s2, above + s3};
    const unsigned next[4] = {above + s1, above + s2, above + s3, above};
    unsigned candPref = 0u; int candNeed = 0; bool has = false;
    #pragma unroll
    for (int i = 0; i < 4; ++i) {
      if ((int)cum[i] >= need && (int)next[i] < need) {
        has = true;
        candPref = (pref << 8) | (unsigned)(4 * lane + i);
        candNeed = need - (int)next[i];
      }
    }
    const unsigned long long m = __ballot(has);
    const int srcLane = (int)(__ffsll((long long)m) - 1);
    pref = (unsigned)__shfl((int)candPref, srcLane, 64);
    need = __shfl(candNeed, srcLane, 64);
  }

  const unsigned T = pref;                  // 204th-largest key
  const unsigned tb = (T & 0x80000000u) ? (T ^ 0x80000000u) : ~T;
  const float thr = __uint_as_float(tb);

  float wvv[16];
  float psTop = 0.f, psAll = 0.f;
  #pragma unroll
  for (int j = 0; j < 16; ++j) {
    const float e = __expf(sv[j] - thr);
    psAll += e;
    const float wt = (key[j] >= T) ? e : 0.f;
    psTop += wt;
    wvv[j] = wt;
  }
  #pragma unroll
  for (int s = 1; s < 64; s <<= 1) {
    psTop += __shfl_xor(psTop, s, 64);
    psAll += __shfl_xor(psAll, s, 64);
  }
  const float inv = 1.f / (psTop + 1e-9f * psAll);

  uint4 o0, o1;
  o0.x = (unsigned)bfbits(wvv[0]*inv)  | ((unsigned)bfbits(wvv[1]*inv)  << 16);
  o0.y = (unsigned)bfbits(wvv[2]*inv)  | ((unsigned)bfbits(wvv[3]*inv)  << 16);
  o0.z = (unsigned)bfbits(wvv[4]*inv)  | ((unsigned)bfbits(wvv[5]*inv)  << 16);
  o0.w = (unsigned)bfbits(wvv[6]*inv)  | ((unsigned)bfbits(wvv[7]*inv)  << 16);
  o1.x = (unsigned)bfbits(wvv[8]*inv)  | ((unsigned)bfbits(wvv[9]*inv)  << 16);
  o1.y = (unsigned)bfbits(wvv[10]*inv) | ((unsigned)bfbits(wvv[11]*inv) << 16);
  o1.z = (unsigned)bfbits(wvv[12]*inv) | ((unsigned)bfbits(wvv[13]*inv) << 16);
  o1.w = (unsigned)bfbits(wvv[14]*inv) | ((unsigned)bfbits(wvv[15]*inv) << 16);
  bf16* op = aw + row * 1024 + lane * 16;
  ((uint4*)op)[0] = o0; ((uint4*)op)[1] = o1;
}

// ---------------------------------------------------------------------------
// fused = sig*dense + (1-sig)*sparse ; x1 = LN1(src + fused)  (bf16 out)
// ---------------------------------------------------------------------------
__global__ __launch_bounds__(256) void fuse_ln1_kernel(
    const float* __restrict__ src, const bf16* __restrict__ dense,
    const bf16* __restrict__ sparse, const float* __restrict__ lam,
    const float* __restrict__ g, const float* __restrict__ beta,
    bf16* __restrict__ x1)
{
  __shared__ float y[ND];
  __shared__ float rbuf[256];
  const int tid = threadIdx.x;
  const size_t base = (size_t)blockIdx.x * ND;
  const float sig = 1.f / (1.f + __expf(-lam[0]));
  const float c1 = 1.f - sig;
  float s1 = 0.f, s2 = 0.f;
  #pragma unroll
  for (int j = 0; j < 4; ++j) {
    const int i = tid + (j << 8);
    const float v = src[base + i] + sig * b2f(dense[base + i]) + c1 * b2f(sparse[base + i]);
    y[i] = v; s1 += v; s2 += v * v;
  }
  const float sum1 = block_sum_256(s1, rbuf, tid);
  const float sum2 = block_sum_256(s2, rbuf, tid);
  const float mean = sum1 * (1.f / ND);
  const float var  = sum2 * (1.f / ND) - mean * mean;
  const float rstd = rsqrtf(var + 1e-5f);
  #pragma unroll
  for (int j = 0; j < 4; ++j) {
    const int i = tid + (j << 8);
    x1[base + i] = f2b((y[i] - mean) * rstd * g[i] + beta[i]);
  }
}

// out = LN2(x1 + ff)  (fp32 out; ff is bf16)
__global__ __launch_bounds__(256) void ln2_kernel(
    const bf16* __restrict__ x1, const bf16* __restrict__ ff,
    const float* __restrict__ g, const float* __restrict__ beta,
    float* __restrict__ outp)
{
  __shared__ float y[ND];
  __shared__ float rbuf[256];
  const int tid = threadIdx.x;
  const size_t base = (size_t)blockIdx.x * ND;
  float s1 = 0.f, s2 = 0.f;
  #pragma unroll
  for (int j = 0; j < 4; ++j) {
    const int i = tid + (j << 8);
    const float v = b2f(x1[base + i]) + b2f(ff[base + i]);
    y[i] = v; s1 += v; s2 += v * v;
  }
  const float sum1 = block_sum_256(s1, rbuf, tid);
  const float sum2 = block_sum_256(s2, rbuf, tid);
  const float mean = sum1 * (1.f / ND);
  const float var  = sum2 * (1.f / ND) - mean * mean;
  const float rstd = rsqrtf(var + 1e-5f);
  #pragma unroll
  for (int j = 0; j < 4; ++j) {
    const int i = tid + (j << 8);
    outp[base + i] = (y[i] - mean) * rstd * g[i] + beta[i];
  }
}

// ---------------------------------------------------------------------------
extern "C" void kernel_launch(void* const* d_in, const int* in_sizes, int n_in,
                              void* d_out, int out_size, void* d_ws, size_t ws_size,
                              hipStream_t stream)
{
  const float* src        = (const float*)d_in[0];
  const float* in_proj_w  = (const float*)d_in[1];
  const float* in_proj_b  = (const float*)d_in[2];
  const float* out_proj_w = (const float*)d_in[3];
  const float* out_proj_b = (const float*)d_in[4];
  const float* Qp_w  = (const float*)d_in[5];
  const float* Qp_b  = (const float*)d_in[6];
  const float* Kp_w  = (const float*)d_in[7];
  const float* Kp_b  = (const float*)d_in[8];
  const float* Vp_w  = (const float*)d_in[9];
  const float* Vp_b  = (const float*)d_in[10];
  const float* lam   = (const float*)d_in[11];
  const float* ff1_w = (const float*)d_in[12];
  const float* ff1_b = (const float*)d_in[13];
  const float* ff2_w = (const float*)d_in[14];
  const float* ff2_b = (const float*)d_in[15];
  const float* ln1_g = (const float*)d_in[16];
  const float* ln1_b = (const float*)d_in[17];
  const float* ln2_g = (const float*)d_in[18];
  const float* ln2_b = (const float*)d_in[19];
  (void)in_sizes; (void)n_in; (void)out_size; (void)ws_size;

  // --------- workspace layout (total ~131.5 MB; 136.3 MB proven safe in R2)
  char* ws = (char*)d_ws;
  size_t off = 0;
  auto take = [&](size_t bytes) -> void* {
    void* p = ws + off; off += (bytes + 255) & ~(size_t)255; return p;
  };
  bf16*  src_bf  = (bf16*) take((size_t)NM * ND * 2);          //  8.4 MB
  bf16*  w_qkv   = (bf16*) take((size_t)3 * ND * ND * 2);      //  6.3 MB
  bf16*  w_out   = (bf16*) take((size_t)ND * ND * 2);          //  2.1 MB
  bf16*  w_vp    = (bf16*) take((size_t)ND * ND * 2);          //  2.1 MB
  bf16*  w_ff1   = (bf16*) take((size_t)NDFF * ND * 2);        //  8.4 MB
  bf16*  w_ff2   = (bf16*) take((size_t)ND * NDFF * 2);        //  8.4 MB
  bf16*  w_qk    = (bf16*) take((size_t)128 * ND * 2);         //  0.26 MB
  float* bias_qk = (float*)take(128 * 4);
  const size_t mark = off;                                     // reuse point
  bf16*  qkv     = (bf16*) take((size_t)NM * 3 * ND * 2);      // 25.2 MB [dead after attn]
  bf16*  S_b     = (bf16*) take((size_t)NH * NS * NS * 2);     // 33.5 MB [dead after attn]
  bf16*  Vt_b    = (bf16*) take((size_t)NH * NDH * NS * 2);    //  2.1 MB [dead after attn]
  bf16*  ctx     = (bf16*) take((size_t)NM * ND * 2);          //  8.4 MB [dead after step 3]
  bf16*  dense   = (bf16*) take((size_t)NM * ND * 2);          //  8.4 MB
  bf16*  QKs_bf  = (bf16*) take((size_t)NM * 128 * 2);         //  1.05 MB
  bf16*  Vsp     = (bf16*) take((size_t)NM * ND * 2);          //  8.4 MB
  bf16*  sparse  = (bf16*) take((size_t)NM * ND * 2);          //  8.4 MB
  // aliases into dead regions (qkv+S_b dead after the attention loop):
  bf16*  x1    = (bf16*)(ws + mark);                                       // [0, 8.4M)
  bf16*  h1    = (bf16*)(ws + mark + (size_t)NM * ND * 2);                 // [8.4, 42.0M)
  bf16*  ffout = (bf16*)(ws + mark + (size_t)NM * ND * 2 + (size_t)NM * NDFF * 2); // [42.0, 50.4M)
  bf16*  aw    = (bf16*)(ws + mark + 2 * (size_t)NM * ND * 2 + (size_t)NM * NDFF * 2); // [50.4, 58.8M)
  float* S_sp  = (float*)(ws + mark + (size_t)NM * ND * 2);    // [8.4, 25.2M): written 4b,
                                                               // read 6a, dead before h1
  bf16*  Vsp_t = (bf16*)ctx;  // ctx dead after step 3

  const dim3 blk(256);
  auto cast = [&](const float* in, bf16* out, int n) {
    cast_kernel<<<dim3((n + 1023) / 1024), blk, 0, stream>>>(in, out, n);
  };
  // 0. fp32 -> bf16 conversions
  cast(src,        src_bf, NM * ND);
  cast(in_proj_w,  w_qkv,  3 * ND * ND);
  cast(out_proj_w, w_out,  ND * ND);
  cast(Vp_w,       w_vp,   ND * ND);
  cast(ff1_w,      w_ff1,  NDFF * ND);
  cast(ff2_w,      w_ff2,  ND * NDFF);
  pack_qk_kernel<<<dim3(128), blk, 0, stream>>>(Qp_w, Kp_w, Qp_b, Kp_b, w_qk, bias_qk);

  // 1. qkv = src @ in_proj^T + b   [4096,3072] bf16  (768 blocks)
  mfma_gemm<128,128,1,0,0><<<dim3(3*ND/128, NM/128, 1), blk, 0, stream>>>(
      src_bf, w_qkv, in_proj_b, qkv, ND, ND, ND, 3*ND, 0,0, 0,0, 0,0, 1.f);

  // 2. dense MHA, per batch (S_b / Vt_b reused across b)
  for (int b = 0; b < NB; ++b) {
    const bf16* qkv_b = qkv + (size_t)b * NS * 3 * ND;
    mfma_gemm<128,128,0,0,0><<<dim3(NS/128, NS/128, NH), blk, 0, stream>>>(
        qkv_b, qkv_b + ND, nullptr, S_b, NDH, 3*ND, 3*ND, NS,
        0, NDH, 0, NDH, 0, (long long)NS*NS, 0.125f);
    softmax_kernel<<<dim3(NH*NS/4), blk, 0, stream>>>(S_b);
    transpose_v_kernel<<<dim3(NS/64, NH), blk, 0, stream>>>(qkv_b, Vt_b);
    // PV: 128x64 tiles -> 8x1x16 = 128 blocks/launch
    mfma_gemm<128,64,0,0,0><<<dim3(1, NS/128, NH), blk, 0, stream>>>(
        S_b, Vt_b, nullptr, ctx + (size_t)b * NS * ND, NS, NS, NS, ND,
        0, (long long)NS*NS, 0, (long long)NDH*NS, 0, NDH, 1.f);
  }

  // 3. dense_output = ctx @ out_proj^T + b  (bf16; 128x64 -> 512 blocks)
  mfma_gemm<128,64,1,0,0><<<dim3(ND/64, NM/128, 1), blk, 0, stream>>>(
      ctx, w_out, out_proj_b, dense, ND, ND, ND, ND, 0,0, 0,0, 0,0, 1.f);
  // 4. QKs_bf = src @ [Qp;Kp]^T + b  (bf16 [4096][128]; 128x64 -> 64 blocks)
  mfma_gemm<128,64,1,0,0><<<dim3(2, NM/128, 1), blk, 0, stream>>>(
      src_bf, w_qk, bias_qk, QKs_bf, ND, ND, ND, 128, 0,0, 0,0, 0,0, 1.f);
  // 4b. S_sp[b] = (Qs Ks^T)/8  fp32, batched over b (128x64 -> 512 blocks)
  mfma_gemm<128,64,0,0,1><<<dim3(NS/64, NS/128, NB), blk, 0, stream>>>(
      QKs_bf, QKs_bf + 64, nullptr, S_sp, 64, 128, 128, NS,
      0, (long long)NS*128, 0, (long long)NS*128, 0, (long long)NS*NS, 0.125f);
  // 5. Vsp = src @ Vp^T + b  (bf16; 128x64 -> 512 blocks)
  mfma_gemm<128,64,1,0,0><<<dim3(ND/64, NM/128, 1), blk, 0, stream>>>(
      src_bf, w_vp, Vp_b, Vsp, ND, ND, ND, ND, 0,0, 0,0, 0,0, 1.f);
  // 5b. Vsp_t[b][d][s] = Vsp[b][s][d]   (ctx slot reused)
  transpose_sq_kernel<<<dim3(NS/64, ND/64, NB), blk, 0, stream>>>(Vsp, Vsp_t);
  // 6a. top-k select + normalized weights -> aw (bf16), one wave per row
  sparse_select_kernel<<<dim3(NM/4), blk, 0, stream>>>(S_sp, aw);
  // 6b. sparse = aw @ Vsp^T  (batched per b; 128x64 -> 512 blocks)
  mfma_gemm<128,64,0,0,0><<<dim3(ND/64, NS/128, NB), blk, 0, stream>>>(
      aw, Vsp_t, nullptr, sparse, NS, NS, NS, ND,
      0, (long long)NS*ND, 0, (long long)ND*NS, 0, (long long)NS*ND, 1.f);
  // 7. fuse + residual + LN1 -> x1 (bf16)  [qkv/S_b dead; x1 aliases them]
  fuse_ln1_kernel<<<dim3(NM), blk, 0, stream>>>(src, dense, sparse, lam, ln1_g, ln1_b, x1);
  // 8. h1 = relu(x1 @ ff1^T + b)  (bf16; 1024 blocks)
  mfma_gemm<128,128,1,1,0><<<dim3(NDFF/128, NM/128, 1), blk, 0, stream>>>(
      x1, w_ff1, ff1_b, h1, ND, ND, ND, NDFF, 0,0, 0,0, 0,0, 1.f);
  // 9. ff = h1 @ ff2^T + b  (bf16; 128x64 -> 512 blocks)
  mfma_gemm<128,64,1,0,0><<<dim3(ND/64, NM/128, 1), blk, 0, stream>>>(
      h1, w_ff2, ff2_b, ffout, NDFF, NDFF, NDFF, ND, 0,0, 0,0, 0,0, 1.f);
  // 10. out = LN2(x1 + ff)  (fp32)
  ln2_kernel<<<dim3(NM), blk, 0, stream>>>(x1, ffout, ln2_g, ln2_b, (float*)d_out);
}